// Round 8
// baseline (3891.862 us; speedup 1.0000x reference)
//
#include <hip/hip_runtime.h>
#include <hip/hip_bf16.h>
#include <hip/hip_fp16.h>

#define NF   64
#define NH   8
#define ND   8
#define NHID 32

__device__ __forceinline__ float bf2f(unsigned short u) {
    union { unsigned int i; float f; } v; v.i = ((unsigned int)u) << 16; return v.f;
}
__device__ __forceinline__ unsigned short f2bf(float f) {
    __hip_bfloat16 b = __float2bfloat16(f);
    union { __hip_bfloat16 b; unsigned short u; } v; v.b = b; return v.u;
}
__device__ __forceinline__ void unpack8(uint4 u, float* o) {
    o[0] = __uint_as_float(u.x << 16); o[1] = __uint_as_float(u.x & 0xffff0000u);
    o[2] = __uint_as_float(u.y << 16); o[3] = __uint_as_float(u.y & 0xffff0000u);
    o[4] = __uint_as_float(u.z << 16); o[5] = __uint_as_float(u.z & 0xffff0000u);
    o[6] = __uint_as_float(u.w << 16); o[7] = __uint_as_float(u.w & 0xffff0000u);
}
__device__ __forceinline__ uint4 pack8(const float* f) {
    uint4 u;
    u.x = (unsigned)f2bf(f[0]) | ((unsigned)f2bf(f[1]) << 16);
    u.y = (unsigned)f2bf(f[2]) | ((unsigned)f2bf(f[3]) << 16);
    u.z = (unsigned)f2bf(f[4]) | ((unsigned)f2bf(f[5]) << 16);
    u.w = (unsigned)f2bf(f[6]) | ((unsigned)f2bf(f[7]) << 16);
    return u;
}
__device__ __forceinline__ float leaky(float x) { return x > 0.f ? x : 0.2f * x; }
__device__ __forceinline__ float sigmoidf(float x) { return 1.f / (1.f + __expf(-x)); }

__global__ void detect_kernel(const int* __restrict__ edge, int* __restrict__ flags) {
    if (threadIdx.x == 0 && blockIdx.x == 0) {
        int oddnz = 0;
        for (int i = 0; i < 32; i++) oddnz |= edge[2 * i + 1];
        flags[0] = (oddnz == 0) ? 1 : 0;
    }
}

__device__ __forceinline__ void load_edge(const int* __restrict__ edge, int e, int E,
                                          int wide, int& s, int& d) {
    if (wide) { s = edge[2 * e]; d = edge[2 * (E + e)]; }
    else      { s = edge[e];     d = edge[E + e]; }
}

// ---------------------------------------------------------------------------
// Node phase: stages g_src/g_dst (bf16), writes base a_dst*g_dst into fp32
// out (full overwrite), zeroes counts/cursor.
// ---------------------------------------------------------------------------
template <bool STORE_G>
__global__ __launch_bounds__(256) void node_kernel_t(
    const float* __restrict__ h,
    const float* __restrict__ W_src, const float* __restrict__ b_src,
    const float* __restrict__ W_dst, const float* __restrict__ b_dst,
    const float* __restrict__ Wa1, const float* __restrict__ ba1,
    const float* __restrict__ Wa2, const float* __restrict__ ba2,
    unsigned short* __restrict__ g_src_out, unsigned short* __restrict__ g_dst_out,
    float* __restrict__ out, int* __restrict__ counts, int* __restrict__ cursor, int N)
{
    __shared__ __align__(16) float sWs[NF * NF];
    __shared__ __align__(16) float sWd[NF * NF];
    __shared__ __align__(16) float sW1[NF * NHID];
    __shared__ __align__(16) float sW2[NHID * NH];
    __shared__ float sbs[NF], sbd[NF], sb1[NHID], sb2[NH];

    int tid = threadIdx.x;
    for (int i = tid; i < NF * NF; i += 256) { sWs[i] = W_src[i]; sWd[i] = W_dst[i]; }
    for (int i = tid; i < NF * NHID; i += 256) sW1[i] = Wa1[i];
    if (tid < NHID * NH) sW2[tid] = Wa2[tid];
    if (tid < NF) { sbs[tid] = b_src[tid]; sbd[tid] = b_dst[tid]; }
    if (tid < NHID) sb1[tid] = ba1[tid];
    if (tid < NH) sb2[tid] = ba2[tid];
    __syncthreads();

    int n = blockIdx.x * 256 + tid;
    if (n >= N) return;

    if (counts) { counts[n] = 0; cursor[n] = 0; }

    float hrow[NF];
    const float4* hv = (const float4*)(h + (size_t)n * NF);
    #pragma unroll
    for (int k = 0; k < 16; k++) {
        float4 u = hv[k];
        hrow[k * 4 + 0] = u.x; hrow[k * 4 + 1] = u.y;
        hrow[k * 4 + 2] = u.z; hrow[k * 4 + 3] = u.w;
    }

    float acc[NF];
    const float4* Wsv = (const float4*)sWs;
    const float4* Wdv = (const float4*)sWd;

    if (STORE_G) {
        #pragma unroll
        for (int j = 0; j < NF; j++) acc[j] = sbs[j];
        for (int i = 0; i < NF; i++) {
            float hi = hrow[i];
            #pragma unroll
            for (int jb = 0; jb < 16; jb++) {
                float4 w = Wsv[i * 16 + jb];
                acc[jb * 4 + 0] = fmaf(hi, w.x, acc[jb * 4 + 0]);
                acc[jb * 4 + 1] = fmaf(hi, w.y, acc[jb * 4 + 1]);
                acc[jb * 4 + 2] = fmaf(hi, w.z, acc[jb * 4 + 2]);
                acc[jb * 4 + 3] = fmaf(hi, w.w, acc[jb * 4 + 3]);
            }
        }
        uint4* gs = (uint4*)(g_src_out + (size_t)n * NF);
        #pragma unroll
        for (int k = 0; k < 8; k++) gs[k] = pack8(acc + k * 8);
    }

    #pragma unroll
    for (int j = 0; j < NF; j++) acc[j] = sbd[j];
    for (int i = 0; i < NF; i++) {
        float hi = hrow[i];
        #pragma unroll
        for (int jb = 0; jb < 16; jb++) {
            float4 w = Wdv[i * 16 + jb];
            acc[jb * 4 + 0] = fmaf(hi, w.x, acc[jb * 4 + 0]);
            acc[jb * 4 + 1] = fmaf(hi, w.y, acc[jb * 4 + 1]);
            acc[jb * 4 + 2] = fmaf(hi, w.z, acc[jb * 4 + 2]);
            acc[jb * 4 + 3] = fmaf(hi, w.w, acc[jb * 4 + 3]);
        }
    }
    if (STORE_G) {
        uint4* gd = (uint4*)(g_dst_out + (size_t)n * NF);
        #pragma unroll
        for (int k = 0; k < 8; k++) gd[k] = pack8(acc + k * 8);
    }

    float hid[NHID];
    #pragma unroll
    for (int j = 0; j < NHID; j++) hid[j] = sb1[j];
    const float4* W1v = (const float4*)sW1;
    for (int i = 0; i < NF; i++) {
        float xi = leaky(acc[i]);
        #pragma unroll
        for (int jb = 0; jb < 8; jb++) {
            float4 w = W1v[i * 8 + jb];
            hid[jb * 4 + 0] = fmaf(xi, w.x, hid[jb * 4 + 0]);
            hid[jb * 4 + 1] = fmaf(xi, w.y, hid[jb * 4 + 1]);
            hid[jb * 4 + 2] = fmaf(xi, w.z, hid[jb * 4 + 2]);
            hid[jb * 4 + 3] = fmaf(xi, w.w, hid[jb * 4 + 3]);
        }
    }
    float a[NH];
    #pragma unroll
    for (int j = 0; j < NH; j++) a[j] = sb2[j];
    #pragma unroll
    for (int k = 0; k < NHID; k++) {
        float xk = leaky(hid[k]);
        #pragma unroll
        for (int j = 0; j < NH; j++) a[j] = fmaf(xk, sW2[k * NH + j], a[j]);
    }
    #pragma unroll
    for (int j = 0; j < NH; j++) a[j] = sigmoidf(a[j]);

    float4* ap = (float4*)(out + (size_t)n * NF);
    #pragma unroll
    for (int k = 0; k < 16; k++) {
        int j = k * 4;
        ap[k] = make_float4(a[(j + 0) >> 3] * acc[j + 0],
                            a[(j + 1) >> 3] * acc[j + 1],
                            a[(j + 2) >> 3] * acc[j + 2],
                            a[(j + 3) >> 3] * acc[j + 3]);
    }
}

__global__ __launch_bounds__(256) void hist_kernel(
    const int* __restrict__ edge, const int* __restrict__ flags,
    int* __restrict__ counts, int E, int N)
{
    int e = blockIdx.x * 256 + threadIdx.x;
    if (e >= E) return;
    int s, d;
    load_edge(edge, e, E, flags[0], s, d);
    if ((unsigned)s >= (unsigned)N || (unsigned)d >= (unsigned)N) return;
    atomicAdd(&counts[d], 1);
}

__global__ __launch_bounds__(256) void scan1_kernel(
    const int* __restrict__ counts, int* __restrict__ offsets,
    int* __restrict__ bsums, int N)
{
    __shared__ int lds[256];
    int tid = threadIdx.x;
    int base = blockIdx.x * 2048 + tid * 8;
    int v[8]; int s = 0;
    #pragma unroll
    for (int k = 0; k < 8; k++) { int idx = base + k; int t = (idx < N) ? counts[idx] : 0; v[k] = t; s += t; }
    lds[tid] = s;
    __syncthreads();
    for (int off = 1; off < 256; off <<= 1) {
        int y = (tid >= off) ? lds[tid - off] : 0;
        __syncthreads();
        lds[tid] += y;
        __syncthreads();
    }
    int run = lds[tid] - s;
    #pragma unroll
    for (int k = 0; k < 8; k++) { int idx = base + k; if (idx < N) offsets[idx] = run; run += v[k]; }
    if (tid == 255) bsums[blockIdx.x] = lds[255];
}

__global__ void scan2_kernel(int* __restrict__ bsums, int* __restrict__ offsets, int NB, int N) {
    if (threadIdx.x == 0 && blockIdx.x == 0) {
        int run = 0;
        for (int i = 0; i < NB; i++) { int t = bsums[i]; bsums[i] = run; run += t; }
        offsets[N] = run;
    }
}

__global__ __launch_bounds__(256) void scan3_kernel(
    int* __restrict__ offsets, const int* __restrict__ bsums, int N)
{
    int add = bsums[blockIdx.x];
    int base = blockIdx.x * 2048 + threadIdx.x * 8;
    #pragma unroll
    for (int k = 0; k < 8; k++) { int idx = base + k; if (idx < N) offsets[idx] += add; }
}

__global__ __launch_bounds__(256) void scatter_kernel(
    const int* __restrict__ edge, const int* __restrict__ flags,
    const int* __restrict__ offsets, int* __restrict__ cursor,
    uint2* __restrict__ sorted_sd, int E, int N)
{
    int e = blockIdx.x * 256 + threadIdx.x;
    if (e >= E) return;
    int s, d;
    load_edge(edge, e, E, flags[0], s, d);
    if ((unsigned)s >= (unsigned)N || (unsigned)d >= (unsigned)N) return;
    int pos = offsets[d] + atomicAdd(&cursor[d], 1);
    sorted_sd[pos] = make_uint2((unsigned)s, (unsigned)d);
}

// ---------------------------------------------------------------------------
// Edge MLP over SORTED slots, 2 edges per thread: one LDS W1 read feeds both
// edges (halves per-edge LDS traffic); consecutive slots usually share d so
// g_dst row hits L1.
// ---------------------------------------------------------------------------
__global__ __launch_bounds__(256) void edge_mlp_sorted_kernel(
    const uint2* __restrict__ sorted_sd, const int* __restrict__ total_p,
    const unsigned short* __restrict__ g_src, const unsigned short* __restrict__ g_dst,
    const float* __restrict__ Wa1, const float* __restrict__ ba1,
    const float* __restrict__ Wa2, const float* __restrict__ ba2,
    __half* __restrict__ a_sorted)
{
    __shared__ __align__(16) float sW1[NF * NHID];
    __shared__ __align__(16) float sW2[NHID * NH];
    __shared__ float sb1[NHID], sb2[NH];
    int tid = threadIdx.x;
    for (int i = tid; i < NF * NHID; i += 256) sW1[i] = Wa1[i];
    if (tid < NHID * NH) sW2[tid] = Wa2[tid];
    if (tid < NHID) sb1[tid] = ba1[tid];
    if (tid < NH) sb2[tid] = ba2[tid];
    __syncthreads();

    int total = *total_p;
    int i0 = (blockIdx.x * 256 + tid) * 2;
    if (i0 >= total) return;
    bool two = (i0 + 1 < total);
    uint2 sd0 = sorted_sd[i0];
    uint2 sd1 = two ? sorted_sd[i0 + 1] : sd0;

    float hid0[NHID], hid1[NHID];
    #pragma unroll
    for (int j = 0; j < NHID; j++) { hid0[j] = sb1[j]; hid1[j] = sb1[j]; }

    const uint4* gs0 = (const uint4*)(g_src + (size_t)sd0.x * NF);
    const uint4* gd0 = (const uint4*)(g_dst + (size_t)sd0.y * NF);
    const uint4* gs1 = (const uint4*)(g_src + (size_t)sd1.x * NF);
    const uint4* gd1 = (const uint4*)(g_dst + (size_t)sd1.y * NF);
    const float4* W1v = (const float4*)sW1;

    #pragma unroll
    for (int k = 0; k < 8; k++) {
        float a0[8], b0[8], a1[8], b1[8];
        unpack8(gs0[k], a0); unpack8(gd0[k], b0);
        unpack8(gs1[k], a1); unpack8(gd1[k], b1);
        #pragma unroll
        for (int t = 0; t < 8; t++) {
            int i = k * 8 + t;
            float x0 = leaky(a0[t] + b0[t]);
            float x1 = leaky(a1[t] + b1[t]);
            #pragma unroll
            for (int jb = 0; jb < 8; jb++) {
                float4 w = W1v[i * 8 + jb];
                hid0[jb * 4 + 0] = fmaf(x0, w.x, hid0[jb * 4 + 0]);
                hid0[jb * 4 + 1] = fmaf(x0, w.y, hid0[jb * 4 + 1]);
                hid0[jb * 4 + 2] = fmaf(x0, w.z, hid0[jb * 4 + 2]);
                hid0[jb * 4 + 3] = fmaf(x0, w.w, hid0[jb * 4 + 3]);
                hid1[jb * 4 + 0] = fmaf(x1, w.x, hid1[jb * 4 + 0]);
                hid1[jb * 4 + 1] = fmaf(x1, w.y, hid1[jb * 4 + 1]);
                hid1[jb * 4 + 2] = fmaf(x1, w.z, hid1[jb * 4 + 2]);
                hid1[jb * 4 + 3] = fmaf(x1, w.w, hid1[jb * 4 + 3]);
            }
        }
    }

    float A0[NH], A1[NH];
    #pragma unroll
    for (int j = 0; j < NH; j++) { A0[j] = sb2[j]; A1[j] = sb2[j]; }
    #pragma unroll
    for (int k = 0; k < NHID; k++) {
        float x0 = leaky(hid0[k]);
        float x1 = leaky(hid1[k]);
        #pragma unroll
        for (int j = 0; j < NH; j++) {
            A0[j] = fmaf(x0, sW2[k * NH + j], A0[j]);
            A1[j] = fmaf(x1, sW2[k * NH + j], A1[j]);
        }
    }

    union { __half h[8]; uint4 u; } pk;
    #pragma unroll
    for (int j = 0; j < NH; j++) pk.h[j] = __float2half(sigmoidf(A0[j]));
    *(uint4*)(a_sorted + (size_t)i0 * NH) = pk.u;
    if (two) {
        #pragma unroll
        for (int j = 0; j < NH; j++) pk.h[j] = __float2half(sigmoidf(A1[j]));
        *(uint4*)(a_sorted + (size_t)(i0 + 1) * NH) = pk.u;
    }
}

// ---------------------------------------------------------------------------
// Aggregate v2: 8 threads per dst (lane=head, 8 features via uint4), unroll-2
// over the segment -> many independent gather streams per wave.
// ---------------------------------------------------------------------------
__global__ __launch_bounds__(256) void aggregate_kernel(
    const int* __restrict__ offsets, const uint2* __restrict__ sorted_sd,
    const __half* __restrict__ a_sorted, const unsigned short* __restrict__ g_src,
    float* __restrict__ out, int N)
{
    int d = blockIdx.x * 32 + (threadIdx.x >> 3);
    if (d >= N) return;
    int l = threadIdx.x & 7;            // head index; features l*8 .. l*8+7
    int beg = offsets[d], end = offsets[d + 1];

    float acc[8] = {0.f, 0.f, 0.f, 0.f, 0.f, 0.f, 0.f, 0.f};
    int i = beg;
    for (; i + 2 <= end; i += 2) {
        unsigned s0 = sorted_sd[i].x;
        unsigned s1 = sorted_sd[i + 1].x;
        float av0 = __half2float(a_sorted[(size_t)i * NH + l]);
        float av1 = __half2float(a_sorted[(size_t)(i + 1) * NH + l]);
        uint4 q0 = *(const uint4*)(g_src + (size_t)s0 * NF + l * 8);
        uint4 q1 = *(const uint4*)(g_src + (size_t)s1 * NF + l * 8);
        float f0[8], f1[8];
        unpack8(q0, f0); unpack8(q1, f1);
        #pragma unroll
        for (int t = 0; t < 8; t++) acc[t] = fmaf(av0, f0[t], acc[t]);
        #pragma unroll
        for (int t = 0; t < 8; t++) acc[t] = fmaf(av1, f1[t], acc[t]);
    }
    if (i < end) {
        unsigned s0 = sorted_sd[i].x;
        float av0 = __half2float(a_sorted[(size_t)i * NH + l]);
        uint4 q0 = *(const uint4*)(g_src + (size_t)s0 * NF + l * 8);
        float f0[8]; unpack8(q0, f0);
        #pragma unroll
        for (int t = 0; t < 8; t++) acc[t] = fmaf(av0, f0[t], acc[t]);
    }

    float4* o4 = (float4*)(out + (size_t)d * NF + l * 8);
    float4 v0 = o4[0], v1 = o4[1];
    v0.x += acc[0]; v0.y += acc[1]; v0.z += acc[2]; v0.w += acc[3];
    v1.x += acc[4]; v1.y += acc[5]; v1.z += acc[6]; v1.w += acc[7];
    o4[0] = v0; o4[1] = v1;
}

// ---------------------------------------------------------------------------
// Fallbacks (small ws): R5 atomic edge kernel / fully fused.
// ---------------------------------------------------------------------------
__global__ __launch_bounds__(256) void edge_kernel(
    const int* __restrict__ edge, const int* __restrict__ flags,
    const unsigned short* __restrict__ g_src, const unsigned short* __restrict__ g_dst,
    const float* __restrict__ Wa1, const float* __restrict__ ba1,
    const float* __restrict__ Wa2, const float* __restrict__ ba2,
    float* __restrict__ out, int E, int N)
{
    __shared__ __align__(16) float sW1[NF * NHID];
    __shared__ __align__(16) float sW2[NHID * NH];
    __shared__ float sb1[NHID], sb2[NH];
    int tid = threadIdx.x;
    for (int i = tid; i < NF * NHID; i += 256) sW1[i] = Wa1[i];
    if (tid < NHID * NH) sW2[tid] = Wa2[tid];
    if (tid < NHID) sb1[tid] = ba1[tid];
    if (tid < NH) sb2[tid] = ba2[tid];
    __syncthreads();

    int e = blockIdx.x * 256 + tid;
    if (e >= E) return;
    int s, d;
    load_edge(edge, e, E, flags[0], s, d);
    if ((unsigned)s >= (unsigned)N || (unsigned)d >= (unsigned)N) return;

    float ms[NF];
    float hid[NHID];
    #pragma unroll
    for (int j = 0; j < NHID; j++) hid[j] = sb1[j];

    const uint4* gs = (const uint4*)(g_src + (size_t)s * NF);
    const uint4* gd = (const uint4*)(g_dst + (size_t)d * NF);
    #pragma unroll
    for (int k = 0; k < 8; k++) {
        float a8[8], b8[8];
        unpack8(gs[k], a8);
        unpack8(gd[k], b8);
        #pragma unroll
        for (int t = 0; t < 8; t++) {
            int i = k * 8 + t;
            ms[i] = a8[t];
            float x = leaky(a8[t] + b8[t]);
            #pragma unroll
            for (int j = 0; j < NHID; j++) hid[j] = fmaf(x, sW1[i * NHID + j], hid[j]);
        }
    }

    float a[NH];
    #pragma unroll
    for (int j = 0; j < NH; j++) a[j] = sb2[j];
    #pragma unroll
    for (int k = 0; k < NHID; k++) {
        float xk = leaky(hid[k]);
        #pragma unroll
        for (int j = 0; j < NH; j++) a[j] = fmaf(xk, sW2[k * NH + j], a[j]);
    }

    float* arow = out + (size_t)d * NF;
    #pragma unroll
    for (int hh = 0; hh < NH; hh++) {
        float ah = sigmoidf(a[hh]);
        #pragma unroll
        for (int dd = 0; dd < ND; dd++)
            unsafeAtomicAdd(arow + hh * ND + dd, ah * ms[hh * ND + dd]);
    }
}

__global__ __launch_bounds__(256) void edge_kernel_fused(
    const int* __restrict__ edge, const int* __restrict__ flags,
    const float* __restrict__ h,
    const float* __restrict__ W_src, const float* __restrict__ b_src,
    const float* __restrict__ W_dst, const float* __restrict__ b_dst,
    const float* __restrict__ Wa1, const float* __restrict__ ba1,
    const float* __restrict__ Wa2, const float* __restrict__ ba2,
    float* __restrict__ out, int E, int N)
{
    __shared__ __align__(16) float sWs[NF * NF];
    __shared__ __align__(16) float sWd[NF * NF];
    __shared__ __align__(16) float sW1[NF * NHID];
    __shared__ __align__(16) float sW2[NHID * NH];
    __shared__ float sbs[NF], sbd[NF], sb1[NHID], sb2[NH];
    int tid = threadIdx.x;
    for (int i = tid; i < NF * NF; i += 256) { sWs[i] = W_src[i]; sWd[i] = W_dst[i]; }
    for (int i = tid; i < NF * NHID; i += 256) sW1[i] = Wa1[i];
    if (tid < NHID * NH) sW2[tid] = Wa2[tid];
    if (tid < NF) { sbs[tid] = b_src[tid]; sbd[tid] = b_dst[tid]; }
    if (tid < NHID) sb1[tid] = ba1[tid];
    if (tid < NH) sb2[tid] = ba2[tid];
    __syncthreads();

    int e = blockIdx.x * 256 + tid;
    if (e >= E) return;
    int wide = flags ? flags[0] : 0;
    int s, d;
    load_edge(edge, e, E, wide, s, d);
    if ((unsigned)s >= (unsigned)N || (unsigned)d >= (unsigned)N) return;

    float gsr[NF], msg[NF];
    {
        float hrow[NF];
        #pragma unroll
        for (int i = 0; i < NF; i++) hrow[i] = h[(size_t)s * NF + i];
        #pragma unroll
        for (int j = 0; j < NF; j++) gsr[j] = sbs[j];
        for (int i = 0; i < NF; i++) {
            float hi = hrow[i];
            #pragma unroll
            for (int j = 0; j < NF; j++) gsr[j] = fmaf(hi, sWs[i * NF + j], gsr[j]);
        }
    }
    #pragma unroll
    for (int j = 0; j < NF; j++) msg[j] = gsr[j] + sbd[j];
    for (int i = 0; i < NF; i++) {
        float hi = h[(size_t)d * NF + i];
        #pragma unroll
        for (int j = 0; j < NF; j++) msg[j] = fmaf(hi, sWd[i * NF + j], msg[j]);
    }

    float hid[NHID];
    #pragma unroll
    for (int j = 0; j < NHID; j++) hid[j] = sb1[j];
    for (int i = 0; i < NF; i++) {
        float x = leaky(msg[i]);
        #pragma unroll
        for (int j = 0; j < NHID; j++) hid[j] = fmaf(x, sW1[i * NHID + j], hid[j]);
    }
    float a[NH];
    #pragma unroll
    for (int j = 0; j < NH; j++) a[j] = sb2[j];
    #pragma unroll
    for (int k = 0; k < NHID; k++) {
        float xk = leaky(hid[k]);
        #pragma unroll
        for (int j = 0; j < NH; j++) a[j] = fmaf(xk, sW2[k * NH + j], a[j]);
    }

    float* arow = out + (size_t)d * NF;
    #pragma unroll
    for (int hh = 0; hh < NH; hh++) {
        float ah = sigmoidf(a[hh]);
        #pragma unroll
        for (int dd = 0; dd < ND; dd++)
            unsafeAtomicAdd(arow + hh * ND + dd, ah * gsr[hh * ND + dd]);
    }
}

static inline size_t al256(size_t x) { return (x + 255) & ~(size_t)255; }

extern "C" void kernel_launch(void* const* d_in, const int* in_sizes, int n_in,
                              void* d_out, int out_size, void* d_ws, size_t ws_size,
                              hipStream_t stream) {
    const float* h       = (const float*)d_in[0];
    const float* W_src   = (const float*)d_in[1];
    const float* b_src   = (const float*)d_in[2];
    const float* W_dst   = (const float*)d_in[3];
    const float* b_dst   = (const float*)d_in[4];
    const float* Wa1_src = (const float*)d_in[5];
    const float* ba1_src = (const float*)d_in[6];
    const float* Wa2_src = (const float*)d_in[7];
    const float* ba2_src = (const float*)d_in[8];
    const float* Wa1_dst = (const float*)d_in[9];
    const float* ba1_dst = (const float*)d_in[10];
    const float* Wa2_dst = (const float*)d_in[11];
    const float* ba2_dst = (const float*)d_in[12];
    const int* edge = (const int*)d_in[13];

    int N = in_sizes[0] / NF;
    int E = in_sizes[13] / 2;
    float* out = (float*)d_out;

    int nodeBlocks = (N + 255) / 256;
    int edgeBlocks = (E + 255) / 256;
    int NB1 = (N + 2047) / 2048;
    int pairBlocks = ((E + 1) / 2 + 255) / 256;

    // ws layout (sort path)
    size_t o_flags  = 0;
    size_t o_gsrc   = al256(o_flags + 256);
    size_t o_gdst   = al256(o_gsrc + (size_t)N * NF * 2);
    size_t o_asort  = al256(o_gdst + (size_t)N * NF * 2);
    size_t o_counts = al256(o_asort + (size_t)E * NH * 2);
    size_t o_offs   = al256(o_counts + (size_t)N * 4);
    size_t o_cursor = al256(o_offs + ((size_t)N + 1) * 4);
    size_t o_bsums  = al256(o_cursor + (size_t)N * 4);
    size_t o_sorted = al256(o_bsums + (size_t)NB1 * 4);
    size_t need     = o_sorted + (size_t)E * 8;

    size_t gB = (size_t)N * NF * 2;

    if (ws_size >= need) {
        char* w = (char*)d_ws;
        int*            flags   = (int*)(w + o_flags);
        unsigned short* g_src   = (unsigned short*)(w + o_gsrc);
        unsigned short* g_dst   = (unsigned short*)(w + o_gdst);
        __half*         a_sort  = (__half*)(w + o_asort);
        int*            counts  = (int*)(w + o_counts);
        int*            offsets = (int*)(w + o_offs);
        int*            cursor  = (int*)(w + o_cursor);
        int*            bsums   = (int*)(w + o_bsums);
        uint2*          sorted  = (uint2*)(w + o_sorted);

        detect_kernel<<<1, 1, 0, stream>>>(edge, flags);

        node_kernel_t<true><<<nodeBlocks, 256, 0, stream>>>(
            h, W_src, b_src, W_dst, b_dst,
            Wa1_dst, ba1_dst, Wa2_dst, ba2_dst,
            g_src, g_dst, out, counts, cursor, N);

        hist_kernel<<<edgeBlocks, 256, 0, stream>>>(edge, flags, counts, E, N);

        scan1_kernel<<<NB1, 256, 0, stream>>>(counts, offsets, bsums, N);
        scan2_kernel<<<1, 1, 0, stream>>>(bsums, offsets, NB1, N);
        scan3_kernel<<<NB1, 256, 0, stream>>>(offsets, bsums, N);

        scatter_kernel<<<edgeBlocks, 256, 0, stream>>>(
            edge, flags, offsets, cursor, sorted, E, N);

        edge_mlp_sorted_kernel<<<pairBlocks, 256, 0, stream>>>(
            sorted, offsets + N, g_src, g_dst,
            Wa1_src, ba1_src, Wa2_src, ba2_src, a_sort);

        aggregate_kernel<<<(N + 31) / 32, 256, 0, stream>>>(
            offsets, sorted, a_sort, g_src, out, N);
    } else if (ws_size >= 256 + 2 * gB) {
        int* flags = (int*)d_ws;
        unsigned short* g_src = (unsigned short*)((char*)d_ws + 256);
        unsigned short* g_dst = g_src + (size_t)N * NF;

        detect_kernel<<<1, 1, 0, stream>>>(edge, flags);

        node_kernel_t<true><<<nodeBlocks, 256, 0, stream>>>(
            h, W_src, b_src, W_dst, b_dst,
            Wa1_dst, ba1_dst, Wa2_dst, ba2_dst,
            g_src, g_dst, out, nullptr, nullptr, N);

        edge_kernel<<<edgeBlocks, 256, 0, stream>>>(
            edge, flags, g_src, g_dst,
            Wa1_src, ba1_src, Wa2_src, ba2_src,
            out, E, N);
    } else {
        int* flags = (ws_size >= 256) ? (int*)d_ws : nullptr;
        if (flags) detect_kernel<<<1, 1, 0, stream>>>(edge, flags);

        node_kernel_t<false><<<nodeBlocks, 256, 0, stream>>>(
            h, W_src, b_src, W_dst, b_dst,
            Wa1_dst, ba1_dst, Wa2_dst, ba2_dst,
            nullptr, nullptr, out, nullptr, nullptr, N);

        edge_kernel_fused<<<edgeBlocks, 256, 0, stream>>>(
            edge, flags, h,
            W_src, b_src, W_dst, b_dst,
            Wa1_src, ba1_src, Wa2_src, ba2_src,
            out, E, N);
    }
}

// Round 9
// 450.352 us; speedup vs baseline: 8.6418x; 8.6418x over previous
//
#include <hip/hip_runtime.h>
#include <hip/hip_bf16.h>
#include <hip/hip_fp16.h>

#define NF   64
#define NH   8
#define ND   8
#define NHID 32

__device__ __forceinline__ float bf2f(unsigned short u) {
    union { unsigned int i; float f; } v; v.i = ((unsigned int)u) << 16; return v.f;
}
__device__ __forceinline__ unsigned short f2bf(float f) {
    __hip_bfloat16 b = __float2bfloat16(f);
    union { __hip_bfloat16 b; unsigned short u; } v; v.b = b; return v.u;
}
__device__ __forceinline__ void unpack8(uint4 u, float* o) {
    o[0] = __uint_as_float(u.x << 16); o[1] = __uint_as_float(u.x & 0xffff0000u);
    o[2] = __uint_as_float(u.y << 16); o[3] = __uint_as_float(u.y & 0xffff0000u);
    o[4] = __uint_as_float(u.z << 16); o[5] = __uint_as_float(u.z & 0xffff0000u);
    o[6] = __uint_as_float(u.w << 16); o[7] = __uint_as_float(u.w & 0xffff0000u);
}
__device__ __forceinline__ uint4 pack8(const float* f) {
    uint4 u;
    u.x = (unsigned)f2bf(f[0]) | ((unsigned)f2bf(f[1]) << 16);
    u.y = (unsigned)f2bf(f[2]) | ((unsigned)f2bf(f[3]) << 16);
    u.z = (unsigned)f2bf(f[4]) | ((unsigned)f2bf(f[5]) << 16);
    u.w = (unsigned)f2bf(f[6]) | ((unsigned)f2bf(f[7]) << 16);
    return u;
}
__device__ __forceinline__ float leaky(float x) { return x > 0.f ? x : 0.2f * x; }
__device__ __forceinline__ float sigmoidf(float x) { return 1.f / (1.f + __expf(-x)); }

__global__ void detect_kernel(const int* __restrict__ edge, int* __restrict__ flags) {
    if (threadIdx.x == 0 && blockIdx.x == 0) {
        int oddnz = 0;
        for (int i = 0; i < 32; i++) oddnz |= edge[2 * i + 1];
        flags[0] = (oddnz == 0) ? 1 : 0;
    }
}

__device__ __forceinline__ void load_edge(const int* __restrict__ edge, int e, int E,
                                          int wide, int& s, int& d) {
    if (wide) { s = edge[2 * e]; d = edge[2 * (E + e)]; }
    else      { s = edge[e];     d = edge[E + e]; }
}

// ---------------------------------------------------------------------------
// Node phase: stages g_src/g_dst (bf16), writes base a_dst*g_dst into fp32
// out (full overwrite), zeroes counts/cursor.
// ---------------------------------------------------------------------------
template <bool STORE_G>
__global__ __launch_bounds__(256) void node_kernel_t(
    const float* __restrict__ h,
    const float* __restrict__ W_src, const float* __restrict__ b_src,
    const float* __restrict__ W_dst, const float* __restrict__ b_dst,
    const float* __restrict__ Wa1, const float* __restrict__ ba1,
    const float* __restrict__ Wa2, const float* __restrict__ ba2,
    unsigned short* __restrict__ g_src_out, unsigned short* __restrict__ g_dst_out,
    float* __restrict__ out, int* __restrict__ counts, int* __restrict__ cursor, int N)
{
    __shared__ __align__(16) float sWs[NF * NF];
    __shared__ __align__(16) float sWd[NF * NF];
    __shared__ __align__(16) float sW1[NF * NHID];
    __shared__ __align__(16) float sW2[NHID * NH];
    __shared__ float sbs[NF], sbd[NF], sb1[NHID], sb2[NH];

    int tid = threadIdx.x;
    for (int i = tid; i < NF * NF; i += 256) { sWs[i] = W_src[i]; sWd[i] = W_dst[i]; }
    for (int i = tid; i < NF * NHID; i += 256) sW1[i] = Wa1[i];
    if (tid < NHID * NH) sW2[tid] = Wa2[tid];
    if (tid < NF) { sbs[tid] = b_src[tid]; sbd[tid] = b_dst[tid]; }
    if (tid < NHID) sb1[tid] = ba1[tid];
    if (tid < NH) sb2[tid] = ba2[tid];
    __syncthreads();

    int n = blockIdx.x * 256 + tid;
    if (n >= N) return;

    if (counts) { counts[n] = 0; cursor[n] = 0; }

    float hrow[NF];
    const float4* hv = (const float4*)(h + (size_t)n * NF);
    #pragma unroll
    for (int k = 0; k < 16; k++) {
        float4 u = hv[k];
        hrow[k * 4 + 0] = u.x; hrow[k * 4 + 1] = u.y;
        hrow[k * 4 + 2] = u.z; hrow[k * 4 + 3] = u.w;
    }

    float acc[NF];
    const float4* Wsv = (const float4*)sWs;
    const float4* Wdv = (const float4*)sWd;

    if (STORE_G) {
        #pragma unroll
        for (int j = 0; j < NF; j++) acc[j] = sbs[j];
        for (int i = 0; i < NF; i++) {
            float hi = hrow[i];
            #pragma unroll
            for (int jb = 0; jb < 16; jb++) {
                float4 w = Wsv[i * 16 + jb];
                acc[jb * 4 + 0] = fmaf(hi, w.x, acc[jb * 4 + 0]);
                acc[jb * 4 + 1] = fmaf(hi, w.y, acc[jb * 4 + 1]);
                acc[jb * 4 + 2] = fmaf(hi, w.z, acc[jb * 4 + 2]);
                acc[jb * 4 + 3] = fmaf(hi, w.w, acc[jb * 4 + 3]);
            }
        }
        uint4* gs = (uint4*)(g_src_out + (size_t)n * NF);
        #pragma unroll
        for (int k = 0; k < 8; k++) gs[k] = pack8(acc + k * 8);
    }

    #pragma unroll
    for (int j = 0; j < NF; j++) acc[j] = sbd[j];
    for (int i = 0; i < NF; i++) {
        float hi = hrow[i];
        #pragma unroll
        for (int jb = 0; jb < 16; jb++) {
            float4 w = Wdv[i * 16 + jb];
            acc[jb * 4 + 0] = fmaf(hi, w.x, acc[jb * 4 + 0]);
            acc[jb * 4 + 1] = fmaf(hi, w.y, acc[jb * 4 + 1]);
            acc[jb * 4 + 2] = fmaf(hi, w.z, acc[jb * 4 + 2]);
            acc[jb * 4 + 3] = fmaf(hi, w.w, acc[jb * 4 + 3]);
        }
    }
    if (STORE_G) {
        uint4* gd = (uint4*)(g_dst_out + (size_t)n * NF);
        #pragma unroll
        for (int k = 0; k < 8; k++) gd[k] = pack8(acc + k * 8);
    }

    float hid[NHID];
    #pragma unroll
    for (int j = 0; j < NHID; j++) hid[j] = sb1[j];
    const float4* W1v = (const float4*)sW1;
    for (int i = 0; i < NF; i++) {
        float xi = leaky(acc[i]);
        #pragma unroll
        for (int jb = 0; jb < 8; jb++) {
            float4 w = W1v[i * 8 + jb];
            hid[jb * 4 + 0] = fmaf(xi, w.x, hid[jb * 4 + 0]);
            hid[jb * 4 + 1] = fmaf(xi, w.y, hid[jb * 4 + 1]);
            hid[jb * 4 + 2] = fmaf(xi, w.z, hid[jb * 4 + 2]);
            hid[jb * 4 + 3] = fmaf(xi, w.w, hid[jb * 4 + 3]);
        }
    }
    float a[NH];
    #pragma unroll
    for (int j = 0; j < NH; j++) a[j] = sb2[j];
    #pragma unroll
    for (int k = 0; k < NHID; k++) {
        float xk = leaky(hid[k]);
        #pragma unroll
        for (int j = 0; j < NH; j++) a[j] = fmaf(xk, sW2[k * NH + j], a[j]);
    }
    #pragma unroll
    for (int j = 0; j < NH; j++) a[j] = sigmoidf(a[j]);

    float4* ap = (float4*)(out + (size_t)n * NF);
    #pragma unroll
    for (int k = 0; k < 16; k++) {
        int j = k * 4;
        ap[k] = make_float4(a[(j + 0) >> 3] * acc[j + 0],
                            a[(j + 1) >> 3] * acc[j + 1],
                            a[(j + 2) >> 3] * acc[j + 2],
                            a[(j + 3) >> 3] * acc[j + 3]);
    }
}

__global__ __launch_bounds__(256) void hist_kernel(
    const int* __restrict__ edge, const int* __restrict__ flags,
    int* __restrict__ counts, int E, int N)
{
    int e = blockIdx.x * 256 + threadIdx.x;
    if (e >= E) return;
    int s, d;
    load_edge(edge, e, E, flags[0], s, d);
    if ((unsigned)s >= (unsigned)N || (unsigned)d >= (unsigned)N) return;
    atomicAdd(&counts[d], 1);
}

__global__ __launch_bounds__(256) void scan1_kernel(
    const int* __restrict__ counts, int* __restrict__ offsets,
    int* __restrict__ bsums, int N)
{
    __shared__ int lds[256];
    int tid = threadIdx.x;
    int base = blockIdx.x * 2048 + tid * 8;
    int v[8]; int s = 0;
    #pragma unroll
    for (int k = 0; k < 8; k++) { int idx = base + k; int t = (idx < N) ? counts[idx] : 0; v[k] = t; s += t; }
    lds[tid] = s;
    __syncthreads();
    for (int off = 1; off < 256; off <<= 1) {
        int y = (tid >= off) ? lds[tid - off] : 0;
        __syncthreads();
        lds[tid] += y;
        __syncthreads();
    }
    int run = lds[tid] - s;
    #pragma unroll
    for (int k = 0; k < 8; k++) { int idx = base + k; if (idx < N) offsets[idx] = run; run += v[k]; }
    if (tid == 255) bsums[blockIdx.x] = lds[255];
}

__global__ void scan2_kernel(int* __restrict__ bsums, int* __restrict__ offsets, int NB, int N) {
    if (threadIdx.x == 0 && blockIdx.x == 0) {
        int run = 0;
        for (int i = 0; i < NB; i++) { int t = bsums[i]; bsums[i] = run; run += t; }
        offsets[N] = run;
    }
}

__global__ __launch_bounds__(256) void scan3_kernel(
    int* __restrict__ offsets, const int* __restrict__ bsums, int N)
{
    int add = bsums[blockIdx.x];
    int base = blockIdx.x * 2048 + threadIdx.x * 8;
    #pragma unroll
    for (int k = 0; k < 8; k++) { int idx = base + k; if (idx < N) offsets[idx] += add; }
}

__global__ __launch_bounds__(256) void scatter_kernel(
    const int* __restrict__ edge, const int* __restrict__ flags,
    const int* __restrict__ offsets, int* __restrict__ cursor,
    uint2* __restrict__ sorted_sd, int E, int N)
{
    int e = blockIdx.x * 256 + threadIdx.x;
    if (e >= E) return;
    int s, d;
    load_edge(edge, e, E, flags[0], s, d);
    if ((unsigned)s >= (unsigned)N || (unsigned)d >= (unsigned)N) return;
    int pos = offsets[d] + atomicAdd(&cursor[d], 1);
    sorted_sd[pos] = make_uint2((unsigned)s, (unsigned)d);
}

// ---------------------------------------------------------------------------
// Edge MLP over SORTED slots, 1 edge per thread (VGPR ~40, high occupancy).
// Consecutive threads usually share d -> g_dst row hits L1/L2. Sequential
// 16B a_sorted writes.
// ---------------------------------------------------------------------------
__global__ __launch_bounds__(256) void edge_mlp_sorted_kernel(
    const uint2* __restrict__ sorted_sd, const int* __restrict__ total_p,
    const unsigned short* __restrict__ g_src, const unsigned short* __restrict__ g_dst,
    const float* __restrict__ Wa1, const float* __restrict__ ba1,
    const float* __restrict__ Wa2, const float* __restrict__ ba2,
    __half* __restrict__ a_sorted)
{
    __shared__ __align__(16) float sW1[NF * NHID];
    __shared__ __align__(16) float sW2[NHID * NH];
    __shared__ float sb1[NHID], sb2[NH];
    int tid = threadIdx.x;
    for (int i = tid; i < NF * NHID; i += 256) sW1[i] = Wa1[i];
    if (tid < NHID * NH) sW2[tid] = Wa2[tid];
    if (tid < NHID) sb1[tid] = ba1[tid];
    if (tid < NH) sb2[tid] = ba2[tid];
    __syncthreads();

    int i0 = blockIdx.x * 256 + tid;
    if (i0 >= *total_p) return;
    uint2 sd = sorted_sd[i0];

    float hid[NHID];
    #pragma unroll
    for (int j = 0; j < NHID; j++) hid[j] = sb1[j];

    const uint4* gs = (const uint4*)(g_src + (size_t)sd.x * NF);
    const uint4* gd = (const uint4*)(g_dst + (size_t)sd.y * NF);
    const float4* W1v = (const float4*)sW1;
    #pragma unroll
    for (int k = 0; k < 8; k++) {
        float a8[8], b8[8];
        unpack8(gs[k], a8);
        unpack8(gd[k], b8);
        #pragma unroll
        for (int t = 0; t < 8; t++) {
            int i = k * 8 + t;
            float x = leaky(a8[t] + b8[t]);
            #pragma unroll
            for (int jb = 0; jb < 8; jb++) {
                float4 w = W1v[i * 8 + jb];
                hid[jb * 4 + 0] = fmaf(x, w.x, hid[jb * 4 + 0]);
                hid[jb * 4 + 1] = fmaf(x, w.y, hid[jb * 4 + 1]);
                hid[jb * 4 + 2] = fmaf(x, w.z, hid[jb * 4 + 2]);
                hid[jb * 4 + 3] = fmaf(x, w.w, hid[jb * 4 + 3]);
            }
        }
    }

    float a[NH];
    #pragma unroll
    for (int j = 0; j < NH; j++) a[j] = sb2[j];
    #pragma unroll
    for (int k = 0; k < NHID; k++) {
        float xk = leaky(hid[k]);
        #pragma unroll
        for (int j = 0; j < NH; j++) a[j] = fmaf(xk, sW2[k * NH + j], a[j]);
    }

    union { __half h[8]; uint4 u; } pk;
    #pragma unroll
    for (int j = 0; j < NH; j++) pk.h[j] = __float2half(sigmoidf(a[j]));
    *(uint4*)(a_sorted + (size_t)i0 * NH) = pk.u;
}

// ---------------------------------------------------------------------------
// Aggregate v2: 8 threads per dst (lane=head, 8 features via uint4), unroll-2
// over the segment -> many independent gather streams per wave.
// ---------------------------------------------------------------------------
__global__ __launch_bounds__(256) void aggregate_kernel(
    const int* __restrict__ offsets, const uint2* __restrict__ sorted_sd,
    const __half* __restrict__ a_sorted, const unsigned short* __restrict__ g_src,
    float* __restrict__ out, int N)
{
    int d = blockIdx.x * 32 + (threadIdx.x >> 3);
    if (d >= N) return;
    int l = threadIdx.x & 7;            // head index; features l*8 .. l*8+7
    int beg = offsets[d], end = offsets[d + 1];

    float acc[8] = {0.f, 0.f, 0.f, 0.f, 0.f, 0.f, 0.f, 0.f};
    int i = beg;
    for (; i + 2 <= end; i += 2) {
        unsigned s0 = sorted_sd[i].x;
        unsigned s1 = sorted_sd[i + 1].x;
        float av0 = __half2float(a_sorted[(size_t)i * NH + l]);
        float av1 = __half2float(a_sorted[(size_t)(i + 1) * NH + l]);
        uint4 q0 = *(const uint4*)(g_src + (size_t)s0 * NF + l * 8);
        uint4 q1 = *(const uint4*)(g_src + (size_t)s1 * NF + l * 8);
        float f0[8], f1[8];
        unpack8(q0, f0); unpack8(q1, f1);
        #pragma unroll
        for (int t = 0; t < 8; t++) acc[t] = fmaf(av0, f0[t], acc[t]);
        #pragma unroll
        for (int t = 0; t < 8; t++) acc[t] = fmaf(av1, f1[t], acc[t]);
    }
    if (i < end) {
        unsigned s0 = sorted_sd[i].x;
        float av0 = __half2float(a_sorted[(size_t)i * NH + l]);
        uint4 q0 = *(const uint4*)(g_src + (size_t)s0 * NF + l * 8);
        float f0[8]; unpack8(q0, f0);
        #pragma unroll
        for (int t = 0; t < 8; t++) acc[t] = fmaf(av0, f0[t], acc[t]);
    }

    float4* o4 = (float4*)(out + (size_t)d * NF + l * 8);
    float4 v0 = o4[0], v1 = o4[1];
    v0.x += acc[0]; v0.y += acc[1]; v0.z += acc[2]; v0.w += acc[3];
    v1.x += acc[4]; v1.y += acc[5]; v1.z += acc[6]; v1.w += acc[7];
    o4[0] = v0; o4[1] = v1;
}

// ---------------------------------------------------------------------------
// Fallbacks (small ws): R5 atomic edge kernel / fully fused.
// ---------------------------------------------------------------------------
__global__ __launch_bounds__(256) void edge_kernel(
    const int* __restrict__ edge, const int* __restrict__ flags,
    const unsigned short* __restrict__ g_src, const unsigned short* __restrict__ g_dst,
    const float* __restrict__ Wa1, const float* __restrict__ ba1,
    const float* __restrict__ Wa2, const float* __restrict__ ba2,
    float* __restrict__ out, int E, int N)
{
    __shared__ __align__(16) float sW1[NF * NHID];
    __shared__ __align__(16) float sW2[NHID * NH];
    __shared__ float sb1[NHID], sb2[NH];
    int tid = threadIdx.x;
    for (int i = tid; i < NF * NHID; i += 256) sW1[i] = Wa1[i];
    if (tid < NHID * NH) sW2[tid] = Wa2[tid];
    if (tid < NHID) sb1[tid] = ba1[tid];
    if (tid < NH) sb2[tid] = ba2[tid];
    __syncthreads();

    int e = blockIdx.x * 256 + tid;
    if (e >= E) return;
    int s, d;
    load_edge(edge, e, E, flags[0], s, d);
    if ((unsigned)s >= (unsigned)N || (unsigned)d >= (unsigned)N) return;

    float ms[NF];
    float hid[NHID];
    #pragma unroll
    for (int j = 0; j < NHID; j++) hid[j] = sb1[j];

    const uint4* gs = (const uint4*)(g_src + (size_t)s * NF);
    const uint4* gd = (const uint4*)(g_dst + (size_t)d * NF);
    #pragma unroll
    for (int k = 0; k < 8; k++) {
        float a8[8], b8[8];
        unpack8(gs[k], a8);
        unpack8(gd[k], b8);
        #pragma unroll
        for (int t = 0; t < 8; t++) {
            int i = k * 8 + t;
            ms[i] = a8[t];
            float x = leaky(a8[t] + b8[t]);
            #pragma unroll
            for (int j = 0; j < NHID; j++) hid[j] = fmaf(x, sW1[i * NHID + j], hid[j]);
        }
    }

    float a[NH];
    #pragma unroll
    for (int j = 0; j < NH; j++) a[j] = sb2[j];
    #pragma unroll
    for (int k = 0; k < NHID; k++) {
        float xk = leaky(hid[k]);
        #pragma unroll
        for (int j = 0; j < NH; j++) a[j] = fmaf(xk, sW2[k * NH + j], a[j]);
    }

    float* arow = out + (size_t)d * NF;
    #pragma unroll
    for (int hh = 0; hh < NH; hh++) {
        float ah = sigmoidf(a[hh]);
        #pragma unroll
        for (int dd = 0; dd < ND; dd++)
            unsafeAtomicAdd(arow + hh * ND + dd, ah * ms[hh * ND + dd]);
    }
}

__global__ __launch_bounds__(256) void edge_kernel_fused(
    const int* __restrict__ edge, const int* __restrict__ flags,
    const float* __restrict__ h,
    const float* __restrict__ W_src, const float* __restrict__ b_src,
    const float* __restrict__ W_dst, const float* __restrict__ b_dst,
    const float* __restrict__ Wa1, const float* __restrict__ ba1,
    const float* __restrict__ Wa2, const float* __restrict__ ba2,
    float* __restrict__ out, int E, int N)
{
    __shared__ __align__(16) float sWs[NF * NF];
    __shared__ __align__(16) float sWd[NF * NF];
    __shared__ __align__(16) float sW1[NF * NHID];
    __shared__ __align__(16) float sW2[NHID * NH];
    __shared__ float sbs[NF], sbd[NF], sb1[NHID], sb2[NH];
    int tid = threadIdx.x;
    for (int i = tid; i < NF * NF; i += 256) { sWs[i] = W_src[i]; sWd[i] = W_dst[i]; }
    for (int i = tid; i < NF * NHID; i += 256) sW1[i] = Wa1[i];
    if (tid < NHID * NH) sW2[tid] = Wa2[tid];
    if (tid < NF) { sbs[tid] = b_src[tid]; sbd[tid] = b_dst[tid]; }
    if (tid < NHID) sb1[tid] = ba1[tid];
    if (tid < NH) sb2[tid] = ba2[tid];
    __syncthreads();

    int e = blockIdx.x * 256 + tid;
    if (e >= E) return;
    int wide = flags ? flags[0] : 0;
    int s, d;
    load_edge(edge, e, E, wide, s, d);
    if ((unsigned)s >= (unsigned)N || (unsigned)d >= (unsigned)N) return;

    float gsr[NF], msg[NF];
    {
        float hrow[NF];
        #pragma unroll
        for (int i = 0; i < NF; i++) hrow[i] = h[(size_t)s * NF + i];
        #pragma unroll
        for (int j = 0; j < NF; j++) gsr[j] = sbs[j];
        for (int i = 0; i < NF; i++) {
            float hi = hrow[i];
            #pragma unroll
            for (int j = 0; j < NF; j++) gsr[j] = fmaf(hi, sWs[i * NF + j], gsr[j]);
        }
    }
    #pragma unroll
    for (int j = 0; j < NF; j++) msg[j] = gsr[j] + sbd[j];
    for (int i = 0; i < NF; i++) {
        float hi = h[(size_t)d * NF + i];
        #pragma unroll
        for (int j = 0; j < NF; j++) msg[j] = fmaf(hi, sWd[i * NF + j], msg[j]);
    }

    float hid[NHID];
    #pragma unroll
    for (int j = 0; j < NHID; j++) hid[j] = sb1[j];
    for (int i = 0; i < NF; i++) {
        float x = leaky(msg[i]);
        #pragma unroll
        for (int j = 0; j < NHID; j++) hid[j] = fmaf(x, sW1[i * NHID + j], hid[j]);
    }
    float a[NH];
    #pragma unroll
    for (int j = 0; j < NH; j++) a[j] = sb2[j];
    #pragma unroll
    for (int k = 0; k < NHID; k++) {
        float xk = leaky(hid[k]);
        #pragma unroll
        for (int j = 0; j < NH; j++) a[j] = fmaf(xk, sW2[k * NH + j], a[j]);
    }

    float* arow = out + (size_t)d * NF;
    #pragma unroll
    for (int hh = 0; hh < NH; hh++) {
        float ah = sigmoidf(a[hh]);
        #pragma unroll
        for (int dd = 0; dd < ND; dd++)
            unsafeAtomicAdd(arow + hh * ND + dd, ah * gsr[hh * ND + dd]);
    }
}

static inline size_t al256(size_t x) { return (x + 255) & ~(size_t)255; }

extern "C" void kernel_launch(void* const* d_in, const int* in_sizes, int n_in,
                              void* d_out, int out_size, void* d_ws, size_t ws_size,
                              hipStream_t stream) {
    const float* h       = (const float*)d_in[0];
    const float* W_src   = (const float*)d_in[1];
    const float* b_src   = (const float*)d_in[2];
    const float* W_dst   = (const float*)d_in[3];
    const float* b_dst   = (const float*)d_in[4];
    const float* Wa1_src = (const float*)d_in[5];
    const float* ba1_src = (const float*)d_in[6];
    const float* Wa2_src = (const float*)d_in[7];
    const float* ba2_src = (const float*)d_in[8];
    const float* Wa1_dst = (const float*)d_in[9];
    const float* ba1_dst = (const float*)d_in[10];
    const float* Wa2_dst = (const float*)d_in[11];
    const float* ba2_dst = (const float*)d_in[12];
    const int* edge = (const int*)d_in[13];

    int N = in_sizes[0] / NF;
    int E = in_sizes[13] / 2;
    float* out = (float*)d_out;

    int nodeBlocks = (N + 255) / 256;
    int edgeBlocks = (E + 255) / 256;
    int NB1 = (N + 2047) / 2048;

    // ws layout (sort path)
    size_t o_flags  = 0;
    size_t o_gsrc   = al256(o_flags + 256);
    size_t o_gdst   = al256(o_gsrc + (size_t)N * NF * 2);
    size_t o_asort  = al256(o_gdst + (size_t)N * NF * 2);
    size_t o_counts = al256(o_asort + (size_t)E * NH * 2);
    size_t o_offs   = al256(o_counts + (size_t)N * 4);
    size_t o_cursor = al256(o_offs + ((size_t)N + 1) * 4);
    size_t o_bsums  = al256(o_cursor + (size_t)N * 4);
    size_t o_sorted = al256(o_bsums + (size_t)NB1 * 4);
    size_t need     = o_sorted + (size_t)E * 8;

    size_t gB = (size_t)N * NF * 2;

    if (ws_size >= need) {
        char* w = (char*)d_ws;
        int*            flags   = (int*)(w + o_flags);
        unsigned short* g_src   = (unsigned short*)(w + o_gsrc);
        unsigned short* g_dst   = (unsigned short*)(w + o_gdst);
        __half*         a_sort  = (__half*)(w + o_asort);
        int*            counts  = (int*)(w + o_counts);
        int*            offsets = (int*)(w + o_offs);
        int*            cursor  = (int*)(w + o_cursor);
        int*            bsums   = (int*)(w + o_bsums);
        uint2*          sorted  = (uint2*)(w + o_sorted);

        detect_kernel<<<1, 1, 0, stream>>>(edge, flags);

        node_kernel_t<true><<<nodeBlocks, 256, 0, stream>>>(
            h, W_src, b_src, W_dst, b_dst,
            Wa1_dst, ba1_dst, Wa2_dst, ba2_dst,
            g_src, g_dst, out, counts, cursor, N);

        hist_kernel<<<edgeBlocks, 256, 0, stream>>>(edge, flags, counts, E, N);

        scan1_kernel<<<NB1, 256, 0, stream>>>(counts, offsets, bsums, N);
        scan2_kernel<<<1, 1, 0, stream>>>(bsums, offsets, NB1, N);
        scan3_kernel<<<NB1, 256, 0, stream>>>(offsets, bsums, N);

        scatter_kernel<<<edgeBlocks, 256, 0, stream>>>(
            edge, flags, offsets, cursor, sorted, E, N);

        edge_mlp_sorted_kernel<<<edgeBlocks, 256, 0, stream>>>(
            sorted, offsets + N, g_src, g_dst,
            Wa1_src, ba1_src, Wa2_src, ba2_src, a_sort);

        aggregate_kernel<<<(N + 31) / 32, 256, 0, stream>>>(
            offsets, sorted, a_sort, g_src, out, N);
    } else if (ws_size >= 256 + 2 * gB) {
        int* flags = (int*)d_ws;
        unsigned short* g_src = (unsigned short*)((char*)d_ws + 256);
        unsigned short* g_dst = g_src + (size_t)N * NF;

        detect_kernel<<<1, 1, 0, stream>>>(edge, flags);

        node_kernel_t<true><<<nodeBlocks, 256, 0, stream>>>(
            h, W_src, b_src, W_dst, b_dst,
            Wa1_dst, ba1_dst, Wa2_dst, ba2_dst,
            g_src, g_dst, out, nullptr, nullptr, N);

        edge_kernel<<<edgeBlocks, 256, 0, stream>>>(
            edge, flags, g_src, g_dst,
            Wa1_src, ba1_src, Wa2_src, ba2_src,
            out, E, N);
    } else {
        int* flags = (ws_size >= 256) ? (int*)d_ws : nullptr;
        if (flags) detect_kernel<<<1, 1, 0, stream>>>(edge, flags);

        node_kernel_t<false><<<nodeBlocks, 256, 0, stream>>>(
            h, W_src, b_src, W_dst, b_dst,
            Wa1_dst, ba1_dst, Wa2_dst, ba2_dst,
            nullptr, nullptr, out, nullptr, nullptr, N);

        edge_kernel_fused<<<edgeBlocks, 256, 0, stream>>>(
            edge, flags, h,
            W_src, b_src, W_dst, b_dst,
            Wa1_src, ba1_src, Wa2_src, ba2_src,
            out, E, N);
    }
}

// Round 10
// 390.744 us; speedup vs baseline: 9.9601x; 1.1526x over previous
//
#include <hip/hip_runtime.h>
#include <hip/hip_bf16.h>
#include <hip/hip_fp16.h>

#define NF   64
#define NH   8
#define ND   8
#define NHID 32
#define XS   68   // LDS row stride in shorts (64 data + 4 pad -> 136B, 8B-aligned, 2-way banks)

typedef __attribute__((ext_vector_type(8))) short bf16x8v;
typedef __attribute__((ext_vector_type(4))) float f32x4v;

__device__ __forceinline__ float bf2f(unsigned short u) {
    union { unsigned int i; float f; } v; v.i = ((unsigned int)u) << 16; return v.f;
}
__device__ __forceinline__ unsigned short f2bf(float f) {
    __hip_bfloat16 b = __float2bfloat16(f);
    union { __hip_bfloat16 b; unsigned short u; } v; v.b = b; return v.u;
}
__device__ __forceinline__ void unpack8(uint4 u, float* o) {
    o[0] = __uint_as_float(u.x << 16); o[1] = __uint_as_float(u.x & 0xffff0000u);
    o[2] = __uint_as_float(u.y << 16); o[3] = __uint_as_float(u.y & 0xffff0000u);
    o[4] = __uint_as_float(u.z << 16); o[5] = __uint_as_float(u.z & 0xffff0000u);
    o[6] = __uint_as_float(u.w << 16); o[7] = __uint_as_float(u.w & 0xffff0000u);
}
__device__ __forceinline__ uint4 pack8(const float* f) {
    uint4 u;
    u.x = (unsigned)f2bf(f[0]) | ((unsigned)f2bf(f[1]) << 16);
    u.y = (unsigned)f2bf(f[2]) | ((unsigned)f2bf(f[3]) << 16);
    u.z = (unsigned)f2bf(f[4]) | ((unsigned)f2bf(f[5]) << 16);
    u.w = (unsigned)f2bf(f[6]) | ((unsigned)f2bf(f[7]) << 16);
    return u;
}
__device__ __forceinline__ float leaky(float x) { return x > 0.f ? x : 0.2f * x; }
__device__ __forceinline__ float sigmoidf(float x) { return 1.f / (1.f + __expf(-x)); }

__global__ void detect_kernel(const int* __restrict__ edge, int* __restrict__ flags) {
    if (threadIdx.x == 0 && blockIdx.x == 0) {
        int oddnz = 0;
        for (int i = 0; i < 32; i++) oddnz |= edge[2 * i + 1];
        flags[0] = (oddnz == 0) ? 1 : 0;
    }
}

__device__ __forceinline__ void load_edge(const int* __restrict__ edge, int e, int E,
                                          int wide, int& s, int& d) {
    if (wide) { s = edge[2 * e]; d = edge[2 * (E + e)]; }
    else      { s = edge[e];     d = edge[E + e]; }
}

// ---------------------------------------------------------------------------
// Node phase (unchanged from R9).
// ---------------------------------------------------------------------------
template <bool STORE_G>
__global__ __launch_bounds__(256) void node_kernel_t(
    const float* __restrict__ h,
    const float* __restrict__ W_src, const float* __restrict__ b_src,
    const float* __restrict__ W_dst, const float* __restrict__ b_dst,
    const float* __restrict__ Wa1, const float* __restrict__ ba1,
    const float* __restrict__ Wa2, const float* __restrict__ ba2,
    unsigned short* __restrict__ g_src_out, unsigned short* __restrict__ g_dst_out,
    float* __restrict__ out, int* __restrict__ counts, int* __restrict__ cursor, int N)
{
    __shared__ __align__(16) float sWs[NF * NF];
    __shared__ __align__(16) float sWd[NF * NF];
    __shared__ __align__(16) float sW1[NF * NHID];
    __shared__ __align__(16) float sW2[NHID * NH];
    __shared__ float sbs[NF], sbd[NF], sb1[NHID], sb2[NH];

    int tid = threadIdx.x;
    for (int i = tid; i < NF * NF; i += 256) { sWs[i] = W_src[i]; sWd[i] = W_dst[i]; }
    for (int i = tid; i < NF * NHID; i += 256) sW1[i] = Wa1[i];
    if (tid < NHID * NH) sW2[tid] = Wa2[tid];
    if (tid < NF) { sbs[tid] = b_src[tid]; sbd[tid] = b_dst[tid]; }
    if (tid < NHID) sb1[tid] = ba1[tid];
    if (tid < NH) sb2[tid] = ba2[tid];
    __syncthreads();

    int n = blockIdx.x * 256 + tid;
    if (n >= N) return;

    if (counts) { counts[n] = 0; cursor[n] = 0; }

    float hrow[NF];
    const float4* hv = (const float4*)(h + (size_t)n * NF);
    #pragma unroll
    for (int k = 0; k < 16; k++) {
        float4 u = hv[k];
        hrow[k * 4 + 0] = u.x; hrow[k * 4 + 1] = u.y;
        hrow[k * 4 + 2] = u.z; hrow[k * 4 + 3] = u.w;
    }

    float acc[NF];
    const float4* Wsv = (const float4*)sWs;
    const float4* Wdv = (const float4*)sWd;

    if (STORE_G) {
        #pragma unroll
        for (int j = 0; j < NF; j++) acc[j] = sbs[j];
        for (int i = 0; i < NF; i++) {
            float hi = hrow[i];
            #pragma unroll
            for (int jb = 0; jb < 16; jb++) {
                float4 w = Wsv[i * 16 + jb];
                acc[jb * 4 + 0] = fmaf(hi, w.x, acc[jb * 4 + 0]);
                acc[jb * 4 + 1] = fmaf(hi, w.y, acc[jb * 4 + 1]);
                acc[jb * 4 + 2] = fmaf(hi, w.z, acc[jb * 4 + 2]);
                acc[jb * 4 + 3] = fmaf(hi, w.w, acc[jb * 4 + 3]);
            }
        }
        uint4* gs = (uint4*)(g_src_out + (size_t)n * NF);
        #pragma unroll
        for (int k = 0; k < 8; k++) gs[k] = pack8(acc + k * 8);
    }

    #pragma unroll
    for (int j = 0; j < NF; j++) acc[j] = sbd[j];
    for (int i = 0; i < NF; i++) {
        float hi = hrow[i];
        #pragma unroll
        for (int jb = 0; jb < 16; jb++) {
            float4 w = Wdv[i * 16 + jb];
            acc[jb * 4 + 0] = fmaf(hi, w.x, acc[jb * 4 + 0]);
            acc[jb * 4 + 1] = fmaf(hi, w.y, acc[jb * 4 + 1]);
            acc[jb * 4 + 2] = fmaf(hi, w.z, acc[jb * 4 + 2]);
            acc[jb * 4 + 3] = fmaf(hi, w.w, acc[jb * 4 + 3]);
        }
    }
    if (STORE_G) {
        uint4* gd = (uint4*)(g_dst_out + (size_t)n * NF);
        #pragma unroll
        for (int k = 0; k < 8; k++) gd[k] = pack8(acc + k * 8);
    }

    float hid[NHID];
    #pragma unroll
    for (int j = 0; j < NHID; j++) hid[j] = sb1[j];
    const float4* W1v = (const float4*)sW1;
    for (int i = 0; i < NF; i++) {
        float xi = leaky(acc[i]);
        #pragma unroll
        for (int jb = 0; jb < 8; jb++) {
            float4 w = W1v[i * 8 + jb];
            hid[jb * 4 + 0] = fmaf(xi, w.x, hid[jb * 4 + 0]);
            hid[jb * 4 + 1] = fmaf(xi, w.y, hid[jb * 4 + 1]);
            hid[jb * 4 + 2] = fmaf(xi, w.z, hid[jb * 4 + 2]);
            hid[jb * 4 + 3] = fmaf(xi, w.w, hid[jb * 4 + 3]);
        }
    }
    float a[NH];
    #pragma unroll
    for (int j = 0; j < NH; j++) a[j] = sb2[j];
    #pragma unroll
    for (int k = 0; k < NHID; k++) {
        float xk = leaky(hid[k]);
        #pragma unroll
        for (int j = 0; j < NH; j++) a[j] = fmaf(xk, sW2[k * NH + j], a[j]);
    }
    #pragma unroll
    for (int j = 0; j < NH; j++) a[j] = sigmoidf(a[j]);

    float4* ap = (float4*)(out + (size_t)n * NF);
    #pragma unroll
    for (int k = 0; k < 16; k++) {
        int j = k * 4;
        ap[k] = make_float4(a[(j + 0) >> 3] * acc[j + 0],
                            a[(j + 1) >> 3] * acc[j + 1],
                            a[(j + 2) >> 3] * acc[j + 2],
                            a[(j + 3) >> 3] * acc[j + 3]);
    }
}

__global__ __launch_bounds__(256) void hist_kernel(
    const int* __restrict__ edge, const int* __restrict__ flags,
    int* __restrict__ counts, int E, int N)
{
    int e = blockIdx.x * 256 + threadIdx.x;
    if (e >= E) return;
    int s, d;
    load_edge(edge, e, E, flags[0], s, d);
    if ((unsigned)s >= (unsigned)N || (unsigned)d >= (unsigned)N) return;
    atomicAdd(&counts[d], 1);
}

__global__ __launch_bounds__(256) void scan1_kernel(
    const int* __restrict__ counts, int* __restrict__ offsets,
    int* __restrict__ bsums, int N)
{
    __shared__ int lds[256];
    int tid = threadIdx.x;
    int base = blockIdx.x * 2048 + tid * 8;
    int v[8]; int s = 0;
    #pragma unroll
    for (int k = 0; k < 8; k++) { int idx = base + k; int t = (idx < N) ? counts[idx] : 0; v[k] = t; s += t; }
    lds[tid] = s;
    __syncthreads();
    for (int off = 1; off < 256; off <<= 1) {
        int y = (tid >= off) ? lds[tid - off] : 0;
        __syncthreads();
        lds[tid] += y;
        __syncthreads();
    }
    int run = lds[tid] - s;
    #pragma unroll
    for (int k = 0; k < 8; k++) { int idx = base + k; if (idx < N) offsets[idx] = run; run += v[k]; }
    if (tid == 255) bsums[blockIdx.x] = lds[255];
}

__global__ void scan2_kernel(int* __restrict__ bsums, int* __restrict__ offsets, int NB, int N) {
    if (threadIdx.x == 0 && blockIdx.x == 0) {
        int run = 0;
        for (int i = 0; i < NB; i++) { int t = bsums[i]; bsums[i] = run; run += t; }
        offsets[N] = run;
    }
}

__global__ __launch_bounds__(256) void scan3_kernel(
    int* __restrict__ offsets, const int* __restrict__ bsums, int N)
{
    int add = bsums[blockIdx.x];
    int base = blockIdx.x * 2048 + threadIdx.x * 8;
    #pragma unroll
    for (int k = 0; k < 8; k++) { int idx = base + k; if (idx < N) offsets[idx] += add; }
}

__global__ __launch_bounds__(256) void scatter_kernel(
    const int* __restrict__ edge, const int* __restrict__ flags,
    const int* __restrict__ offsets, int* __restrict__ cursor,
    uint2* __restrict__ sorted_sd, int E, int N)
{
    int e = blockIdx.x * 256 + threadIdx.x;
    if (e >= E) return;
    int s, d;
    load_edge(edge, e, E, flags[0], s, d);
    if ((unsigned)s >= (unsigned)N || (unsigned)d >= (unsigned)N) return;
    int pos = offsets[d] + atomicAdd(&cursor[d], 1);
    sorted_sd[pos] = make_uint2((unsigned)s, (unsigned)d);
}

// ---------------------------------------------------------------------------
// Edge MLP via MFMA. Per wave: 64 sorted slots. Lanes stage x=leaky(gs+gd)
// rows (bf16) into LDS; layer 1 (64x64 @ 64x32) via 16 mfma_f32_16x16x32_bf16;
// bias+leaky back to LDS (C-layout: col=lane&15, row=quad*4+reg); layer 2
// (32->8) scalar per lane; sigmoid -> fp16x8 store at the slot index.
// ---------------------------------------------------------------------------
__global__ __launch_bounds__(256) void edge_mlp_mfma_kernel(
    const uint2* __restrict__ sorted_sd, const int* __restrict__ total_p,
    const unsigned short* __restrict__ g_src, const unsigned short* __restrict__ g_dst,
    const float* __restrict__ Wa1, const float* __restrict__ ba1,
    const float* __restrict__ Wa2, const float* __restrict__ ba2,
    __half* __restrict__ a_sorted)
{
    __shared__ __align__(16) unsigned short sX[4 * 64 * XS];  // 34.8 KB, reused for H
    __shared__ __align__(16) float sW2[NHID * NH];
    __shared__ float sb1[NHID], sb2[NH];

    int tid = threadIdx.x;
    if (tid < NHID * NH) sW2[tid] = Wa2[tid];
    if (tid < NHID) sb1[tid] = ba1[tid];
    if (tid < NH) sb2[tid] = ba2[tid];

    int wave = tid >> 6;
    int lane = tid & 63;
    int nsub = lane & 15;
    int quad = lane >> 4;
    int total = *total_p;
    int i = blockIdx.x * 256 + wave * 64 + lane;
    bool valid = i < total;
    uint2 sd = valid ? sorted_sd[i] : make_uint2(0u, 0u);

    // ---- phase 1: x rows -> LDS ----
    unsigned short* xrow = sX + (wave * 64 + lane) * XS;
    {
        const uint4* gs = (const uint4*)(g_src + (size_t)sd.x * NF);
        const uint4* gd = (const uint4*)(g_dst + (size_t)sd.y * NF);
        #pragma unroll
        for (int k = 0; k < 8; k++) {
            float A8[8], B8[8], x8[8];
            unpack8(gs[k], A8); unpack8(gd[k], B8);
            #pragma unroll
            for (int t = 0; t < 8; t++) x8[t] = leaky(A8[t] + B8[t]);
            uint4 pk = pack8(x8);
            uint2* q = (uint2*)(xrow + k * 8);     // 8B-aligned
            q[0] = make_uint2(pk.x, pk.y);
            q[1] = make_uint2(pk.z, pk.w);
        }
    }

    // ---- W1 B-fragments: B[k][n], lane holds n=nsub(+16*nt), k=quad*8+j (+32*ks)
    bf16x8v Bf[2][2];
    #pragma unroll
    for (int ks = 0; ks < 2; ks++) {
        #pragma unroll
        for (int nt = 0; nt < 2; nt++) {
            union { unsigned short s[8]; bf16x8v v; } u;
            #pragma unroll
            for (int j = 0; j < 8; j++) {
                int k = ks * 32 + quad * 8 + j;
                int n = nt * 16 + nsub;
                u.s[j] = f2bf(Wa1[k * NHID + n]);
            }
            Bf[ks][nt] = u.v;
        }
    }

    __syncthreads();   // X rows visible (also covers sW2/sb1/sb2 staging)

    // ---- layer 1 MFMAs ----
    f32x4v acc[4][2];
    #pragma unroll
    for (int mt = 0; mt < 4; mt++)
        #pragma unroll
        for (int nt = 0; nt < 2; nt++) {
            f32x4v z = {0.f, 0.f, 0.f, 0.f};
            acc[mt][nt] = z;
        }

    const unsigned short* wbase = sX + wave * 64 * XS;
    #pragma unroll
    for (int ks = 0; ks < 2; ks++) {
        #pragma unroll
        for (int mt = 0; mt < 4; mt++) {
            const unsigned short* ap = wbase + (mt * 16 + nsub) * XS + ks * 32 + quad * 8;
            union { uint2 d[2]; bf16x8v v; } ua;
            ua.d[0] = *(const uint2*)ap;
            ua.d[1] = *(const uint2*)(ap + 4);
            #pragma unroll
            for (int nt = 0; nt < 2; nt++)
                acc[mt][nt] = __builtin_amdgcn_mfma_f32_16x16x32_bf16(
                    ua.v, Bf[ks][nt], acc[mt][nt], 0, 0, 0);
        }
    }

    __syncthreads();   // all X reads done before H overwrites the region

    // ---- bias + leaky -> H (bf16) in C-layout ----
    #pragma unroll
    for (int nt = 0; nt < 2; nt++) {
        int n = nt * 16 + nsub;
        float b1v = sb1[n];
        #pragma unroll
        for (int mt = 0; mt < 4; mt++) {
            #pragma unroll
            for (int r = 0; r < 4; r++) {
                int m = mt * 16 + quad * 4 + r;
                sX[(wave * 64 + m) * XS + n] = f2bf(leaky(acc[mt][nt][r] + b1v));
            }
        }
    }

    __syncthreads();   // H visible

    // ---- layer 2 scalar: a = sigmoid(H_row @ W2 + b2) ----
    float hid[NHID];
    const unsigned short* hrow = wbase + lane * XS;
    #pragma unroll
    for (int k = 0; k < 8; k++) {
        uint2 dv = *(const uint2*)(hrow + k * 4);
        hid[k * 4 + 0] = bf2f((unsigned short)(dv.x & 0xffffu));
        hid[k * 4 + 1] = bf2f((unsigned short)(dv.x >> 16));
        hid[k * 4 + 2] = bf2f((unsigned short)(dv.y & 0xffffu));
        hid[k * 4 + 3] = bf2f((unsigned short)(dv.y >> 16));
    }
    float a[NH];
    #pragma unroll
    for (int j = 0; j < NH; j++) a[j] = sb2[j];
    #pragma unroll
    for (int k = 0; k < NHID; k++) {
        float xk = hid[k];  // leaky already applied
        #pragma unroll
        for (int j = 0; j < NH; j++) a[j] = fmaf(xk, sW2[k * NH + j], a[j]);
    }

    if (valid) {
        union { __half h[8]; uint4 u; } pk;
        #pragma unroll
        for (int j = 0; j < NH; j++) pk.h[j] = __float2half(sigmoidf(a[j]));
        *(uint4*)(a_sorted + (size_t)i * NH) = pk.u;
    }
}

// ---------------------------------------------------------------------------
// Aggregate v2 (unchanged from R9).
// ---------------------------------------------------------------------------
__global__ __launch_bounds__(256) void aggregate_kernel(
    const int* __restrict__ offsets, const uint2* __restrict__ sorted_sd,
    const __half* __restrict__ a_sorted, const unsigned short* __restrict__ g_src,
    float* __restrict__ out, int N)
{
    int d = blockIdx.x * 32 + (threadIdx.x >> 3);
    if (d >= N) return;
    int l = threadIdx.x & 7;
    int beg = offsets[d], end = offsets[d + 1];

    float acc[8] = {0.f, 0.f, 0.f, 0.f, 0.f, 0.f, 0.f, 0.f};
    int i = beg;
    for (; i + 2 <= end; i += 2) {
        unsigned s0 = sorted_sd[i].x;
        unsigned s1 = sorted_sd[i + 1].x;
        float av0 = __half2float(a_sorted[(size_t)i * NH + l]);
        float av1 = __half2float(a_sorted[(size_t)(i + 1) * NH + l]);
        uint4 q0 = *(const uint4*)(g_src + (size_t)s0 * NF + l * 8);
        uint4 q1 = *(const uint4*)(g_src + (size_t)s1 * NF + l * 8);
        float f0[8], f1[8];
        unpack8(q0, f0); unpack8(q1, f1);
        #pragma unroll
        for (int t = 0; t < 8; t++) acc[t] = fmaf(av0, f0[t], acc[t]);
        #pragma unroll
        for (int t = 0; t < 8; t++) acc[t] = fmaf(av1, f1[t], acc[t]);
    }
    if (i < end) {
        unsigned s0 = sorted_sd[i].x;
        float av0 = __half2float(a_sorted[(size_t)i * NH + l]);
        uint4 q0 = *(const uint4*)(g_src + (size_t)s0 * NF + l * 8);
        float f0[8]; unpack8(q0, f0);
        #pragma unroll
        for (int t = 0; t < 8; t++) acc[t] = fmaf(av0, f0[t], acc[t]);
    }

    float4* o4 = (float4*)(out + (size_t)d * NF + l * 8);
    float4 v0 = o4[0], v1 = o4[1];
    v0.x += acc[0]; v0.y += acc[1]; v0.z += acc[2]; v0.w += acc[3];
    v1.x += acc[4]; v1.y += acc[5]; v1.z += acc[6]; v1.w += acc[7];
    o4[0] = v0; o4[1] = v1;
}

// ---------------------------------------------------------------------------
// Fallbacks (small ws): R5 atomic edge kernel / fully fused.
// ---------------------------------------------------------------------------
__global__ __launch_bounds__(256) void edge_kernel(
    const int* __restrict__ edge, const int* __restrict__ flags,
    const unsigned short* __restrict__ g_src, const unsigned short* __restrict__ g_dst,
    const float* __restrict__ Wa1, const float* __restrict__ ba1,
    const float* __restrict__ Wa2, const float* __restrict__ ba2,
    float* __restrict__ out, int E, int N)
{
    __shared__ __align__(16) float sW1[NF * NHID];
    __shared__ __align__(16) float sW2[NHID * NH];
    __shared__ float sb1[NHID], sb2[NH];
    int tid = threadIdx.x;
    for (int i = tid; i < NF * NHID; i += 256) sW1[i] = Wa1[i];
    if (tid < NHID * NH) sW2[tid] = Wa2[tid];
    if (tid < NHID) sb1[tid] = ba1[tid];
    if (tid < NH) sb2[tid] = ba2[tid];
    __syncthreads();

    int e = blockIdx.x * 256 + tid;
    if (e >= E) return;
    int s, d;
    load_edge(edge, e, E, flags[0], s, d);
    if ((unsigned)s >= (unsigned)N || (unsigned)d >= (unsigned)N) return;

    float ms[NF];
    float hid[NHID];
    #pragma unroll
    for (int j = 0; j < NHID; j++) hid[j] = sb1[j];

    const uint4* gs = (const uint4*)(g_src + (size_t)s * NF);
    const uint4* gd = (const uint4*)(g_dst + (size_t)d * NF);
    #pragma unroll
    for (int k = 0; k < 8; k++) {
        float a8[8], b8[8];
        unpack8(gs[k], a8);
        unpack8(gd[k], b8);
        #pragma unroll
        for (int t = 0; t < 8; t++) {
            int i = k * 8 + t;
            ms[i] = a8[t];
            float x = leaky(a8[t] + b8[t]);
            #pragma unroll
            for (int j = 0; j < NHID; j++) hid[j] = fmaf(x, sW1[i * NHID + j], hid[j]);
        }
    }

    float a[NH];
    #pragma unroll
    for (int j = 0; j < NH; j++) a[j] = sb2[j];
    #pragma unroll
    for (int k = 0; k < NHID; k++) {
        float xk = leaky(hid[k]);
        #pragma unroll
        for (int j = 0; j < NH; j++) a[j] = fmaf(xk, sW2[k * NH + j], a[j]);
    }

    float* arow = out + (size_t)d * NF;
    #pragma unroll
    for (int hh = 0; hh < NH; hh++) {
        float ah = sigmoidf(a[hh]);
        #pragma unroll
        for (int dd = 0; dd < ND; dd++)
            unsafeAtomicAdd(arow + hh * ND + dd, ah * ms[hh * ND + dd]);
    }
}

__global__ __launch_bounds__(256) void edge_kernel_fused(
    const int* __restrict__ edge, const int* __restrict__ flags,
    const float* __restrict__ h,
    const float* __restrict__ W_src, const float* __restrict__ b_src,
    const float* __restrict__ W_dst, const float* __restrict__ b_dst,
    const float* __restrict__ Wa1, const float* __restrict__ ba1,
    const float* __restrict__ Wa2, const float* __restrict__ ba2,
    float* __restrict__ out, int E, int N)
{
    __shared__ __align__(16) float sWs[NF * NF];
    __shared__ __align__(16) float sWd[NF * NF];
    __shared__ __align__(16) float sW1[NF * NHID];
    __shared__ __align__(16) float sW2[NHID * NH];
    __shared__ float sbs[NF], sbd[NF], sb1[NHID], sb2[NH];
    int tid = threadIdx.x;
    for (int i = tid; i < NF * NF; i += 256) { sWs[i] = W_src[i]; sWd[i] = W_dst[i]; }
    for (int i = tid; i < NF * NHID; i += 256) sW1[i] = Wa1[i];
    if (tid < NHID * NH) sW2[tid] = Wa2[tid];
    if (tid < NF) { sbs[tid] = b_src[tid]; sbd[tid] = b_dst[tid]; }
    if (tid < NHID) sb1[tid] = ba1[tid];
    if (tid < NH) sb2[tid] = ba2[tid];
    __syncthreads();

    int e = blockIdx.x * 256 + tid;
    if (e >= E) return;
    int wide = flags ? flags[0] : 0;
    int s, d;
    load_edge(edge, e, E, wide, s, d);
    if ((unsigned)s >= (unsigned)N || (unsigned)d >= (unsigned)N) return;

    float gsr[NF], msg[NF];
    {
        float hrow[NF];
        #pragma unroll
        for (int i = 0; i < NF; i++) hrow[i] = h[(size_t)s * NF + i];
        #pragma unroll
        for (int j = 0; j < NF; j++) gsr[j] = sbs[j];
        for (int i = 0; i < NF; i++) {
            float hi = hrow[i];
            #pragma unroll
            for (int j = 0; j < NF; j++) gsr[j] = fmaf(hi, sWs[i * NF + j], gsr[j]);
        }
    }
    #pragma unroll
    for (int j = 0; j < NF; j++) msg[j] = gsr[j] + sbd[j];
    for (int i = 0; i < NF; i++) {
        float hi = h[(size_t)d * NF + i];
        #pragma unroll
        for (int j = 0; j < NF; j++) msg[j] = fmaf(hi, sWd[i * NF + j], msg[j]);
    }

    float hid[NHID];
    #pragma unroll
    for (int j = 0; j < NHID; j++) hid[j] = sb1[j];
    for (int i = 0; i < NF; i++) {
        float x = leaky(msg[i]);
        #pragma unroll
        for (int j = 0; j < NHID; j++) hid[j] = fmaf(x, sW1[i * NHID + j], hid[j]);
    }
    float a[NH];
    #pragma unroll
    for (int j = 0; j < NH; j++) a[j] = sb2[j];
    #pragma unroll
    for (int k = 0; k < NHID; k++) {
        float xk = leaky(hid[k]);
        #pragma unroll
        for (int j = 0; j < NH; j++) a[j] = fmaf(xk, sW2[k * NH + j], a[j]);
    }

    float* arow = out + (size_t)d * NF;
    #pragma unroll
    for (int hh = 0; hh < NH; hh++) {
        float ah = sigmoidf(a[hh]);
        #pragma unroll
        for (int dd = 0; dd < ND; dd++)
            unsafeAtomicAdd(arow + hh * ND + dd, ah * gsr[hh * ND + dd]);
    }
}

static inline size_t al256(size_t x) { return (x + 255) & ~(size_t)255; }

extern "C" void kernel_launch(void* const* d_in, const int* in_sizes, int n_in,
                              void* d_out, int out_size, void* d_ws, size_t ws_size,
                              hipStream_t stream) {
    const float* h       = (const float*)d_in[0];
    const float* W_src   = (const float*)d_in[1];
    const float* b_src   = (const float*)d_in[2];
    const float* W_dst   = (const float*)d_in[3];
    const float* b_dst   = (const float*)d_in[4];
    const float* Wa1_src = (const float*)d_in[5];
    const float* ba1_src = (const float*)d_in[6];
    const float* Wa2_src = (const float*)d_in[7];
    const float* ba2_src = (const float*)d_in[8];
    const float* Wa1_dst = (const float*)d_in[9];
    const float* ba1_dst = (const float*)d_in[10];
    const float* Wa2_dst = (const float*)d_in[11];
    const float* ba2_dst = (const float*)d_in[12];
    const int* edge = (const int*)d_in[13];

    int N = in_sizes[0] / NF;
    int E = in_sizes[13] / 2;
    float* out = (float*)d_out;

    int nodeBlocks = (N + 255) / 256;
    int edgeBlocks = (E + 255) / 256;
    int NB1 = (N + 2047) / 2048;

    size_t o_flags  = 0;
    size_t o_gsrc   = al256(o_flags + 256);
    size_t o_gdst   = al256(o_gsrc + (size_t)N * NF * 2);
    size_t o_asort  = al256(o_gdst + (size_t)N * NF * 2);
    size_t o_counts = al256(o_asort + (size_t)E * NH * 2);
    size_t o_offs   = al256(o_counts + (size_t)N * 4);
    size_t o_cursor = al256(o_offs + ((size_t)N + 1) * 4);
    size_t o_bsums  = al256(o_cursor + (size_t)N * 4);
    size_t o_sorted = al256(o_bsums + (size_t)NB1 * 4);
    size_t need     = o_sorted + (size_t)E * 8;

    size_t gB = (size_t)N * NF * 2;

    if (ws_size >= need) {
        char* w = (char*)d_ws;
        int*            flags   = (int*)(w + o_flags);
        unsigned short* g_src   = (unsigned short*)(w + o_gsrc);
        unsigned short* g_dst   = (unsigned short*)(w + o_gdst);
        __half*         a_sort  = (__half*)(w + o_asort);
        int*            counts  = (int*)(w + o_counts);
        int*            offsets = (int*)(w + o_offs);
        int*            cursor  = (int*)(w + o_cursor);
        int*            bsums   = (int*)(w + o_bsums);
        uint2*          sorted  = (uint2*)(w + o_sorted);

        detect_kernel<<<1, 1, 0, stream>>>(edge, flags);

        node_kernel_t<true><<<nodeBlocks, 256, 0, stream>>>(
            h, W_src, b_src, W_dst, b_dst,
            Wa1_dst, ba1_dst, Wa2_dst, ba2_dst,
            g_src, g_dst, out, counts, cursor, N);

        hist_kernel<<<edgeBlocks, 256, 0, stream>>>(edge, flags, counts, E, N);

        scan1_kernel<<<NB1, 256, 0, stream>>>(counts, offsets, bsums, N);
        scan2_kernel<<<1, 1, 0, stream>>>(bsums, offsets, NB1, N);
        scan3_kernel<<<NB1, 256, 0, stream>>>(offsets, bsums, N);

        scatter_kernel<<<edgeBlocks, 256, 0, stream>>>(
            edge, flags, offsets, cursor, sorted, E, N);

        edge_mlp_mfma_kernel<<<edgeBlocks, 256, 0, stream>>>(
            sorted, offsets + N, g_src, g_dst,
            Wa1_src, ba1_src, Wa2_src, ba2_src, a_sort);

        aggregate_kernel<<<(N + 31) / 32, 256, 0, stream>>>(
            offsets, sorted, a_sort, g_src, out, N);
    } else if (ws_size >= 256 + 2 * gB) {
        int* flags = (int*)d_ws;
        unsigned short* g_src = (unsigned short*)((char*)d_ws + 256);
        unsigned short* g_dst = g_src + (size_t)N * NF;

        detect_kernel<<<1, 1, 0, stream>>>(edge, flags);

        node_kernel_t<true><<<nodeBlocks, 256, 0, stream>>>(
            h, W_src, b_src, W_dst, b_dst,
            Wa1_dst, ba1_dst, Wa2_dst, ba2_dst,
            g_src, g_dst, out, nullptr, nullptr, N);

        edge_kernel<<<edgeBlocks, 256, 0, stream>>>(
            edge, flags, g_src, g_dst,
            Wa1_src, ba1_src, Wa2_src, ba2_src,
            out, E, N);
    } else {
        int* flags = (ws_size >= 256) ? (int*)d_ws : nullptr;
        if (flags) detect_kernel<<<1, 1, 0, stream>>>(edge, flags);

        node_kernel_t<false><<<nodeBlocks, 256, 0, stream>>>(
            h, W_src, b_src, W_dst, b_dst,
            Wa1_dst, ba1_dst, Wa2_dst, ba2_dst,
            nullptr, nullptr, out, nullptr, nullptr, N);

        edge_kernel_fused<<<edgeBlocks, 256, 0, stream>>>(
            edge, flags, h,
            W_src, b_src, W_dst, b_dst,
            Wa1_src, ba1_src, Wa2_src, ba2_src,
            out, E, N);
    }
}

// Round 11
// 341.320 us; speedup vs baseline: 11.4024x; 1.1448x over previous
//
#include <hip/hip_runtime.h>
#include <hip/hip_bf16.h>
#include <hip/hip_fp16.h>

#define NF   64
#define NH   8
#define ND   8
#define NHID 32
#define XS   68   // LDS row stride in shorts (136B: 8B-aligned, 2-way banks at worst)

typedef __attribute__((ext_vector_type(8))) short bf16x8v;
typedef __attribute__((ext_vector_type(4))) float f32x4v;

__device__ __forceinline__ float bf2f(unsigned short u) {
    union { unsigned int i; float f; } v; v.i = ((unsigned int)u) << 16; return v.f;
}
__device__ __forceinline__ unsigned short f2bf(float f) {
    __hip_bfloat16 b = __float2bfloat16(f);
    union { __hip_bfloat16 b; unsigned short u; } v; v.b = b; return v.u;
}
__device__ __forceinline__ void unpack8(uint4 u, float* o) {
    o[0] = __uint_as_float(u.x << 16); o[1] = __uint_as_float(u.x & 0xffff0000u);
    o[2] = __uint_as_float(u.y << 16); o[3] = __uint_as_float(u.y & 0xffff0000u);
    o[4] = __uint_as_float(u.z << 16); o[5] = __uint_as_float(u.z & 0xffff0000u);
    o[6] = __uint_as_float(u.w << 16); o[7] = __uint_as_float(u.w & 0xffff0000u);
}
__device__ __forceinline__ uint4 pack8(const float* f) {
    uint4 u;
    u.x = (unsigned)f2bf(f[0]) | ((unsigned)f2bf(f[1]) << 16);
    u.y = (unsigned)f2bf(f[2]) | ((unsigned)f2bf(f[3]) << 16);
    u.z = (unsigned)f2bf(f[4]) | ((unsigned)f2bf(f[5]) << 16);
    u.w = (unsigned)f2bf(f[6]) | ((unsigned)f2bf(f[7]) << 16);
    return u;
}
__device__ __forceinline__ float leaky(float x) { return x > 0.f ? x : 0.2f * x; }
__device__ __forceinline__ float sigmoidf(float x) { return 1.f / (1.f + __expf(-x)); }

__global__ void detect_kernel(const int* __restrict__ edge, int* __restrict__ flags) {
    if (threadIdx.x == 0 && blockIdx.x == 0) {
        int oddnz = 0;
        for (int i = 0; i < 32; i++) oddnz |= edge[2 * i + 1];
        flags[0] = (oddnz == 0) ? 1 : 0;
    }
}

__device__ __forceinline__ void load_edge(const int* __restrict__ edge, int e, int E,
                                          int wide, int& s, int& d) {
    if (wide) { s = edge[2 * e]; d = edge[2 * (E + e)]; }
    else      { s = edge[e];     d = edge[E + e]; }
}

// ---------------------------------------------------------------------------
// Node phase via MFMA: one wave per 64 nodes. h rows staged bf16 in LDS,
// g = h@W + b via 16x16x32 MFMAs (layouts verified by the edge kernel),
// raw g kept in LDS for the global store / base term; MLP layer1 via MFMA
// (leaky applied on A-load), layer2 + sigmoid scalar; base a_dst*g_dst -> out.
// ---------------------------------------------------------------------------
__global__ __launch_bounds__(64) void node_mfma_kernel(
    const float* __restrict__ h,
    const float* __restrict__ W_src, const float* __restrict__ b_src,
    const float* __restrict__ W_dst, const float* __restrict__ b_dst,
    const float* __restrict__ Wa1, const float* __restrict__ ba1,
    const float* __restrict__ Wa2, const float* __restrict__ ba2,
    unsigned short* __restrict__ g_src_out, unsigned short* __restrict__ g_dst_out,
    float* __restrict__ out, int* __restrict__ counts, int* __restrict__ cursor, int N)
{
    __shared__ __align__(16) unsigned short sX[64 * XS];  // h rows, later hid
    __shared__ __align__(16) unsigned short sY[64 * XS];  // g rows (raw)
    __shared__ float sW2[NHID * NH];
    __shared__ float sb2[NH];

    int lane = threadIdx.x;
    int nsub = lane & 15, quad = lane >> 4;
    int base = blockIdx.x * 64;
    int n = base + lane;
    bool valid = n < N;
    size_t nn = valid ? (size_t)n : (size_t)(N - 1);

    if (valid) { counts[n] = 0; cursor[n] = 0; }
    for (int i = lane; i < NHID * NH; i += 64) sW2[i] = Wa2[i];
    if (lane < NH) sb2[lane] = ba2[lane];

    // stage h row (fp32 -> bf16) into sX
    {
        const float4* hv = (const float4*)(h + nn * NF);
        unsigned short* xrow = sX + lane * XS;
        #pragma unroll
        for (int k = 0; k < 8; k++) {
            float4 u0 = hv[2 * k], u1 = hv[2 * k + 1];
            float f[8] = { u0.x, u0.y, u0.z, u0.w, u1.x, u1.y, u1.z, u1.w };
            uint4 p = pack8(f);
            uint2* q = (uint2*)(xrow + k * 8);
            q[0] = make_uint2(p.x, p.y);
            q[1] = make_uint2(p.z, p.w);
        }
    }
    __syncthreads();

    // ---- two 64x64 transforms: m=0 -> g_src, m=1 -> g_dst ----
    #pragma unroll 1
    for (int m = 0; m < 2; m++) {
        const float* W  = m ? W_dst : W_src;
        const float* bb = m ? b_dst : b_src;
        unsigned short* gout = m ? g_dst_out : g_src_out;

        bf16x8v Bf[2][4];   // [ks][nt]: B[k][n], n=nt*16+nsub, k=ks*32+quad*8+j
        #pragma unroll
        for (int ks = 0; ks < 2; ks++)
            #pragma unroll
            for (int nt = 0; nt < 4; nt++) {
                union { unsigned short s[8]; bf16x8v v; } u;
                #pragma unroll
                for (int j = 0; j < 8; j++)
                    u.s[j] = f2bf(W[(ks * 32 + quad * 8 + j) * NF + nt * 16 + nsub]);
                Bf[ks][nt] = u.v;
            }

        f32x4v acc[4][4];
        #pragma unroll
        for (int mt = 0; mt < 4; mt++)
            #pragma unroll
            for (int nt = 0; nt < 4; nt++) {
                f32x4v z = {0.f, 0.f, 0.f, 0.f};
                acc[mt][nt] = z;
            }

        #pragma unroll
        for (int ks = 0; ks < 2; ks++)
            #pragma unroll
            for (int mt = 0; mt < 4; mt++) {
                const unsigned short* ap = sX + (mt * 16 + nsub) * XS + ks * 32 + quad * 8;
                union { uint2 d[2]; bf16x8v v; } ua;
                ua.d[0] = *(const uint2*)ap;
                ua.d[1] = *(const uint2*)(ap + 4);
                #pragma unroll
                for (int nt = 0; nt < 4; nt++)
                    acc[mt][nt] = __builtin_amdgcn_mfma_f32_16x16x32_bf16(
                        ua.v, Bf[ks][nt], acc[mt][nt], 0, 0, 0);
            }

        if (m == 1) __syncthreads();   // g_src row-reads of sY done before overwrite

        // C-layout (col=lane&15, row=quad*4+reg) + bias -> sY raw bf16
        #pragma unroll
        for (int nt = 0; nt < 4; nt++) {
            float bv = bb[nt * 16 + nsub];
            #pragma unroll
            for (int mt = 0; mt < 4; mt++)
                #pragma unroll
                for (int r = 0; r < 4; r++)
                    sY[(mt * 16 + quad * 4 + r) * XS + nt * 16 + nsub] =
                        f2bf(acc[mt][nt][r] + bv);
        }
        __syncthreads();

        if (valid) {
            const unsigned short* yrow = sY + lane * XS;
            uint4* gp = (uint4*)(gout + (size_t)n * NF);
            #pragma unroll
            for (int k = 0; k < 8; k++) {
                uint2 a = *(const uint2*)(yrow + k * 8);
                uint2 b = *(const uint2*)(yrow + k * 8 + 4);
                gp[k] = make_uint4(a.x, a.y, b.x, b.y);
            }
        }
    }
    // sY now holds raw g_dst rows.

    // ---- MLP layer 1 via MFMA: A = leaky(g_dst), B = W1 [64x32] ----
    bf16x8v B1f[2][2];
    #pragma unroll
    for (int ks = 0; ks < 2; ks++)
        #pragma unroll
        for (int nt = 0; nt < 2; nt++) {
            union { unsigned short s[8]; bf16x8v v; } u;
            #pragma unroll
            for (int j = 0; j < 8; j++)
                u.s[j] = f2bf(Wa1[(ks * 32 + quad * 8 + j) * NHID + nt * 16 + nsub]);
            B1f[ks][nt] = u.v;
        }

    f32x4v acc2[4][2];
    #pragma unroll
    for (int mt = 0; mt < 4; mt++)
        #pragma unroll
        for (int nt = 0; nt < 2; nt++) {
            f32x4v z = {0.f, 0.f, 0.f, 0.f};
            acc2[mt][nt] = z;
        }

    #pragma unroll
    for (int ks = 0; ks < 2; ks++)
        #pragma unroll
        for (int mt = 0; mt < 4; mt++) {
            const unsigned short* ap = sY + (mt * 16 + nsub) * XS + ks * 32 + quad * 8;
            uint2 d0 = *(const uint2*)ap;
            uint2 d1 = *(const uint2*)(ap + 4);
            float f[8];
            unpack8(make_uint4(d0.x, d0.y, d1.x, d1.y), f);
            #pragma unroll
            for (int t = 0; t < 8; t++) f[t] = leaky(f[t]);
            uint4 p = pack8(f);
            union { uint4 u; bf16x8v v; } ua; ua.u = p;
            #pragma unroll
            for (int nt = 0; nt < 2; nt++)
                acc2[mt][nt] = __builtin_amdgcn_mfma_f32_16x16x32_bf16(
                    ua.v, B1f[ks][nt], acc2[mt][nt], 0, 0, 0);
        }
    __syncthreads();   // all sX reads (none remain) / ensure ordering before hid writes

    // hid = leaky(acc2 + b1) -> sX cols 0..31
    #pragma unroll
    for (int nt = 0; nt < 2; nt++) {
        float b1v = ba1[nt * 16 + nsub];
        #pragma unroll
        for (int mt = 0; mt < 4; mt++)
            #pragma unroll
            for (int r = 0; r < 4; r++)
                sX[(mt * 16 + quad * 4 + r) * XS + nt * 16 + nsub] =
                    f2bf(leaky(acc2[mt][nt][r] + b1v));
    }
    __syncthreads();

    // ---- layer 2 scalar + base term ----
    if (valid) {
        float hid[NHID];
        const unsigned short* hrow = sX + lane * XS;
        #pragma unroll
        for (int k = 0; k < 8; k++) {
            uint2 dv = *(const uint2*)(hrow + k * 4);
            hid[k * 4 + 0] = bf2f((unsigned short)(dv.x & 0xffffu));
            hid[k * 4 + 1] = bf2f((unsigned short)(dv.x >> 16));
            hid[k * 4 + 2] = bf2f((unsigned short)(dv.y & 0xffffu));
            hid[k * 4 + 3] = bf2f((unsigned short)(dv.y >> 16));
        }
        float a[NH];
        #pragma unroll
        for (int j = 0; j < NH; j++) a[j] = sb2[j];
        #pragma unroll
        for (int k = 0; k < NHID; k++) {
            float xk = hid[k];
            #pragma unroll
            for (int j = 0; j < NH; j++) a[j] = fmaf(xk, sW2[k * NH + j], a[j]);
        }
        #pragma unroll
        for (int j = 0; j < NH; j++) a[j] = sigmoidf(a[j]);

        const unsigned short* yrow = sY + lane * XS;
        float4* op = (float4*)(out + (size_t)n * NF);
        #pragma unroll
        for (int k = 0; k < 8; k++) {
            uint2 u0 = *(const uint2*)(yrow + k * 8);
            uint2 u1 = *(const uint2*)(yrow + k * 8 + 4);
            float g[8];
            unpack8(make_uint4(u0.x, u0.y, u1.x, u1.y), g);
            float ah0 = a[(k * 8) >> 3];
            op[2 * k]     = make_float4(ah0 * g[0], ah0 * g[1], ah0 * g[2], ah0 * g[3]);
            op[2 * k + 1] = make_float4(ah0 * g[4], ah0 * g[5], ah0 * g[6], ah0 * g[7]);
        }
    }
}

// ---------------------------------------------------------------------------
// Node phase, scalar (fallback tiers only).
// ---------------------------------------------------------------------------
template <bool STORE_G>
__global__ __launch_bounds__(256) void node_kernel_t(
    const float* __restrict__ h,
    const float* __restrict__ W_src, const float* __restrict__ b_src,
    const float* __restrict__ W_dst, const float* __restrict__ b_dst,
    const float* __restrict__ Wa1, const float* __restrict__ ba1,
    const float* __restrict__ Wa2, const float* __restrict__ ba2,
    unsigned short* __restrict__ g_src_out, unsigned short* __restrict__ g_dst_out,
    float* __restrict__ out, int* __restrict__ counts, int* __restrict__ cursor, int N)
{
    __shared__ __align__(16) float sWs[NF * NF];
    __shared__ __align__(16) float sWd[NF * NF];
    __shared__ __align__(16) float sW1[NF * NHID];
    __shared__ __align__(16) float sW2[NHID * NH];
    __shared__ float sbs[NF], sbd[NF], sb1[NHID], sb2[NH];

    int tid = threadIdx.x;
    for (int i = tid; i < NF * NF; i += 256) { sWs[i] = W_src[i]; sWd[i] = W_dst[i]; }
    for (int i = tid; i < NF * NHID; i += 256) sW1[i] = Wa1[i];
    if (tid < NHID * NH) sW2[tid] = Wa2[tid];
    if (tid < NF) { sbs[tid] = b_src[tid]; sbd[tid] = b_dst[tid]; }
    if (tid < NHID) sb1[tid] = ba1[tid];
    if (tid < NH) sb2[tid] = ba2[tid];
    __syncthreads();

    int n = blockIdx.x * 256 + tid;
    if (n >= N) return;

    if (counts) { counts[n] = 0; cursor[n] = 0; }

    float hrow[NF];
    const float4* hv = (const float4*)(h + (size_t)n * NF);
    #pragma unroll
    for (int k = 0; k < 16; k++) {
        float4 u = hv[k];
        hrow[k * 4 + 0] = u.x; hrow[k * 4 + 1] = u.y;
        hrow[k * 4 + 2] = u.z; hrow[k * 4 + 3] = u.w;
    }

    float acc[NF];
    const float4* Wsv = (const float4*)sWs;
    const float4* Wdv = (const float4*)sWd;

    if (STORE_G) {
        #pragma unroll
        for (int j = 0; j < NF; j++) acc[j] = sbs[j];
        for (int i = 0; i < NF; i++) {
            float hi = hrow[i];
            #pragma unroll
            for (int jb = 0; jb < 16; jb++) {
                float4 w = Wsv[i * 16 + jb];
                acc[jb * 4 + 0] = fmaf(hi, w.x, acc[jb * 4 + 0]);
                acc[jb * 4 + 1] = fmaf(hi, w.y, acc[jb * 4 + 1]);
                acc[jb * 4 + 2] = fmaf(hi, w.z, acc[jb * 4 + 2]);
                acc[jb * 4 + 3] = fmaf(hi, w.w, acc[jb * 4 + 3]);
            }
        }
        uint4* gs = (uint4*)(g_src_out + (size_t)n * NF);
        #pragma unroll
        for (int k = 0; k < 8; k++) gs[k] = pack8(acc + k * 8);
    }

    #pragma unroll
    for (int j = 0; j < NF; j++) acc[j] = sbd[j];
    for (int i = 0; i < NF; i++) {
        float hi = hrow[i];
        #pragma unroll
        for (int jb = 0; jb < 16; jb++) {
            float4 w = Wdv[i * 16 + jb];
            acc[jb * 4 + 0] = fmaf(hi, w.x, acc[jb * 4 + 0]);
            acc[jb * 4 + 1] = fmaf(hi, w.y, acc[jb * 4 + 1]);
            acc[jb * 4 + 2] = fmaf(hi, w.z, acc[jb * 4 + 2]);
            acc[jb * 4 + 3] = fmaf(hi, w.w, acc[jb * 4 + 3]);
        }
    }
    if (STORE_G) {
        uint4* gd = (uint4*)(g_dst_out + (size_t)n * NF);
        #pragma unroll
        for (int k = 0; k < 8; k++) gd[k] = pack8(acc + k * 8);
    }

    float hid[NHID];
    #pragma unroll
    for (int j = 0; j < NHID; j++) hid[j] = sb1[j];
    const float4* W1v = (const float4*)sW1;
    for (int i = 0; i < NF; i++) {
        float xi = leaky(acc[i]);
        #pragma unroll
        for (int jb = 0; jb < 8; jb++) {
            float4 w = W1v[i * 8 + jb];
            hid[jb * 4 + 0] = fmaf(xi, w.x, hid[jb * 4 + 0]);
            hid[jb * 4 + 1] = fmaf(xi, w.y, hid[jb * 4 + 1]);
            hid[jb * 4 + 2] = fmaf(xi, w.z, hid[jb * 4 + 2]);
            hid[jb * 4 + 3] = fmaf(xi, w.w, hid[jb * 4 + 3]);
        }
    }
    float a[NH];
    #pragma unroll
    for (int j = 0; j < NH; j++) a[j] = sb2[j];
    #pragma unroll
    for (int k = 0; k < NHID; k++) {
        float xk = leaky(hid[k]);
        #pragma unroll
        for (int j = 0; j < NH; j++) a[j] = fmaf(xk, sW2[k * NH + j], a[j]);
    }
    #pragma unroll
    for (int j = 0; j < NH; j++) a[j] = sigmoidf(a[j]);

    float4* ap = (float4*)(out + (size_t)n * NF);
    #pragma unroll
    for (int k = 0; k < 16; k++) {
        int j = k * 4;
        ap[k] = make_float4(a[(j + 0) >> 3] * acc[j + 0],
                            a[(j + 1) >> 3] * acc[j + 1],
                            a[(j + 2) >> 3] * acc[j + 2],
                            a[(j + 3) >> 3] * acc[j + 3]);
    }
}

__global__ __launch_bounds__(256) void hist_kernel(
    const int* __restrict__ edge, const int* __restrict__ flags,
    int* __restrict__ counts, int E, int N)
{
    int e = blockIdx.x * 256 + threadIdx.x;
    if (e >= E) return;
    int s, d;
    load_edge(edge, e, E, flags[0], s, d);
    if ((unsigned)s >= (unsigned)N || (unsigned)d >= (unsigned)N) return;
    atomicAdd(&counts[d], 1);
}

__global__ __launch_bounds__(256) void scan1_kernel(
    const int* __restrict__ counts, int* __restrict__ offsets,
    int* __restrict__ bsums, int N)
{
    __shared__ int lds[256];
    int tid = threadIdx.x;
    int base = blockIdx.x * 2048 + tid * 8;
    int v[8]; int s = 0;
    #pragma unroll
    for (int k = 0; k < 8; k++) { int idx = base + k; int t = (idx < N) ? counts[idx] : 0; v[k] = t; s += t; }
    lds[tid] = s;
    __syncthreads();
    for (int off = 1; off < 256; off <<= 1) {
        int y = (tid >= off) ? lds[tid - off] : 0;
        __syncthreads();
        lds[tid] += y;
        __syncthreads();
    }
    int run = lds[tid] - s;
    #pragma unroll
    for (int k = 0; k < 8; k++) { int idx = base + k; if (idx < N) offsets[idx] = run; run += v[k]; }
    if (tid == 255) bsums[blockIdx.x] = lds[255];
}

__global__ void scan2_kernel(int* __restrict__ bsums, int* __restrict__ offsets, int NB, int N) {
    if (threadIdx.x == 0 && blockIdx.x == 0) {
        int run = 0;
        for (int i = 0; i < NB; i++) { int t = bsums[i]; bsums[i] = run; run += t; }
        offsets[N] = run;
    }
}

__global__ __launch_bounds__(256) void scan3_kernel(
    int* __restrict__ offsets, const int* __restrict__ bsums, int N)
{
    int add = bsums[blockIdx.x];
    int base = blockIdx.x * 2048 + threadIdx.x * 8;
    #pragma unroll
    for (int k = 0; k < 8; k++) { int idx = base + k; if (idx < N) offsets[idx] += add; }
}

__global__ __launch_bounds__(256) void scatter_kernel(
    const int* __restrict__ edge, const int* __restrict__ flags,
    const int* __restrict__ offsets, int* __restrict__ cursor,
    uint2* __restrict__ sorted_sd, int E, int N)
{
    int e = blockIdx.x * 256 + threadIdx.x;
    if (e >= E) return;
    int s, d;
    load_edge(edge, e, E, flags[0], s, d);
    if ((unsigned)s >= (unsigned)N || (unsigned)d >= (unsigned)N) return;
    int pos = offsets[d] + atomicAdd(&cursor[d], 1);
    sorted_sd[pos] = make_uint2((unsigned)s, (unsigned)d);
}

// ---------------------------------------------------------------------------
// Edge MLP via MFMA (unchanged from R10 — verified).
// ---------------------------------------------------------------------------
__global__ __launch_bounds__(256) void edge_mlp_mfma_kernel(
    const uint2* __restrict__ sorted_sd, const int* __restrict__ total_p,
    const unsigned short* __restrict__ g_src, const unsigned short* __restrict__ g_dst,
    const float* __restrict__ Wa1, const float* __restrict__ ba1,
    const float* __restrict__ Wa2, const float* __restrict__ ba2,
    __half* __restrict__ a_sorted)
{
    __shared__ __align__(16) unsigned short sX[4 * 64 * XS];
    __shared__ __align__(16) float sW2[NHID * NH];
    __shared__ float sb1[NHID], sb2[NH];

    int tid = threadIdx.x;
    if (tid < NHID * NH) sW2[tid] = Wa2[tid];
    if (tid < NHID) sb1[tid] = ba1[tid];
    if (tid < NH) sb2[tid] = ba2[tid];

    int wave = tid >> 6;
    int lane = tid & 63;
    int nsub = lane & 15;
    int quad = lane >> 4;
    int total = *total_p;
    int i = blockIdx.x * 256 + wave * 64 + lane;
    bool valid = i < total;
    uint2 sd = valid ? sorted_sd[i] : make_uint2(0u, 0u);

    unsigned short* xrow = sX + (wave * 64 + lane) * XS;
    {
        const uint4* gs = (const uint4*)(g_src + (size_t)sd.x * NF);
        const uint4* gd = (const uint4*)(g_dst + (size_t)sd.y * NF);
        #pragma unroll
        for (int k = 0; k < 8; k++) {
            float A8[8], B8[8], x8[8];
            unpack8(gs[k], A8); unpack8(gd[k], B8);
            #pragma unroll
            for (int t = 0; t < 8; t++) x8[t] = leaky(A8[t] + B8[t]);
            uint4 pk = pack8(x8);
            uint2* q = (uint2*)(xrow + k * 8);
            q[0] = make_uint2(pk.x, pk.y);
            q[1] = make_uint2(pk.z, pk.w);
        }
    }

    bf16x8v Bf[2][2];
    #pragma unroll
    for (int ks = 0; ks < 2; ks++) {
        #pragma unroll
        for (int nt = 0; nt < 2; nt++) {
            union { unsigned short s[8]; bf16x8v v; } u;
            #pragma unroll
            for (int j = 0; j < 8; j++) {
                int k = ks * 32 + quad * 8 + j;
                int n = nt * 16 + nsub;
                u.s[j] = f2bf(Wa1[k * NHID + n]);
            }
            Bf[ks][nt] = u.v;
        }
    }

    __syncthreads();

    f32x4v acc[4][2];
    #pragma unroll
    for (int mt = 0; mt < 4; mt++)
        #pragma unroll
        for (int nt = 0; nt < 2; nt++) {
            f32x4v z = {0.f, 0.f, 0.f, 0.f};
            acc[mt][nt] = z;
        }

    const unsigned short* wbase = sX + wave * 64 * XS;
    #pragma unroll
    for (int ks = 0; ks < 2; ks++) {
        #pragma unroll
        for (int mt = 0; mt < 4; mt++) {
            const unsigned short* ap = wbase + (mt * 16 + nsub) * XS + ks * 32 + quad * 8;
            union { uint2 d[2]; bf16x8v v; } ua;
            ua.d[0] = *(const uint2*)ap;
            ua.d[1] = *(const uint2*)(ap + 4);
            #pragma unroll
            for (int nt = 0; nt < 2; nt++)
                acc[mt][nt] = __builtin_amdgcn_mfma_f32_16x16x32_bf16(
                    ua.v, Bf[ks][nt], acc[mt][nt], 0, 0, 0);
        }
    }

    __syncthreads();

    #pragma unroll
    for (int nt = 0; nt < 2; nt++) {
        int n = nt * 16 + nsub;
        float b1v = sb1[n];
        #pragma unroll
        for (int mt = 0; mt < 4; mt++) {
            #pragma unroll
            for (int r = 0; r < 4; r++) {
                int m = mt * 16 + quad * 4 + r;
                sX[(wave * 64 + m) * XS + n] = f2bf(leaky(acc[mt][nt][r] + b1v));
            }
        }
    }

    __syncthreads();

    float hid[NHID];
    const unsigned short* hrow = wbase + lane * XS;
    #pragma unroll
    for (int k = 0; k < 8; k++) {
        uint2 dv = *(const uint2*)(hrow + k * 4);
        hid[k * 4 + 0] = bf2f((unsigned short)(dv.x & 0xffffu));
        hid[k * 4 + 1] = bf2f((unsigned short)(dv.x >> 16));
        hid[k * 4 + 2] = bf2f((unsigned short)(dv.y & 0xffffu));
        hid[k * 4 + 3] = bf2f((unsigned short)(dv.y >> 16));
    }
    float a[NH];
    #pragma unroll
    for (int j = 0; j < NH; j++) a[j] = sb2[j];
    #pragma unroll
    for (int k = 0; k < NHID; k++) {
        float xk = hid[k];
        #pragma unroll
        for (int j = 0; j < NH; j++) a[j] = fmaf(xk, sW2[k * NH + j], a[j]);
    }

    if (valid) {
        union { __half h[8]; uint4 u; } pk;
        #pragma unroll
        for (int j = 0; j < NH; j++) pk.h[j] = __float2half(sigmoidf(a[j]));
        *(uint4*)(a_sorted + (size_t)i * NH) = pk.u;
    }
}

// ---------------------------------------------------------------------------
// Aggregate v2 (unchanged).
// ---------------------------------------------------------------------------
__global__ __launch_bounds__(256) void aggregate_kernel(
    const int* __restrict__ offsets, const uint2* __restrict__ sorted_sd,
    const __half* __restrict__ a_sorted, const unsigned short* __restrict__ g_src,
    float* __restrict__ out, int N)
{
    int d = blockIdx.x * 32 + (threadIdx.x >> 3);
    if (d >= N) return;
    int l = threadIdx.x & 7;
    int beg = offsets[d], end = offsets[d + 1];

    float acc[8] = {0.f, 0.f, 0.f, 0.f, 0.f, 0.f, 0.f, 0.f};
    int i = beg;
    for (; i + 2 <= end; i += 2) {
        unsigned s0 = sorted_sd[i].x;
        unsigned s1 = sorted_sd[i + 1].x;
        float av0 = __half2float(a_sorted[(size_t)i * NH + l]);
        float av1 = __half2float(a_sorted[(size_t)(i + 1) * NH + l]);
        uint4 q0 = *(const uint4*)(g_src + (size_t)s0 * NF + l * 8);
        uint4 q1 = *(const uint4*)(g_src + (size_t)s1 * NF + l * 8);
        float f0[8], f1[8];
        unpack8(q0, f0); unpack8(q1, f1);
        #pragma unroll
        for (int t = 0; t < 8; t++) acc[t] = fmaf(av0, f0[t], acc[t]);
        #pragma unroll
        for (int t = 0; t < 8; t++) acc[t] = fmaf(av1, f1[t], acc[t]);
    }
    if (i < end) {
        unsigned s0 = sorted_sd[i].x;
        float av0 = __half2float(a_sorted[(size_t)i * NH + l]);
        uint4 q0 = *(const uint4*)(g_src + (size_t)s0 * NF + l * 8);
        float f0[8]; unpack8(q0, f0);
        #pragma unroll
        for (int t = 0; t < 8; t++) acc[t] = fmaf(av0, f0[t], acc[t]);
    }

    float4* o4 = (float4*)(out + (size_t)d * NF + l * 8);
    float4 v0 = o4[0], v1 = o4[1];
    v0.x += acc[0]; v0.y += acc[1]; v0.z += acc[2]; v0.w += acc[3];
    v1.x += acc[4]; v1.y += acc[5]; v1.z += acc[6]; v1.w += acc[7];
    o4[0] = v0; o4[1] = v1;
}

// ---------------------------------------------------------------------------
// Fallbacks (small ws).
// ---------------------------------------------------------------------------
__global__ __launch_bounds__(256) void edge_kernel(
    const int* __restrict__ edge, const int* __restrict__ flags,
    const unsigned short* __restrict__ g_src, const unsigned short* __restrict__ g_dst,
    const float* __restrict__ Wa1, const float* __restrict__ ba1,
    const float* __restrict__ Wa2, const float* __restrict__ ba2,
    float* __restrict__ out, int E, int N)
{
    __shared__ __align__(16) float sW1[NF * NHID];
    __shared__ __align__(16) float sW2[NHID * NH];
    __shared__ float sb1[NHID], sb2[NH];
    int tid = threadIdx.x;
    for (int i = tid; i < NF * NHID; i += 256) sW1[i] = Wa1[i];
    if (tid < NHID * NH) sW2[tid] = Wa2[tid];
    if (tid < NHID) sb1[tid] = ba1[tid];
    if (tid < NH) sb2[tid] = ba2[tid];
    __syncthreads();

    int e = blockIdx.x * 256 + tid;
    if (e >= E) return;
    int s, d;
    load_edge(edge, e, E, flags[0], s, d);
    if ((unsigned)s >= (unsigned)N || (unsigned)d >= (unsigned)N) return;

    float ms[NF];
    float hid[NHID];
    #pragma unroll
    for (int j = 0; j < NHID; j++) hid[j] = sb1[j];

    const uint4* gs = (const uint4*)(g_src + (size_t)s * NF);
    const uint4* gd = (const uint4*)(g_dst + (size_t)d * NF);
    #pragma unroll
    for (int k = 0; k < 8; k++) {
        float a8[8], b8[8];
        unpack8(gs[k], a8);
        unpack8(gd[k], b8);
        #pragma unroll
        for (int t = 0; t < 8; t++) {
            int i = k * 8 + t;
            ms[i] = a8[t];
            float x = leaky(a8[t] + b8[t]);
            #pragma unroll
            for (int j = 0; j < NHID; j++) hid[j] = fmaf(x, sW1[i * NHID + j], hid[j]);
        }
    }

    float a[NH];
    #pragma unroll
    for (int j = 0; j < NH; j++) a[j] = sb2[j];
    #pragma unroll
    for (int k = 0; k < NHID; k++) {
        float xk = leaky(hid[k]);
        #pragma unroll
        for (int j = 0; j < NH; j++) a[j] = fmaf(xk, sW2[k * NH + j], a[j]);
    }

    float* arow = out + (size_t)d * NF;
    #pragma unroll
    for (int hh = 0; hh < NH; hh++) {
        float ah = sigmoidf(a[hh]);
        #pragma unroll
        for (int dd = 0; dd < ND; dd++)
            unsafeAtomicAdd(arow + hh * ND + dd, ah * ms[hh * ND + dd]);
    }
}

__global__ __launch_bounds__(256) void edge_kernel_fused(
    const int* __restrict__ edge, const int* __restrict__ flags,
    const float* __restrict__ h,
    const float* __restrict__ W_src, const float* __restrict__ b_src,
    const float* __restrict__ W_dst, const float* __restrict__ b_dst,
    const float* __restrict__ Wa1, const float* __restrict__ ba1,
    const float* __restrict__ Wa2, const float* __restrict__ ba2,
    float* __restrict__ out, int E, int N)
{
    __shared__ __align__(16) float sWs[NF * NF];
    __shared__ __align__(16) float sWd[NF * NF];
    __shared__ __align__(16) float sW1[NF * NHID];
    __shared__ __align__(16) float sW2[NHID * NH];
    __shared__ float sbs[NF], sbd[NF], sb1[NHID], sb2[NH];
    int tid = threadIdx.x;
    for (int i = tid; i < NF * NF; i += 256) { sWs[i] = W_src[i]; sWd[i] = W_dst[i]; }
    for (int i = tid; i < NF * NHID; i += 256) sW1[i] = Wa1[i];
    if (tid < NHID * NH) sW2[tid] = Wa2[tid];
    if (tid < NF) { sbs[tid] = b_src[tid]; sbd[tid] = b_dst[tid]; }
    if (tid < NHID) sb1[tid] = ba1[tid];
    if (tid < NH) sb2[tid] = ba2[tid];
    __syncthreads();

    int e = blockIdx.x * 256 + tid;
    if (e >= E) return;
    int wide = flags ? flags[0] : 0;
    int s, d;
    load_edge(edge, e, E, wide, s, d);
    if ((unsigned)s >= (unsigned)N || (unsigned)d >= (unsigned)N) return;

    float gsr[NF], msg[NF];
    {
        float hrow[NF];
        #pragma unroll
        for (int i = 0; i < NF; i++) hrow[i] = h[(size_t)s * NF + i];
        #pragma unroll
        for (int j = 0; j < NF; j++) gsr[j] = sbs[j];
        for (int i = 0; i < NF; i++) {
            float hi = hrow[i];
            #pragma unroll
            for (int j = 0; j < NF; j++) gsr[j] = fmaf(hi, sWs[i * NF + j], gsr[j]);
        }
    }
    #pragma unroll
    for (int j = 0; j < NF; j++) msg[j] = gsr[j] + sbd[j];
    for (int i = 0; i < NF; i++) {
        float hi = h[(size_t)d * NF + i];
        #pragma unroll
        for (int j = 0; j < NF; j++) msg[j] = fmaf(hi, sWd[i * NF + j], msg[j]);
    }

    float hid[NHID];
    #pragma unroll
    for (int j = 0; j < NHID; j++) hid[j] = sb1[j];
    for (int i = 0; i < NF; i++) {
        float x = leaky(msg[i]);
        #pragma unroll
        for (int j = 0; j < NHID; j++) hid[j] = fmaf(x, sW1[i * NHID + j], hid[j]);
    }
    float a[NH];
    #pragma unroll
    for (int j = 0; j < NH; j++) a[j] = sb2[j];
    #pragma unroll
    for (int k = 0; k < NHID; k++) {
        float xk = leaky(hid[k]);
        #pragma unroll
        for (int j = 0; j < NH; j++) a[j] = fmaf(xk, sW2[k * NH + j], a[j]);
    }

    float* arow = out + (size_t)d * NF;
    #pragma unroll
    for (int hh = 0; hh < NH; hh++) {
        float ah = sigmoidf(a[hh]);
        #pragma unroll
        for (int dd = 0; dd < ND; dd++)
            unsafeAtomicAdd(arow + hh * ND + dd, ah * gsr[hh * ND + dd]);
    }
}

static inline size_t al256(size_t x) { return (x + 255) & ~(size_t)255; }

extern "C" void kernel_launch(void* const* d_in, const int* in_sizes, int n_in,
                              void* d_out, int out_size, void* d_ws, size_t ws_size,
                              hipStream_t stream) {
    const float* h       = (const float*)d_in[0];
    const float* W_src   = (const float*)d_in[1];
    const float* b_src   = (const float*)d_in[2];
    const float* W_dst   = (const float*)d_in[3];
    const float* b_dst   = (const float*)d_in[4];
    const float* Wa1_src = (const float*)d_in[5];
    const float* ba1_src = (const float*)d_in[6];
    const float* Wa2_src = (const float*)d_in[7];
    const float* ba2_src = (const float*)d_in[8];
    const float* Wa1_dst = (const float*)d_in[9];
    const float* ba1_dst = (const float*)d_in[10];
    const float* Wa2_dst = (const float*)d_in[11];
    const float* ba2_dst = (const float*)d_in[12];
    const int* edge = (const int*)d_in[13];

    int N = in_sizes[0] / NF;
    int E = in_sizes[13] / 2;
    float* out = (float*)d_out;

    int nodeBlocks = (N + 255) / 256;
    int nodeWaves  = (N + 63) / 64;
    int edgeBlocks = (E + 255) / 256;
    int NB1 = (N + 2047) / 2048;

    size_t o_flags  = 0;
    size_t o_gsrc   = al256(o_flags + 256);
    size_t o_gdst   = al256(o_gsrc + (size_t)N * NF * 2);
    size_t o_asort  = al256(o_gdst + (size_t)N * NF * 2);
    size_t o_counts = al256(o_asort + (size_t)E * NH * 2);
    size_t o_offs   = al256(o_counts + (size_t)N * 4);
    size_t o_cursor = al256(o_offs + ((size_t)N + 1) * 4);
    size_t o_bsums  = al256(o_cursor + (size_t)N * 4);
    size_t o_sorted = al256(o_bsums + (size_t)NB1 * 4);
    size_t need     = o_sorted + (size_t)E * 8;

    size_t gB = (size_t)N * NF * 2;

    if (ws_size >= need) {
        char* w = (char*)d_ws;
        int*            flags   = (int*)(w + o_flags);
        unsigned short* g_src   = (unsigned short*)(w + o_gsrc);
        unsigned short* g_dst   = (unsigned short*)(w + o_gdst);
        __half*         a_sort  = (__half*)(w + o_asort);
        int*            counts  = (int*)(w + o_counts);
        int*            offsets = (int*)(w + o_offs);
        int*            cursor  = (int*)(w + o_cursor);
        int*            bsums   = (int*)(w + o_bsums);
        uint2*          sorted  = (uint2*)(w + o_sorted);

        detect_kernel<<<1, 1, 0, stream>>>(edge, flags);

        node_mfma_kernel<<<nodeWaves, 64, 0, stream>>>(
            h, W_src, b_src, W_dst, b_dst,
            Wa1_dst, ba1_dst, Wa2_dst, ba2_dst,
            g_src, g_dst, out, counts, cursor, N);

        hist_kernel<<<edgeBlocks, 256, 0, stream>>>(edge, flags, counts, E, N);

        scan1_kernel<<<NB1, 256, 0, stream>>>(counts, offsets, bsums, N);
        scan2_kernel<<<1, 1, 0, stream>>>(bsums, offsets, NB1, N);
        scan3_kernel<<<NB1, 256, 0, stream>>>(offsets, bsums, N);

        scatter_kernel<<<edgeBlocks, 256, 0, stream>>>(
            edge, flags, offsets, cursor, sorted, E, N);

        edge_mlp_mfma_kernel<<<edgeBlocks, 256, 0, stream>>>(
            sorted, offsets + N, g_src, g_dst,
            Wa1_src, ba1_src, Wa2_src, ba2_src, a_sort);

        aggregate_kernel<<<(N + 31) / 32, 256, 0, stream>>>(
            offsets, sorted, a_sort, g_src, out, N);
    } else if (ws_size >= 256 + 2 * gB) {
        int* flags = (int*)d_ws;
        unsigned short* g_src = (unsigned short*)((char*)d_ws + 256);
        unsigned short* g_dst = g_src + (size_t)N * NF;

        detect_kernel<<<1, 1, 0, stream>>>(edge, flags);

        node_kernel_t<true><<<nodeBlocks, 256, 0, stream>>>(
            h, W_src, b_src, W_dst, b_dst,
            Wa1_dst, ba1_dst, Wa2_dst, ba2_dst,
            g_src, g_dst, out, nullptr, nullptr, N);

        edge_kernel<<<edgeBlocks, 256, 0, stream>>>(
            edge, flags, g_src, g_dst,
            Wa1_src, ba1_src, Wa2_src, ba2_src,
            out, E, N);
    } else {
        int* flags = (ws_size >= 256) ? (int*)d_ws : nullptr;
        if (flags) detect_kernel<<<1, 1, 0, stream>>>(edge, flags);

        node_kernel_t<false><<<nodeBlocks, 256, 0, stream>>>(
            h, W_src, b_src, W_dst, b_dst,
            Wa1_dst, ba1_dst, Wa2_dst, ba2_dst,
            nullptr, nullptr, out, nullptr, nullptr, N);

        edge_kernel_fused<<<edgeBlocks, 256, 0, stream>>>(
            edge, flags, h,
            W_src, b_src, W_dst, b_dst,
            Wa1_src, ba1_src, Wa2_src, ba2_src,
            out, E, N);
    }
}

// Round 12
// 294.184 us; speedup vs baseline: 13.2294x; 1.1602x over previous
//
#include <hip/hip_runtime.h>
#include <hip/hip_bf16.h>
#include <hip/hip_fp16.h>

#define NF   64
#define NH   8
#define ND   8
#define NHID 32
#define XS   68   // LDS row stride in shorts (136B: 8B-aligned, 2-way banks at worst)

typedef __attribute__((ext_vector_type(8))) short bf16x8v;
typedef __attribute__((ext_vector_type(4))) float f32x4v;

__device__ __forceinline__ float bf2f(unsigned short u) {
    union { unsigned int i; float f; } v; v.i = ((unsigned int)u) << 16; return v.f;
}
__device__ __forceinline__ unsigned short f2bf(float f) {
    __hip_bfloat16 b = __float2bfloat16(f);
    union { __hip_bfloat16 b; unsigned short u; } v; v.b = b; return v.u;
}
__device__ __forceinline__ void unpack8(uint4 u, float* o) {
    o[0] = __uint_as_float(u.x << 16); o[1] = __uint_as_float(u.x & 0xffff0000u);
    o[2] = __uint_as_float(u.y << 16); o[3] = __uint_as_float(u.y & 0xffff0000u);
    o[4] = __uint_as_float(u.z << 16); o[5] = __uint_as_float(u.z & 0xffff0000u);
    o[6] = __uint_as_float(u.w << 16); o[7] = __uint_as_float(u.w & 0xffff0000u);
}
__device__ __forceinline__ uint4 pack8(const float* f) {
    uint4 u;
    u.x = (unsigned)f2bf(f[0]) | ((unsigned)f2bf(f[1]) << 16);
    u.y = (unsigned)f2bf(f[2]) | ((unsigned)f2bf(f[3]) << 16);
    u.z = (unsigned)f2bf(f[4]) | ((unsigned)f2bf(f[5]) << 16);
    u.w = (unsigned)f2bf(f[6]) | ((unsigned)f2bf(f[7]) << 16);
    return u;
}
__device__ __forceinline__ float leaky(float x) { return x > 0.f ? x : 0.2f * x; }
__device__ __forceinline__ float sigmoidf(float x) { return 1.f / (1.f + __expf(-x)); }

__global__ void detect_kernel(const int* __restrict__ edge, int* __restrict__ flags) {
    if (threadIdx.x == 0 && blockIdx.x == 0) {
        int oddnz = 0;
        for (int i = 0; i < 32; i++) oddnz |= edge[2 * i + 1];
        flags[0] = (oddnz == 0) ? 1 : 0;
    }
}

__device__ __forceinline__ void load_edge(const int* __restrict__ edge, int e, int E,
                                          int wide, int& s, int& d) {
    if (wide) { s = edge[2 * e]; d = edge[2 * (E + e)]; }
    else      { s = edge[e];     d = edge[E + e]; }
}

// ---------------------------------------------------------------------------
// Node phase via MFMA (unchanged from R11, minus cursor zeroing).
// ---------------------------------------------------------------------------
__global__ __launch_bounds__(64) void node_mfma_kernel(
    const float* __restrict__ h,
    const float* __restrict__ W_src, const float* __restrict__ b_src,
    const float* __restrict__ W_dst, const float* __restrict__ b_dst,
    const float* __restrict__ Wa1, const float* __restrict__ ba1,
    const float* __restrict__ Wa2, const float* __restrict__ ba2,
    unsigned short* __restrict__ g_src_out, unsigned short* __restrict__ g_dst_out,
    float* __restrict__ out, int* __restrict__ counts, int N)
{
    __shared__ __align__(16) unsigned short sX[64 * XS];  // h rows, later hid
    __shared__ __align__(16) unsigned short sY[64 * XS];  // g rows (raw)
    __shared__ float sW2[NHID * NH];
    __shared__ float sb2[NH];

    int lane = threadIdx.x;
    int nsub = lane & 15, quad = lane >> 4;
    int base = blockIdx.x * 64;
    int n = base + lane;
    bool valid = n < N;
    size_t nn = valid ? (size_t)n : (size_t)(N - 1);

    if (valid && counts) counts[n] = 0;
    for (int i = lane; i < NHID * NH; i += 64) sW2[i] = Wa2[i];
    if (lane < NH) sb2[lane] = ba2[lane];

    {
        const float4* hv = (const float4*)(h + nn * NF);
        unsigned short* xrow = sX + lane * XS;
        #pragma unroll
        for (int k = 0; k < 8; k++) {
            float4 u0 = hv[2 * k], u1 = hv[2 * k + 1];
            float f[8] = { u0.x, u0.y, u0.z, u0.w, u1.x, u1.y, u1.z, u1.w };
            uint4 p = pack8(f);
            uint2* q = (uint2*)(xrow + k * 8);
            q[0] = make_uint2(p.x, p.y);
            q[1] = make_uint2(p.z, p.w);
        }
    }
    __syncthreads();

    #pragma unroll 1
    for (int m = 0; m < 2; m++) {
        const float* W  = m ? W_dst : W_src;
        const float* bb = m ? b_dst : b_src;
        unsigned short* gout = m ? g_dst_out : g_src_out;

        bf16x8v Bf[2][4];
        #pragma unroll
        for (int ks = 0; ks < 2; ks++)
            #pragma unroll
            for (int nt = 0; nt < 4; nt++) {
                union { unsigned short s[8]; bf16x8v v; } u;
                #pragma unroll
                for (int j = 0; j < 8; j++)
                    u.s[j] = f2bf(W[(ks * 32 + quad * 8 + j) * NF + nt * 16 + nsub]);
                Bf[ks][nt] = u.v;
            }

        f32x4v acc[4][4];
        #pragma unroll
        for (int mt = 0; mt < 4; mt++)
            #pragma unroll
            for (int nt = 0; nt < 4; nt++) {
                f32x4v z = {0.f, 0.f, 0.f, 0.f};
                acc[mt][nt] = z;
            }

        #pragma unroll
        for (int ks = 0; ks < 2; ks++)
            #pragma unroll
            for (int mt = 0; mt < 4; mt++) {
                const unsigned short* ap = sX + (mt * 16 + nsub) * XS + ks * 32 + quad * 8;
                union { uint2 d[2]; bf16x8v v; } ua;
                ua.d[0] = *(const uint2*)ap;
                ua.d[1] = *(const uint2*)(ap + 4);
                #pragma unroll
                for (int nt = 0; nt < 4; nt++)
                    acc[mt][nt] = __builtin_amdgcn_mfma_f32_16x16x32_bf16(
                        ua.v, Bf[ks][nt], acc[mt][nt], 0, 0, 0);
            }

        if (m == 1) __syncthreads();

        #pragma unroll
        for (int nt = 0; nt < 4; nt++) {
            float bv = bb[nt * 16 + nsub];
            #pragma unroll
            for (int mt = 0; mt < 4; mt++)
                #pragma unroll
                for (int r = 0; r < 4; r++)
                    sY[(mt * 16 + quad * 4 + r) * XS + nt * 16 + nsub] =
                        f2bf(acc[mt][nt][r] + bv);
        }
        __syncthreads();

        if (valid) {
            const unsigned short* yrow = sY + lane * XS;
            uint4* gp = (uint4*)(gout + (size_t)n * NF);
            #pragma unroll
            for (int k = 0; k < 8; k++) {
                uint2 a = *(const uint2*)(yrow + k * 8);
                uint2 b = *(const uint2*)(yrow + k * 8 + 4);
                gp[k] = make_uint4(a.x, a.y, b.x, b.y);
            }
        }
    }

    bf16x8v B1f[2][2];
    #pragma unroll
    for (int ks = 0; ks < 2; ks++)
        #pragma unroll
        for (int nt = 0; nt < 2; nt++) {
            union { unsigned short s[8]; bf16x8v v; } u;
            #pragma unroll
            for (int j = 0; j < 8; j++)
                u.s[j] = f2bf(Wa1[(ks * 32 + quad * 8 + j) * NHID + nt * 16 + nsub]);
            B1f[ks][nt] = u.v;
        }

    f32x4v acc2[4][2];
    #pragma unroll
    for (int mt = 0; mt < 4; mt++)
        #pragma unroll
        for (int nt = 0; nt < 2; nt++) {
            f32x4v z = {0.f, 0.f, 0.f, 0.f};
            acc2[mt][nt] = z;
        }

    #pragma unroll
    for (int ks = 0; ks < 2; ks++)
        #pragma unroll
        for (int mt = 0; mt < 4; mt++) {
            const unsigned short* ap = sY + (mt * 16 + nsub) * XS + ks * 32 + quad * 8;
            uint2 d0 = *(const uint2*)ap;
            uint2 d1 = *(const uint2*)(ap + 4);
            float f[8];
            unpack8(make_uint4(d0.x, d0.y, d1.x, d1.y), f);
            #pragma unroll
            for (int t = 0; t < 8; t++) f[t] = leaky(f[t]);
            uint4 p = pack8(f);
            union { uint4 u; bf16x8v v; } ua; ua.u = p;
            #pragma unroll
            for (int nt = 0; nt < 2; nt++)
                acc2[mt][nt] = __builtin_amdgcn_mfma_f32_16x16x32_bf16(
                    ua.v, B1f[ks][nt], acc2[mt][nt], 0, 0, 0);
        }
    __syncthreads();

    #pragma unroll
    for (int nt = 0; nt < 2; nt++) {
        float b1v = ba1[nt * 16 + nsub];
        #pragma unroll
        for (int mt = 0; mt < 4; mt++)
            #pragma unroll
            for (int r = 0; r < 4; r++)
                sX[(mt * 16 + quad * 4 + r) * XS + nt * 16 + nsub] =
                    f2bf(leaky(acc2[mt][nt][r] + b1v));
    }
    __syncthreads();

    if (valid) {
        float hid[NHID];
        const unsigned short* hrow = sX + lane * XS;
        #pragma unroll
        for (int k = 0; k < 8; k++) {
            uint2 dv = *(const uint2*)(hrow + k * 4);
            hid[k * 4 + 0] = bf2f((unsigned short)(dv.x & 0xffffu));
            hid[k * 4 + 1] = bf2f((unsigned short)(dv.x >> 16));
            hid[k * 4 + 2] = bf2f((unsigned short)(dv.y & 0xffffu));
            hid[k * 4 + 3] = bf2f((unsigned short)(dv.y >> 16));
        }
        float a[NH];
        #pragma unroll
        for (int j = 0; j < NH; j++) a[j] = sb2[j];
        #pragma unroll
        for (int k = 0; k < NHID; k++) {
            float xk = hid[k];
            #pragma unroll
            for (int j = 0; j < NH; j++) a[j] = fmaf(xk, sW2[k * NH + j], a[j]);
        }
        #pragma unroll
        for (int j = 0; j < NH; j++) a[j] = sigmoidf(a[j]);

        const unsigned short* yrow = sY + lane * XS;
        float4* op = (float4*)(out + (size_t)n * NF);
        #pragma unroll
        for (int k = 0; k < 8; k++) {
            uint2 u0 = *(const uint2*)(yrow + k * 8);
            uint2 u1 = *(const uint2*)(yrow + k * 8 + 4);
            float g[8];
            unpack8(make_uint4(u0.x, u0.y, u1.x, u1.y), g);
            float ah0 = a[(k * 8) >> 3];
            op[2 * k]     = make_float4(ah0 * g[0], ah0 * g[1], ah0 * g[2], ah0 * g[3]);
            op[2 * k + 1] = make_float4(ah0 * g[4], ah0 * g[5], ah0 * g[6], ah0 * g[7]);
        }
    }
}

// ---------------------------------------------------------------------------
// Node phase, scalar (fallback tiers only).
// ---------------------------------------------------------------------------
template <bool STORE_G>
__global__ __launch_bounds__(256) void node_kernel_t(
    const float* __restrict__ h,
    const float* __restrict__ W_src, const float* __restrict__ b_src,
    const float* __restrict__ W_dst, const float* __restrict__ b_dst,
    const float* __restrict__ Wa1, const float* __restrict__ ba1,
    const float* __restrict__ Wa2, const float* __restrict__ ba2,
    unsigned short* __restrict__ g_src_out, unsigned short* __restrict__ g_dst_out,
    float* __restrict__ out, int N)
{
    __shared__ __align__(16) float sWs[NF * NF];
    __shared__ __align__(16) float sWd[NF * NF];
    __shared__ __align__(16) float sW1[NF * NHID];
    __shared__ __align__(16) float sW2[NHID * NH];
    __shared__ float sbs[NF], sbd[NF], sb1[NHID], sb2[NH];

    int tid = threadIdx.x;
    for (int i = tid; i < NF * NF; i += 256) { sWs[i] = W_src[i]; sWd[i] = W_dst[i]; }
    for (int i = tid; i < NF * NHID; i += 256) sW1[i] = Wa1[i];
    if (tid < NHID * NH) sW2[tid] = Wa2[tid];
    if (tid < NF) { sbs[tid] = b_src[tid]; sbd[tid] = b_dst[tid]; }
    if (tid < NHID) sb1[tid] = ba1[tid];
    if (tid < NH) sb2[tid] = ba2[tid];
    __syncthreads();

    int n = blockIdx.x * 256 + tid;
    if (n >= N) return;

    float hrow[NF];
    const float4* hv = (const float4*)(h + (size_t)n * NF);
    #pragma unroll
    for (int k = 0; k < 16; k++) {
        float4 u = hv[k];
        hrow[k * 4 + 0] = u.x; hrow[k * 4 + 1] = u.y;
        hrow[k * 4 + 2] = u.z; hrow[k * 4 + 3] = u.w;
    }

    float acc[NF];
    const float4* Wsv = (const float4*)sWs;
    const float4* Wdv = (const float4*)sWd;

    if (STORE_G) {
        #pragma unroll
        for (int j = 0; j < NF; j++) acc[j] = sbs[j];
        for (int i = 0; i < NF; i++) {
            float hi = hrow[i];
            #pragma unroll
            for (int jb = 0; jb < 16; jb++) {
                float4 w = Wsv[i * 16 + jb];
                acc[jb * 4 + 0] = fmaf(hi, w.x, acc[jb * 4 + 0]);
                acc[jb * 4 + 1] = fmaf(hi, w.y, acc[jb * 4 + 1]);
                acc[jb * 4 + 2] = fmaf(hi, w.z, acc[jb * 4 + 2]);
                acc[jb * 4 + 3] = fmaf(hi, w.w, acc[jb * 4 + 3]);
            }
        }
        uint4* gs = (uint4*)(g_src_out + (size_t)n * NF);
        #pragma unroll
        for (int k = 0; k < 8; k++) gs[k] = pack8(acc + k * 8);
    }

    #pragma unroll
    for (int j = 0; j < NF; j++) acc[j] = sbd[j];
    for (int i = 0; i < NF; i++) {
        float hi = hrow[i];
        #pragma unroll
        for (int jb = 0; jb < 16; jb++) {
            float4 w = Wdv[i * 16 + jb];
            acc[jb * 4 + 0] = fmaf(hi, w.x, acc[jb * 4 + 0]);
            acc[jb * 4 + 1] = fmaf(hi, w.y, acc[jb * 4 + 1]);
            acc[jb * 4 + 2] = fmaf(hi, w.z, acc[jb * 4 + 2]);
            acc[jb * 4 + 3] = fmaf(hi, w.w, acc[jb * 4 + 3]);
        }
    }
    if (STORE_G) {
        uint4* gd = (uint4*)(g_dst_out + (size_t)n * NF);
        #pragma unroll
        for (int k = 0; k < 8; k++) gd[k] = pack8(acc + k * 8);
    }

    float hid[NHID];
    #pragma unroll
    for (int j = 0; j < NHID; j++) hid[j] = sb1[j];
    const float4* W1v = (const float4*)sW1;
    for (int i = 0; i < NF; i++) {
        float xi = leaky(acc[i]);
        #pragma unroll
        for (int jb = 0; jb < 8; jb++) {
            float4 w = W1v[i * 8 + jb];
            hid[jb * 4 + 0] = fmaf(xi, w.x, hid[jb * 4 + 0]);
            hid[jb * 4 + 1] = fmaf(xi, w.y, hid[jb * 4 + 1]);
            hid[jb * 4 + 2] = fmaf(xi, w.z, hid[jb * 4 + 2]);
            hid[jb * 4 + 3] = fmaf(xi, w.w, hid[jb * 4 + 3]);
        }
    }
    float a[NH];
    #pragma unroll
    for (int j = 0; j < NH; j++) a[j] = sb2[j];
    #pragma unroll
    for (int k = 0; k < NHID; k++) {
        float xk = leaky(hid[k]);
        #pragma unroll
        for (int j = 0; j < NH; j++) a[j] = fmaf(xk, sW2[k * NH + j], a[j]);
    }
    #pragma unroll
    for (int j = 0; j < NH; j++) a[j] = sigmoidf(a[j]);

    float4* ap = (float4*)(out + (size_t)n * NF);
    #pragma unroll
    for (int k = 0; k < 16; k++) {
        int j = k * 4;
        ap[k] = make_float4(a[(j + 0) >> 3] * acc[j + 0],
                            a[(j + 1) >> 3] * acc[j + 1],
                            a[(j + 2) >> 3] * acc[j + 2],
                            a[(j + 3) >> 3] * acc[j + 3]);
    }
}

// ---------------------------------------------------------------------------
// Hist + rank claim: rank[e] = atomicAdd(&counts[d],1)  (rank store coalesced).
// ---------------------------------------------------------------------------
__global__ __launch_bounds__(256) void hist_kernel(
    const int* __restrict__ edge, const int* __restrict__ flags,
    int* __restrict__ counts, int* __restrict__ rank, int E, int N)
{
    int e = blockIdx.x * 256 + threadIdx.x;
    if (e >= E) return;
    int s, d;
    load_edge(edge, e, E, flags[0], s, d);
    if ((unsigned)s >= (unsigned)N || (unsigned)d >= (unsigned)N) { rank[e] = -1; return; }
    rank[e] = atomicAdd(&counts[d], 1);
}

__global__ __launch_bounds__(256) void scan1_kernel(
    const int* __restrict__ counts, int* __restrict__ offsets,
    int* __restrict__ bsums, int N)
{
    __shared__ int lds[256];
    int tid = threadIdx.x;
    int base = blockIdx.x * 2048 + tid * 8;
    int v[8]; int s = 0;
    #pragma unroll
    for (int k = 0; k < 8; k++) { int idx = base + k; int t = (idx < N) ? counts[idx] : 0; v[k] = t; s += t; }
    lds[tid] = s;
    __syncthreads();
    for (int off = 1; off < 256; off <<= 1) {
        int y = (tid >= off) ? lds[tid - off] : 0;
        __syncthreads();
        lds[tid] += y;
        __syncthreads();
    }
    int run = lds[tid] - s;
    #pragma unroll
    for (int k = 0; k < 8; k++) { int idx = base + k; if (idx < N) offsets[idx] = run; run += v[k]; }
    if (tid == 255) bsums[blockIdx.x] = lds[255];
}

__global__ void scan2_kernel(int* __restrict__ bsums, int* __restrict__ offsets, int NB, int N) {
    if (threadIdx.x == 0 && blockIdx.x == 0) {
        int run = 0;
        for (int i = 0; i < NB; i++) { int t = bsums[i]; bsums[i] = run; run += t; }
        offsets[N] = run;
    }
}

__global__ __launch_bounds__(256) void scan3_kernel(
    int* __restrict__ offsets, const int* __restrict__ bsums, int N)
{
    int add = bsums[blockIdx.x];
    int base = blockIdx.x * 2048 + threadIdx.x * 8;
    #pragma unroll
    for (int k = 0; k < 8; k++) { int idx = base + k; if (idx < N) offsets[idx] += add; }
}

// ---------------------------------------------------------------------------
// Scatter (atomic-free): pos = offsets[d] + rank[e].
// ---------------------------------------------------------------------------
__global__ __launch_bounds__(256) void scatter_kernel(
    const int* __restrict__ edge, const int* __restrict__ flags,
    const int* __restrict__ offsets, const int* __restrict__ rank,
    uint2* __restrict__ sorted_sd, int E, int N)
{
    int e = blockIdx.x * 256 + threadIdx.x;
    if (e >= E) return;
    int r = rank[e];
    if (r < 0) return;
    int s, d;
    load_edge(edge, e, E, flags[0], s, d);
    int pos = offsets[d] + r;
    sorted_sd[pos] = make_uint2((unsigned)s, (unsigned)d);
}

// ---------------------------------------------------------------------------
// Edge MLP via MFMA (unchanged — verified).
// ---------------------------------------------------------------------------
__global__ __launch_bounds__(256) void edge_mlp_mfma_kernel(
    const uint2* __restrict__ sorted_sd, const int* __restrict__ total_p,
    const unsigned short* __restrict__ g_src, const unsigned short* __restrict__ g_dst,
    const float* __restrict__ Wa1, const float* __restrict__ ba1,
    const float* __restrict__ Wa2, const float* __restrict__ ba2,
    __half* __restrict__ a_sorted)
{
    __shared__ __align__(16) unsigned short sX[4 * 64 * XS];
    __shared__ __align__(16) float sW2[NHID * NH];
    __shared__ float sb1[NHID], sb2[NH];

    int tid = threadIdx.x;
    if (tid < NHID * NH) sW2[tid] = Wa2[tid];
    if (tid < NHID) sb1[tid] = ba1[tid];
    if (tid < NH) sb2[tid] = ba2[tid];

    int wave = tid >> 6;
    int lane = tid & 63;
    int nsub = lane & 15;
    int quad = lane >> 4;
    int total = *total_p;
    int i = blockIdx.x * 256 + wave * 64 + lane;
    bool valid = i < total;
    uint2 sd = valid ? sorted_sd[i] : make_uint2(0u, 0u);

    unsigned short* xrow = sX + (wave * 64 + lane) * XS;
    {
        const uint4* gs = (const uint4*)(g_src + (size_t)sd.x * NF);
        const uint4* gd = (const uint4*)(g_dst + (size_t)sd.y * NF);
        #pragma unroll
        for (int k = 0; k < 8; k++) {
            float A8[8], B8[8], x8[8];
            unpack8(gs[k], A8); unpack8(gd[k], B8);
            #pragma unroll
            for (int t = 0; t < 8; t++) x8[t] = leaky(A8[t] + B8[t]);
            uint4 pk = pack8(x8);
            uint2* q = (uint2*)(xrow + k * 8);
            q[0] = make_uint2(pk.x, pk.y);
            q[1] = make_uint2(pk.z, pk.w);
        }
    }

    bf16x8v Bf[2][2];
    #pragma unroll
    for (int ks = 0; ks < 2; ks++) {
        #pragma unroll
        for (int nt = 0; nt < 2; nt++) {
            union { unsigned short s[8]; bf16x8v v; } u;
            #pragma unroll
            for (int j = 0; j < 8; j++) {
                int k = ks * 32 + quad * 8 + j;
                int n = nt * 16 + nsub;
                u.s[j] = f2bf(Wa1[k * NHID + n]);
            }
            Bf[ks][nt] = u.v;
        }
    }

    __syncthreads();

    f32x4v acc[4][2];
    #pragma unroll
    for (int mt = 0; mt < 4; mt++)
        #pragma unroll
        for (int nt = 0; nt < 2; nt++) {
            f32x4v z = {0.f, 0.f, 0.f, 0.f};
            acc[mt][nt] = z;
        }

    const unsigned short* wbase = sX + wave * 64 * XS;
    #pragma unroll
    for (int ks = 0; ks < 2; ks++) {
        #pragma unroll
        for (int mt = 0; mt < 4; mt++) {
            const unsigned short* ap = wbase + (mt * 16 + nsub) * XS + ks * 32 + quad * 8;
            union { uint2 d[2]; bf16x8v v; } ua;
            ua.d[0] = *(const uint2*)ap;
            ua.d[1] = *(const uint2*)(ap + 4);
            #pragma unroll
            for (int nt = 0; nt < 2; nt++)
                acc[mt][nt] = __builtin_amdgcn_mfma_f32_16x16x32_bf16(
                    ua.v, Bf[ks][nt], acc[mt][nt], 0, 0, 0);
        }
    }

    __syncthreads();

    #pragma unroll
    for (int nt = 0; nt < 2; nt++) {
        int n = nt * 16 + nsub;
        float b1v = sb1[n];
        #pragma unroll
        for (int mt = 0; mt < 4; mt++) {
            #pragma unroll
            for (int r = 0; r < 4; r++) {
                int m = mt * 16 + quad * 4 + r;
                sX[(wave * 64 + m) * XS + n] = f2bf(leaky(acc[mt][nt][r] + b1v));
            }
        }
    }

    __syncthreads();

    float hid[NHID];
    const unsigned short* hrow = wbase + lane * XS;
    #pragma unroll
    for (int k = 0; k < 8; k++) {
        uint2 dv = *(const uint2*)(hrow + k * 4);
        hid[k * 4 + 0] = bf2f((unsigned short)(dv.x & 0xffffu));
        hid[k * 4 + 1] = bf2f((unsigned short)(dv.x >> 16));
        hid[k * 4 + 2] = bf2f((unsigned short)(dv.y & 0xffffu));
        hid[k * 4 + 3] = bf2f((unsigned short)(dv.y >> 16));
    }
    float a[NH];
    #pragma unroll
    for (int j = 0; j < NH; j++) a[j] = sb2[j];
    #pragma unroll
    for (int k = 0; k < NHID; k++) {
        float xk = hid[k];
        #pragma unroll
        for (int j = 0; j < NH; j++) a[j] = fmaf(xk, sW2[k * NH + j], a[j]);
    }

    if (valid) {
        union { __half h[8]; uint4 u; } pk;
        #pragma unroll
        for (int j = 0; j < NH; j++) pk.h[j] = __float2half(sigmoidf(a[j]));
        *(uint4*)(a_sorted + (size_t)i * NH) = pk.u;
    }
}

// ---------------------------------------------------------------------------
// Aggregate v2 (unchanged).
// ---------------------------------------------------------------------------
__global__ __launch_bounds__(256) void aggregate_kernel(
    const int* __restrict__ offsets, const uint2* __restrict__ sorted_sd,
    const __half* __restrict__ a_sorted, const unsigned short* __restrict__ g_src,
    float* __restrict__ out, int N)
{
    int d = blockIdx.x * 32 + (threadIdx.x >> 3);
    if (d >= N) return;
    int l = threadIdx.x & 7;
    int beg = offsets[d], end = offsets[d + 1];

    float acc[8] = {0.f, 0.f, 0.f, 0.f, 0.f, 0.f, 0.f, 0.f};
    int i = beg;
    for (; i + 2 <= end; i += 2) {
        unsigned s0 = sorted_sd[i].x;
        unsigned s1 = sorted_sd[i + 1].x;
        float av0 = __half2float(a_sorted[(size_t)i * NH + l]);
        float av1 = __half2float(a_sorted[(size_t)(i + 1) * NH + l]);
        uint4 q0 = *(const uint4*)(g_src + (size_t)s0 * NF + l * 8);
        uint4 q1 = *(const uint4*)(g_src + (size_t)s1 * NF + l * 8);
        float f0[8], f1[8];
        unpack8(q0, f0); unpack8(q1, f1);
        #pragma unroll
        for (int t = 0; t < 8; t++) acc[t] = fmaf(av0, f0[t], acc[t]);
        #pragma unroll
        for (int t = 0; t < 8; t++) acc[t] = fmaf(av1, f1[t], acc[t]);
    }
    if (i < end) {
        unsigned s0 = sorted_sd[i].x;
        float av0 = __half2float(a_sorted[(size_t)i * NH + l]);
        uint4 q0 = *(const uint4*)(g_src + (size_t)s0 * NF + l * 8);
        float f0[8]; unpack8(q0, f0);
        #pragma unroll
        for (int t = 0; t < 8; t++) acc[t] = fmaf(av0, f0[t], acc[t]);
    }

    float4* o4 = (float4*)(out + (size_t)d * NF + l * 8);
    float4 v0 = o4[0], v1 = o4[1];
    v0.x += acc[0]; v0.y += acc[1]; v0.z += acc[2]; v0.w += acc[3];
    v1.x += acc[4]; v1.y += acc[5]; v1.z += acc[6]; v1.w += acc[7];
    o4[0] = v0; o4[1] = v1;
}

// ---------------------------------------------------------------------------
// Fallbacks (small ws).
// ---------------------------------------------------------------------------
__global__ __launch_bounds__(256) void edge_kernel(
    const int* __restrict__ edge, const int* __restrict__ flags,
    const unsigned short* __restrict__ g_src, const unsigned short* __restrict__ g_dst,
    const float* __restrict__ Wa1, const float* __restrict__ ba1,
    const float* __restrict__ Wa2, const float* __restrict__ ba2,
    float* __restrict__ out, int E, int N)
{
    __shared__ __align__(16) float sW1[NF * NHID];
    __shared__ __align__(16) float sW2[NHID * NH];
    __shared__ float sb1[NHID], sb2[NH];
    int tid = threadIdx.x;
    for (int i = tid; i < NF * NHID; i += 256) sW1[i] = Wa1[i];
    if (tid < NHID * NH) sW2[tid] = Wa2[tid];
    if (tid < NHID) sb1[tid] = ba1[tid];
    if (tid < NH) sb2[tid] = ba2[tid];
    __syncthreads();

    int e = blockIdx.x * 256 + tid;
    if (e >= E) return;
    int s, d;
    load_edge(edge, e, E, flags[0], s, d);
    if ((unsigned)s >= (unsigned)N || (unsigned)d >= (unsigned)N) return;

    float ms[NF];
    float hid[NHID];
    #pragma unroll
    for (int j = 0; j < NHID; j++) hid[j] = sb1[j];

    const uint4* gs = (const uint4*)(g_src + (size_t)s * NF);
    const uint4* gd = (const uint4*)(g_dst + (size_t)d * NF);
    #pragma unroll
    for (int k = 0; k < 8; k++) {
        float a8[8], b8[8];
        unpack8(gs[k], a8);
        unpack8(gd[k], b8);
        #pragma unroll
        for (int t = 0; t < 8; t++) {
            int i = k * 8 + t;
            ms[i] = a8[t];
            float x = leaky(a8[t] + b8[t]);
            #pragma unroll
            for (int j = 0; j < NHID; j++) hid[j] = fmaf(x, sW1[i * NHID + j], hid[j]);
        }
    }

    float a[NH];
    #pragma unroll
    for (int j = 0; j < NH; j++) a[j] = sb2[j];
    #pragma unroll
    for (int k = 0; k < NHID; k++) {
        float xk = leaky(hid[k]);
        #pragma unroll
        for (int j = 0; j < NH; j++) a[j] = fmaf(xk, sW2[k * NH + j], a[j]);
    }

    float* arow = out + (size_t)d * NF;
    #pragma unroll
    for (int hh = 0; hh < NH; hh++) {
        float ah = sigmoidf(a[hh]);
        #pragma unroll
        for (int dd = 0; dd < ND; dd++)
            unsafeAtomicAdd(arow + hh * ND + dd, ah * ms[hh * ND + dd]);
    }
}

__global__ __launch_bounds__(256) void edge_kernel_fused(
    const int* __restrict__ edge, const int* __restrict__ flags,
    const float* __restrict__ h,
    const float* __restrict__ W_src, const float* __restrict__ b_src,
    const float* __restrict__ W_dst, const float* __restrict__ b_dst,
    const float* __restrict__ Wa1, const float* __restrict__ ba1,
    const float* __restrict__ Wa2, const float* __restrict__ ba2,
    float* __restrict__ out, int E, int N)
{
    __shared__ __align__(16) float sWs[NF * NF];
    __shared__ __align__(16) float sWd[NF * NF];
    __shared__ __align__(16) float sW1[NF * NHID];
    __shared__ __align__(16) float sW2[NHID * NH];
    __shared__ float sbs[NF], sbd[NF], sb1[NHID], sb2[NH];
    int tid = threadIdx.x;
    for (int i = tid; i < NF * NF; i += 256) { sWs[i] = W_src[i]; sWd[i] = W_dst[i]; }
    for (int i = tid; i < NF * NHID; i += 256) sW1[i] = Wa1[i];
    if (tid < NHID * NH) sW2[tid] = Wa2[tid];
    if (tid < NF) { sbs[tid] = b_src[tid]; sbd[tid] = b_dst[tid]; }
    if (tid < NHID) sb1[tid] = ba1[tid];
    if (tid < NH) sb2[tid] = ba2[tid];
    __syncthreads();

    int e = blockIdx.x * 256 + tid;
    if (e >= E) return;
    int wide = flags ? flags[0] : 0;
    int s, d;
    load_edge(edge, e, E, wide, s, d);
    if ((unsigned)s >= (unsigned)N || (unsigned)d >= (unsigned)N) return;

    float gsr[NF], msg[NF];
    {
        float hrow[NF];
        #pragma unroll
        for (int i = 0; i < NF; i++) hrow[i] = h[(size_t)s * NF + i];
        #pragma unroll
        for (int j = 0; j < NF; j++) gsr[j] = sbs[j];
        for (int i = 0; i < NF; i++) {
            float hi = hrow[i];
            #pragma unroll
            for (int j = 0; j < NF; j++) gsr[j] = fmaf(hi, sWs[i * NF + j], gsr[j]);
        }
    }
    #pragma unroll
    for (int j = 0; j < NF; j++) msg[j] = gsr[j] + sbd[j];
    for (int i = 0; i < NF; i++) {
        float hi = h[(size_t)d * NF + i];
        #pragma unroll
        for (int j = 0; j < NF; j++) msg[j] = fmaf(hi, sWd[i * NF + j], msg[j]);
    }

    float hid[NHID];
    #pragma unroll
    for (int j = 0; j < NHID; j++) hid[j] = sb1[j];
    for (int i = 0; i < NF; i++) {
        float x = leaky(msg[i]);
        #pragma unroll
        for (int j = 0; j < NHID; j++) hid[j] = fmaf(x, sW1[i * NHID + j], hid[j]);
    }
    float a[NH];
    #pragma unroll
    for (int j = 0; j < NH; j++) a[j] = sb2[j];
    #pragma unroll
    for (int k = 0; k < NHID; k++) {
        float xk = leaky(hid[k]);
        #pragma unroll
        for (int j = 0; j < NH; j++) a[j] = fmaf(xk, sW2[k * NH + j], a[j]);
    }

    float* arow = out + (size_t)d * NF;
    #pragma unroll
    for (int hh = 0; hh < NH; hh++) {
        float ah = sigmoidf(a[hh]);
        #pragma unroll
        for (int dd = 0; dd < ND; dd++)
            unsafeAtomicAdd(arow + hh * ND + dd, ah * gsr[hh * ND + dd]);
    }
}

static inline size_t al256(size_t x) { return (x + 255) & ~(size_t)255; }

extern "C" void kernel_launch(void* const* d_in, const int* in_sizes, int n_in,
                              void* d_out, int out_size, void* d_ws, size_t ws_size,
                              hipStream_t stream) {
    const float* h       = (const float*)d_in[0];
    const float* W_src   = (const float*)d_in[1];
    const float* b_src   = (const float*)d_in[2];
    const float* W_dst   = (const float*)d_in[3];
    const float* b_dst   = (const float*)d_in[4];
    const float* Wa1_src = (const float*)d_in[5];
    const float* ba1_src = (const float*)d_in[6];
    const float* Wa2_src = (const float*)d_in[7];
    const float* ba2_src = (const float*)d_in[8];
    const float* Wa1_dst = (const float*)d_in[9];
    const float* ba1_dst = (const float*)d_in[10];
    const float* Wa2_dst = (const float*)d_in[11];
    const float* ba2_dst = (const float*)d_in[12];
    const int* edge = (const int*)d_in[13];

    int N = in_sizes[0] / NF;
    int E = in_sizes[13] / 2;
    float* out = (float*)d_out;

    int nodeBlocks = (N + 255) / 256;
    int nodeWaves  = (N + 63) / 64;
    int edgeBlocks = (E + 255) / 256;
    int NB1 = (N + 2047) / 2048;

    size_t o_flags  = 0;
    size_t o_gsrc   = al256(o_flags + 256);
    size_t o_gdst   = al256(o_gsrc + (size_t)N * NF * 2);
    size_t o_asort  = al256(o_gdst + (size_t)N * NF * 2);   // E*NH*2 bytes; first E*4 aliased as rank[]
    size_t o_counts = al256(o_asort + (size_t)E * NH * 2);
    size_t o_offs   = al256(o_counts + (size_t)N * 4);
    size_t o_bsums  = al256(o_offs + ((size_t)N + 1) * 4);
    size_t o_sorted = al256(o_bsums + (size_t)NB1 * 4);
    size_t need     = o_sorted + (size_t)E * 8;

    size_t gB = (size_t)N * NF * 2;

    if (ws_size >= need) {
        char* w = (char*)d_ws;
        int*            flags   = (int*)(w + o_flags);
        unsigned short* g_src   = (unsigned short*)(w + o_gsrc);
        unsigned short* g_dst   = (unsigned short*)(w + o_gdst);
        __half*         a_sort  = (__half*)(w + o_asort);
        int*            rank    = (int*)(w + o_asort);      // alias: dead before a_sort is born
        int*            counts  = (int*)(w + o_counts);
        int*            offsets = (int*)(w + o_offs);
        int*            bsums   = (int*)(w + o_bsums);
        uint2*          sorted  = (uint2*)(w + o_sorted);

        detect_kernel<<<1, 1, 0, stream>>>(edge, flags);

        node_mfma_kernel<<<nodeWaves, 64, 0, stream>>>(
            h, W_src, b_src, W_dst, b_dst,
            Wa1_dst, ba1_dst, Wa2_dst, ba2_dst,
            g_src, g_dst, out, counts, N);

        hist_kernel<<<edgeBlocks, 256, 0, stream>>>(edge, flags, counts, rank, E, N);

        scan1_kernel<<<NB1, 256, 0, stream>>>(counts, offsets, bsums, N);
        scan2_kernel<<<1, 1, 0, stream>>>(bsums, offsets, NB1, N);
        scan3_kernel<<<NB1, 256, 0, stream>>>(offsets, bsums, N);

        scatter_kernel<<<edgeBlocks, 256, 0, stream>>>(
            edge, flags, offsets, rank, sorted, E, N);

        edge_mlp_mfma_kernel<<<edgeBlocks, 256, 0, stream>>>(
            sorted, offsets + N, g_src, g_dst,
            Wa1_src, ba1_src, Wa2_src, ba2_src, a_sort);

        aggregate_kernel<<<(N + 31) / 32, 256, 0, stream>>>(
            offsets, sorted, a_sort, g_src, out, N);
    } else if (ws_size >= 256 + 2 * gB) {
        int* flags = (int*)d_ws;
        unsigned short* g_src = (unsigned short*)((char*)d_ws + 256);
        unsigned short* g_dst = g_src + (size_t)N * NF;

        detect_kernel<<<1, 1, 0, stream>>>(edge, flags);

        node_kernel_t<true><<<nodeBlocks, 256, 0, stream>>>(
            h, W_src, b_src, W_dst, b_dst,
            Wa1_dst, ba1_dst, Wa2_dst, ba2_dst,
            g_src, g_dst, out, N);

        edge_kernel<<<edgeBlocks, 256, 0, stream>>>(
            edge, flags, g_src, g_dst,
            Wa1_src, ba1_src, Wa2_src, ba2_src,
            out, E, N);
    } else {
        int* flags = (ws_size >= 256) ? (int*)d_ws : nullptr;
        if (flags) detect_kernel<<<1, 1, 0, stream>>>(edge, flags);

        node_kernel_t<false><<<nodeBlocks, 256, 0, stream>>>(
            h, W_src, b_src, W_dst, b_dst,
            Wa1_dst, ba1_dst, Wa2_dst, ba2_dst,
            nullptr, nullptr, out, N);

        edge_kernel_fused<<<edgeBlocks, 256, 0, stream>>>(
            edge, flags, h,
            W_src, b_src, W_dst, b_dst,
            Wa1_src, ba1_src, Wa2_src, ba2_src,
            out, E, N);
    }
}

// Round 13
// 288.459 us; speedup vs baseline: 13.4919x; 1.0198x over previous
//
#include <hip/hip_runtime.h>
#include <hip/hip_bf16.h>
#include <hip/hip_fp16.h>

#define NF   64
#define NH   8
#define ND   8
#define NHID 32
#define XS   68   // LDS row stride in shorts (136B: 8B-aligned, 2-way banks at worst)
#define OS   10   // sOut row stride in halves (20B -> conflict-free u32 reads)

typedef __attribute__((ext_vector_type(8))) short bf16x8v;
typedef __attribute__((ext_vector_type(4))) float f32x4v;

__device__ __forceinline__ float bf2f(unsigned short u) {
    union { unsigned int i; float f; } v; v.i = ((unsigned int)u) << 16; return v.f;
}
__device__ __forceinline__ unsigned short f2bf(float f) {
    __hip_bfloat16 b = __float2bfloat16(f);
    union { __hip_bfloat16 b; unsigned short u; } v; v.b = b; return v.u;
}
__device__ __forceinline__ void unpack8(uint4 u, float* o) {
    o[0] = __uint_as_float(u.x << 16); o[1] = __uint_as_float(u.x & 0xffff0000u);
    o[2] = __uint_as_float(u.y << 16); o[3] = __uint_as_float(u.y & 0xffff0000u);
    o[4] = __uint_as_float(u.z << 16); o[5] = __uint_as_float(u.z & 0xffff0000u);
    o[6] = __uint_as_float(u.w << 16); o[7] = __uint_as_float(u.w & 0xffff0000u);
}
__device__ __forceinline__ uint4 pack8(const float* f) {
    uint4 u;
    u.x = (unsigned)f2bf(f[0]) | ((unsigned)f2bf(f[1]) << 16);
    u.y = (unsigned)f2bf(f[2]) | ((unsigned)f2bf(f[3]) << 16);
    u.z = (unsigned)f2bf(f[4]) | ((unsigned)f2bf(f[5]) << 16);
    u.w = (unsigned)f2bf(f[6]) | ((unsigned)f2bf(f[7]) << 16);
    return u;
}
__device__ __forceinline__ float leaky(float x) { return fmaxf(x, 0.2f * x); }
__device__ __forceinline__ float sigmoidf(float x) { return 1.f / (1.f + __expf(-x)); }

__global__ void detect_kernel(const int* __restrict__ edge, int* __restrict__ flags) {
    if (threadIdx.x == 0 && blockIdx.x == 0) {
        int oddnz = 0;
        for (int i = 0; i < 32; i++) oddnz |= edge[2 * i + 1];
        flags[0] = (oddnz == 0) ? 1 : 0;
    }
}

__device__ __forceinline__ void load_edge(const int* __restrict__ edge, int e, int E,
                                          int wide, int& s, int& d) {
    if (wide) { s = edge[2 * e]; d = edge[2 * (E + e)]; }
    else      { s = edge[e];     d = edge[E + e]; }
}

// ---------------------------------------------------------------------------
// Weight prep: transpose + bf16-cast into ws.
// Layout (shorts): [0,4096) WsT[n*64+k] | [4096,8192) WdT | [8192,10240) W1dT[n*64+k]
//                  [10240,12288) W1sT[n*64+k] | [12288,12544) W2sT[n*32+k]
// ---------------------------------------------------------------------------
#define WBF_TOTAL 12544
__global__ __launch_bounds__(256) void prep_weights_kernel(
    const float* __restrict__ Ws, const float* __restrict__ Wd,
    const float* __restrict__ W1d, const float* __restrict__ W1s,
    const float* __restrict__ W2s, unsigned short* __restrict__ o)
{
    int i = blockIdx.x * 256 + threadIdx.x;
    float v;
    if (i < 4096)        { int j = i;         v = Ws [(j & 63) * 64 + (j >> 6)]; }
    else if (i < 8192)   { int j = i - 4096;  v = Wd [(j & 63) * 64 + (j >> 6)]; }
    else if (i < 10240)  { int j = i - 8192;  v = W1d[(j & 63) * 32 + (j >> 6)]; }
    else if (i < 12288)  { int j = i - 10240; v = W1s[(j & 63) * 32 + (j >> 6)]; }
    else if (i < 12544)  { int j = i - 12288; v = W2s[(j & 31) * 8  + (j >> 5)]; }
    else return;
    o[i] = f2bf(v);
}

// ---------------------------------------------------------------------------
// Node phase via MFMA; B-fragments from pre-transposed bf16 weights.
// ---------------------------------------------------------------------------
__global__ __launch_bounds__(64) void node_mfma_kernel(
    const float* __restrict__ h,
    const unsigned short* __restrict__ WsT, const float* __restrict__ b_src,
    const unsigned short* __restrict__ WdT, const float* __restrict__ b_dst,
    const unsigned short* __restrict__ W1T, const float* __restrict__ ba1,
    const float* __restrict__ Wa2, const float* __restrict__ ba2,
    unsigned short* __restrict__ g_src_out, unsigned short* __restrict__ g_dst_out,
    float* __restrict__ out, int* __restrict__ counts, int N)
{
    __shared__ __align__(16) unsigned short sX[64 * XS];  // h rows, later hid
    __shared__ __align__(16) unsigned short sY[64 * XS];  // g rows (raw)
    __shared__ float sW2[NHID * NH];
    __shared__ float sb2[NH];

    int lane = threadIdx.x;
    int nsub = lane & 15, quad = lane >> 4;
    int base = blockIdx.x * 64;
    int n = base + lane;
    bool valid = n < N;
    size_t nn = valid ? (size_t)n : (size_t)(N - 1);

    if (valid && counts) counts[n] = 0;
    for (int i = lane; i < NHID * NH; i += 64) sW2[i] = Wa2[i];
    if (lane < NH) sb2[lane] = ba2[lane];

    {
        const float4* hv = (const float4*)(h + nn * NF);
        unsigned short* xrow = sX + lane * XS;
        #pragma unroll
        for (int k = 0; k < 8; k++) {
            float4 u0 = hv[2 * k], u1 = hv[2 * k + 1];
            float f[8] = { u0.x, u0.y, u0.z, u0.w, u1.x, u1.y, u1.z, u1.w };
            uint4 p = pack8(f);
            uint2* q = (uint2*)(xrow + k * 8);
            q[0] = make_uint2(p.x, p.y);
            q[1] = make_uint2(p.z, p.w);
        }
    }
    __syncthreads();

    #pragma unroll 1
    for (int m = 0; m < 2; m++) {
        const unsigned short* WT = m ? WdT : WsT;
        const float* bb = m ? b_dst : b_src;
        unsigned short* gout = m ? g_dst_out : g_src_out;

        bf16x8v Bf[2][4];
        #pragma unroll
        for (int ks = 0; ks < 2; ks++)
            #pragma unroll
            for (int nt = 0; nt < 4; nt++) {
                union { uint4 u; bf16x8v v; } u;
                u.u = *(const uint4*)(WT + (nt * 16 + nsub) * 64 + ks * 32 + quad * 8);
                Bf[ks][nt] = u.v;
            }

        f32x4v acc[4][4];
        #pragma unroll
        for (int mt = 0; mt < 4; mt++)
            #pragma unroll
            for (int nt = 0; nt < 4; nt++) {
                f32x4v z = {0.f, 0.f, 0.f, 0.f};
                acc[mt][nt] = z;
            }

        #pragma unroll
        for (int ks = 0; ks < 2; ks++)
            #pragma unroll
            for (int mt = 0; mt < 4; mt++) {
                const unsigned short* ap = sX + (mt * 16 + nsub) * XS + ks * 32 + quad * 8;
                union { uint2 d[2]; bf16x8v v; } ua;
                ua.d[0] = *(const uint2*)ap;
                ua.d[1] = *(const uint2*)(ap + 4);
                #pragma unroll
                for (int nt = 0; nt < 4; nt++)
                    acc[mt][nt] = __builtin_amdgcn_mfma_f32_16x16x32_bf16(
                        ua.v, Bf[ks][nt], acc[mt][nt], 0, 0, 0);
            }

        if (m == 1) __syncthreads();

        #pragma unroll
        for (int nt = 0; nt < 4; nt++) {
            float bv = bb[nt * 16 + nsub];
            #pragma unroll
            for (int mt = 0; mt < 4; mt++)
                #pragma unroll
                for (int r = 0; r < 4; r++)
                    sY[(mt * 16 + quad * 4 + r) * XS + nt * 16 + nsub] =
                        f2bf(acc[mt][nt][r] + bv);
        }
        __syncthreads();

        if (valid) {
            const unsigned short* yrow = sY + lane * XS;
            uint4* gp = (uint4*)(gout + (size_t)n * NF);
            #pragma unroll
            for (int k = 0; k < 8; k++) {
                uint2 a = *(const uint2*)(yrow + k * 8);
                uint2 b = *(const uint2*)(yrow + k * 8 + 4);
                gp[k] = make_uint4(a.x, a.y, b.x, b.y);
            }
        }
    }

    bf16x8v B1f[2][2];
    #pragma unroll
    for (int ks = 0; ks < 2; ks++)
        #pragma unroll
        for (int nt = 0; nt < 2; nt++) {
            union { uint4 u; bf16x8v v; } u;
            u.u = *(const uint4*)(W1T + (nt * 16 + nsub) * 64 + ks * 32 + quad * 8);
            B1f[ks][nt] = u.v;
        }

    f32x4v acc2[4][2];
    #pragma unroll
    for (int mt = 0; mt < 4; mt++)
        #pragma unroll
        for (int nt = 0; nt < 2; nt++) {
            f32x4v z = {0.f, 0.f, 0.f, 0.f};
            acc2[mt][nt] = z;
        }

    #pragma unroll
    for (int ks = 0; ks < 2; ks++)
        #pragma unroll
        for (int mt = 0; mt < 4; mt++) {
            const unsigned short* ap = sY + (mt * 16 + nsub) * XS + ks * 32 + quad * 8;
            uint2 d0 = *(const uint2*)ap;
            uint2 d1 = *(const uint2*)(ap + 4);
            float f[8];
            unpack8(make_uint4(d0.x, d0.y, d1.x, d1.y), f);
            #pragma unroll
            for (int t = 0; t < 8; t++) f[t] = leaky(f[t]);
            uint4 p = pack8(f);
            union { uint4 u; bf16x8v v; } ua; ua.u = p;
            #pragma unroll
            for (int nt = 0; nt < 2; nt++)
                acc2[mt][nt] = __builtin_amdgcn_mfma_f32_16x16x32_bf16(
                    ua.v, B1f[ks][nt], acc2[mt][nt], 0, 0, 0);
        }
    __syncthreads();

    #pragma unroll
    for (int nt = 0; nt < 2; nt++) {
        float b1v = ba1[nt * 16 + nsub];
        #pragma unroll
        for (int mt = 0; mt < 4; mt++)
            #pragma unroll
            for (int r = 0; r < 4; r++)
                sX[(mt * 16 + quad * 4 + r) * XS + nt * 16 + nsub] =
                    f2bf(leaky(acc2[mt][nt][r] + b1v));
    }
    __syncthreads();

    if (valid) {
        float hid[NHID];
        const unsigned short* hrow = sX + lane * XS;
        #pragma unroll
        for (int k = 0; k < 8; k++) {
            uint2 dv = *(const uint2*)(hrow + k * 4);
            hid[k * 4 + 0] = bf2f((unsigned short)(dv.x & 0xffffu));
            hid[k * 4 + 1] = bf2f((unsigned short)(dv.x >> 16));
            hid[k * 4 + 2] = bf2f((unsigned short)(dv.y & 0xffffu));
            hid[k * 4 + 3] = bf2f((unsigned short)(dv.y >> 16));
        }
        float a[NH];
        #pragma unroll
        for (int j = 0; j < NH; j++) a[j] = sb2[j];
        #pragma unroll
        for (int k = 0; k < NHID; k++) {
            float xk = hid[k];
            #pragma unroll
            for (int j = 0; j < NH; j++) a[j] = fmaf(xk, sW2[k * NH + j], a[j]);
        }
        #pragma unroll
        for (int j = 0; j < NH; j++) a[j] = sigmoidf(a[j]);

        const unsigned short* yrow = sY + lane * XS;
        float4* op = (float4*)(out + (size_t)n * NF);
        #pragma unroll
        for (int k = 0; k < 8; k++) {
            uint2 u0 = *(const uint2*)(yrow + k * 8);
            uint2 u1 = *(const uint2*)(yrow + k * 8 + 4);
            float g[8];
            unpack8(make_uint4(u0.x, u0.y, u1.x, u1.y), g);
            float ah0 = a[(k * 8) >> 3];
            op[2 * k]     = make_float4(ah0 * g[0], ah0 * g[1], ah0 * g[2], ah0 * g[3]);
            op[2 * k + 1] = make_float4(ah0 * g[4], ah0 * g[5], ah0 * g[6], ah0 * g[7]);
        }
    }
}

// ---------------------------------------------------------------------------
// Node phase, scalar (fallback tiers only).
// ---------------------------------------------------------------------------
template <bool STORE_G>
__global__ __launch_bounds__(256) void node_kernel_t(
    const float* __restrict__ h,
    const float* __restrict__ W_src, const float* __restrict__ b_src,
    const float* __restrict__ W_dst, const float* __restrict__ b_dst,
    const float* __restrict__ Wa1, const float* __restrict__ ba1,
    const float* __restrict__ Wa2, const float* __restrict__ ba2,
    unsigned short* __restrict__ g_src_out, unsigned short* __restrict__ g_dst_out,
    float* __restrict__ out, int N)
{
    __shared__ __align__(16) float sWs[NF * NF];
    __shared__ __align__(16) float sWd[NF * NF];
    __shared__ __align__(16) float sW1[NF * NHID];
    __shared__ __align__(16) float sW2[NHID * NH];
    __shared__ float sbs[NF], sbd[NF], sb1[NHID], sb2[NH];

    int tid = threadIdx.x;
    for (int i = tid; i < NF * NF; i += 256) { sWs[i] = W_src[i]; sWd[i] = W_dst[i]; }
    for (int i = tid; i < NF * NHID; i += 256) sW1[i] = Wa1[i];
    if (tid < NHID * NH) sW2[tid] = Wa2[tid];
    if (tid < NF) { sbs[tid] = b_src[tid]; sbd[tid] = b_dst[tid]; }
    if (tid < NHID) sb1[tid] = ba1[tid];
    if (tid < NH) sb2[tid] = ba2[tid];
    __syncthreads();

    int n = blockIdx.x * 256 + tid;
    if (n >= N) return;

    float hrow[NF];
    const float4* hv = (const float4*)(h + (size_t)n * NF);
    #pragma unroll
    for (int k = 0; k < 16; k++) {
        float4 u = hv[k];
        hrow[k * 4 + 0] = u.x; hrow[k * 4 + 1] = u.y;
        hrow[k * 4 + 2] = u.z; hrow[k * 4 + 3] = u.w;
    }

    float acc[NF];
    const float4* Wsv = (const float4*)sWs;
    const float4* Wdv = (const float4*)sWd;

    if (STORE_G) {
        #pragma unroll
        for (int j = 0; j < NF; j++) acc[j] = sbs[j];
        for (int i = 0; i < NF; i++) {
            float hi = hrow[i];
            #pragma unroll
            for (int jb = 0; jb < 16; jb++) {
                float4 w = Wsv[i * 16 + jb];
                acc[jb * 4 + 0] = fmaf(hi, w.x, acc[jb * 4 + 0]);
                acc[jb * 4 + 1] = fmaf(hi, w.y, acc[jb * 4 + 1]);
                acc[jb * 4 + 2] = fmaf(hi, w.z, acc[jb * 4 + 2]);
                acc[jb * 4 + 3] = fmaf(hi, w.w, acc[jb * 4 + 3]);
            }
        }
        uint4* gs = (uint4*)(g_src_out + (size_t)n * NF);
        #pragma unroll
        for (int k = 0; k < 8; k++) gs[k] = pack8(acc + k * 8);
    }

    #pragma unroll
    for (int j = 0; j < NF; j++) acc[j] = sbd[j];
    for (int i = 0; i < NF; i++) {
        float hi = hrow[i];
        #pragma unroll
        for (int jb = 0; jb < 16; jb++) {
            float4 w = Wdv[i * 16 + jb];
            acc[jb * 4 + 0] = fmaf(hi, w.x, acc[jb * 4 + 0]);
            acc[jb * 4 + 1] = fmaf(hi, w.y, acc[jb * 4 + 1]);
            acc[jb * 4 + 2] = fmaf(hi, w.z, acc[jb * 4 + 2]);
            acc[jb * 4 + 3] = fmaf(hi, w.w, acc[jb * 4 + 3]);
        }
    }
    if (STORE_G) {
        uint4* gd = (uint4*)(g_dst_out + (size_t)n * NF);
        #pragma unroll
        for (int k = 0; k < 8; k++) gd[k] = pack8(acc + k * 8);
    }

    float hid[NHID];
    #pragma unroll
    for (int j = 0; j < NHID; j++) hid[j] = sb1[j];
    const float4* W1v = (const float4*)sW1;
    for (int i = 0; i < NF; i++) {
        float xi = leaky(acc[i]);
        #pragma unroll
        for (int jb = 0; jb < 8; jb++) {
            float4 w = W1v[i * 8 + jb];
            hid[jb * 4 + 0] = fmaf(xi, w.x, hid[jb * 4 + 0]);
            hid[jb * 4 + 1] = fmaf(xi, w.y, hid[jb * 4 + 1]);
            hid[jb * 4 + 2] = fmaf(xi, w.z, hid[jb * 4 + 2]);
            hid[jb * 4 + 3] = fmaf(xi, w.w, hid[jb * 4 + 3]);
        }
    }
    float a[NH];
    #pragma unroll
    for (int j = 0; j < NH; j++) a[j] = sb2[j];
    #pragma unroll
    for (int k = 0; k < NHID; k++) {
        float xk = leaky(hid[k]);
        #pragma unroll
        for (int j = 0; j < NH; j++) a[j] = fmaf(xk, sW2[k * NH + j], a[j]);
    }
    #pragma unroll
    for (int j = 0; j < NH; j++) a[j] = sigmoidf(a[j]);

    float4* ap = (float4*)(out + (size_t)n * NF);
    #pragma unroll
    for (int k = 0; k < 16; k++) {
        int j = k * 4;
        ap[k] = make_float4(a[(j + 0) >> 3] * acc[j + 0],
                            a[(j + 1) >> 3] * acc[j + 1],
                            a[(j + 2) >> 3] * acc[j + 2],
                            a[(j + 3) >> 3] * acc[j + 3]);
    }
}

// ---------------------------------------------------------------------------
// Hist + rank claim.
// ---------------------------------------------------------------------------
__global__ __launch_bounds__(256) void hist_kernel(
    const int* __restrict__ edge, const int* __restrict__ flags,
    int* __restrict__ counts, int* __restrict__ rank, int E, int N)
{
    int e = blockIdx.x * 256 + threadIdx.x;
    if (e >= E) return;
    int s, d;
    load_edge(edge, e, E, flags[0], s, d);
    if ((unsigned)s >= (unsigned)N || (unsigned)d >= (unsigned)N) { rank[e] = -1; return; }
    rank[e] = atomicAdd(&counts[d], 1);
}

__global__ __launch_bounds__(256) void scan1_kernel(
    const int* __restrict__ counts, int* __restrict__ offsets,
    int* __restrict__ bsums, int N)
{
    __shared__ int lds[256];
    int tid = threadIdx.x;
    int base = blockIdx.x * 2048 + tid * 8;
    int v[8]; int s = 0;
    #pragma unroll
    for (int k = 0; k < 8; k++) { int idx = base + k; int t = (idx < N) ? counts[idx] : 0; v[k] = t; s += t; }
    lds[tid] = s;
    __syncthreads();
    for (int off = 1; off < 256; off <<= 1) {
        int y = (tid >= off) ? lds[tid - off] : 0;
        __syncthreads();
        lds[tid] += y;
        __syncthreads();
    }
    int run = lds[tid] - s;
    #pragma unroll
    for (int k = 0; k < 8; k++) { int idx = base + k; if (idx < N) offsets[idx] = run; run += v[k]; }
    if (tid == 255) bsums[blockIdx.x] = lds[255];
}

__global__ void scan2_kernel(int* __restrict__ bsums, int* __restrict__ offsets, int NB, int N) {
    if (threadIdx.x == 0 && blockIdx.x == 0) {
        int run = 0;
        for (int i = 0; i < NB; i++) { int t = bsums[i]; bsums[i] = run; run += t; }
        offsets[N] = run;
    }
}

__global__ __launch_bounds__(256) void scan3_kernel(
    int* __restrict__ offsets, const int* __restrict__ bsums, int N)
{
    int add = bsums[blockIdx.x];
    int base = blockIdx.x * 2048 + threadIdx.x * 8;
    #pragma unroll
    for (int k = 0; k < 8; k++) { int idx = base + k; if (idx < N) offsets[idx] += add; }
}

__global__ __launch_bounds__(256) void scatter_kernel(
    const int* __restrict__ edge, const int* __restrict__ flags,
    const int* __restrict__ offsets, const int* __restrict__ rank,
    uint2* __restrict__ sorted_sd, int E, int N)
{
    int e = blockIdx.x * 256 + threadIdx.x;
    if (e >= E) return;
    int r = rank[e];
    if (r < 0) return;
    int s, d;
    load_edge(edge, e, E, flags[0], s, d);
    int pos = offsets[d] + r;
    sorted_sd[pos] = make_uint2((unsigned)s, (unsigned)d);
}

// ---------------------------------------------------------------------------
// Edge MLP, both layers via MFMA; weights from pre-transposed bf16.
// ---------------------------------------------------------------------------
__global__ __launch_bounds__(256) void edge_mlp_mfma_kernel(
    const uint2* __restrict__ sorted_sd, const int* __restrict__ total_p,
    const unsigned short* __restrict__ g_src, const unsigned short* __restrict__ g_dst,
    const unsigned short* __restrict__ W1T, const float* __restrict__ ba1,
    const unsigned short* __restrict__ W2T, const float* __restrict__ ba2,
    __half* __restrict__ a_sorted)
{
    __shared__ __align__(16) unsigned short sX[4 * 64 * XS];
    __shared__ __align__(16) __half sOut[4 * 64 * OS];
    __shared__ float sb1[NHID], sb2[NH];

    int tid = threadIdx.x;
    if (tid < NHID) sb1[tid] = ba1[tid];
    if (tid < NH) sb2[tid] = ba2[tid];

    int wave = tid >> 6;
    int lane = tid & 63;
    int nsub = lane & 15;
    int quad = lane >> 4;
    int total = *total_p;
    int i = blockIdx.x * 256 + wave * 64 + lane;
    bool valid = i < total;
    uint2 sd = valid ? sorted_sd[i] : make_uint2(0u, 0u);

    // ---- stage x = leaky(gs + gd) rows ----
    unsigned short* xrow = sX + (wave * 64 + lane) * XS;
    {
        const uint4* gs = (const uint4*)(g_src + (size_t)sd.x * NF);
        const uint4* gd = (const uint4*)(g_dst + (size_t)sd.y * NF);
        #pragma unroll
        for (int k = 0; k < 8; k++) {
            float A8[8], B8[8], x8[8];
            unpack8(gs[k], A8); unpack8(gd[k], B8);
            #pragma unroll
            for (int t = 0; t < 8; t++) x8[t] = leaky(A8[t] + B8[t]);
            uint4 pk = pack8(x8);
            uint2* q = (uint2*)(xrow + k * 8);
            q[0] = make_uint2(pk.x, pk.y);
            q[1] = make_uint2(pk.z, pk.w);
        }
    }

    // ---- layer-1 B-fragments: one 16B load each ----
    bf16x8v Bf[2][2];
    #pragma unroll
    for (int ks = 0; ks < 2; ks++)
        #pragma unroll
        for (int nt = 0; nt < 2; nt++) {
            union { uint4 u; bf16x8v v; } u;
            u.u = *(const uint4*)(W1T + (nt * 16 + nsub) * 64 + ks * 32 + quad * 8);
            Bf[ks][nt] = u.v;
        }
    // ---- layer-2 B-fragment (N=16, cols 8..15 zero) ----
    bf16x8v B2f;
    {
        union { uint4 u; bf16x8v v; } u;
        if (nsub < NH) u.u = *(const uint4*)(W2T + nsub * 32 + quad * 8);
        else           u.u = make_uint4(0u, 0u, 0u, 0u);
        B2f = u.v;
    }

    __syncthreads();

    // ---- layer 1 ----
    f32x4v acc[4][2];
    #pragma unroll
    for (int mt = 0; mt < 4; mt++)
        #pragma unroll
        for (int nt = 0; nt < 2; nt++) {
            f32x4v z = {0.f, 0.f, 0.f, 0.f};
            acc[mt][nt] = z;
        }

    const unsigned short* wbase = sX + wave * 64 * XS;
    #pragma unroll
    for (int ks = 0; ks < 2; ks++) {
        #pragma unroll
        for (int mt = 0; mt < 4; mt++) {
            const unsigned short* ap = wbase + (mt * 16 + nsub) * XS + ks * 32 + quad * 8;
            union { uint2 d[2]; bf16x8v v; } ua;
            ua.d[0] = *(const uint2*)ap;
            ua.d[1] = *(const uint2*)(ap + 4);
            #pragma unroll
            for (int nt = 0; nt < 2; nt++)
                acc[mt][nt] = __builtin_amdgcn_mfma_f32_16x16x32_bf16(
                    ua.v, Bf[ks][nt], acc[mt][nt], 0, 0, 0);
        }
    }

    __syncthreads();

    // ---- H = leaky(acc + b1) back to sX (C-layout) ----
    #pragma unroll
    for (int nt = 0; nt < 2; nt++) {
        int n = nt * 16 + nsub;
        float b1v = sb1[n];
        #pragma unroll
        for (int mt = 0; mt < 4; mt++) {
            #pragma unroll
            for (int r = 0; r < 4; r++) {
                int m = mt * 16 + quad * 4 + r;
                sX[(wave * 64 + m) * XS + n] = f2bf(leaky(acc[mt][nt][r] + b1v));
            }
        }
    }

    __syncthreads();

    // ---- layer 2 via MFMA: H[64x32] @ W2[32x16(8 valid)] ----
    f32x4v acc2[4];
    #pragma unroll
    for (int mt = 0; mt < 4; mt++) { f32x4v z = {0.f, 0.f, 0.f, 0.f}; acc2[mt] = z; }
    #pragma unroll
    for (int mt = 0; mt < 4; mt++) {
        const unsigned short* ap = wbase + (mt * 16 + nsub) * XS + quad * 8;
        union { uint2 d[2]; bf16x8v v; } ua;
        ua.d[0] = *(const uint2*)ap;
        ua.d[1] = *(const uint2*)(ap + 4);
        acc2[mt] = __builtin_amdgcn_mfma_f32_16x16x32_bf16(ua.v, B2f, acc2[mt], 0, 0, 0);
    }

    // ---- sigmoid + route through sOut for row-contiguous store ----
    if (nsub < NH) {
        float b2v = sb2[nsub];
        #pragma unroll
        for (int mt = 0; mt < 4; mt++)
            #pragma unroll
            for (int r = 0; r < 4; r++) {
                int m = mt * 16 + quad * 4 + r;
                sOut[(wave * 64 + m) * OS + nsub] = __float2half(sigmoidf(acc2[mt][r] + b2v));
            }
    }
    __syncthreads();

    if (valid) {
        const unsigned int* orow = (const unsigned int*)(sOut + (wave * 64 + lane) * OS);
        uint4 pk = make_uint4(orow[0], orow[1], orow[2], orow[3]);
        *(uint4*)(a_sorted + (size_t)i * NH) = pk;
    }
}

// ---------------------------------------------------------------------------
// Aggregate v2 (unchanged).
// ---------------------------------------------------------------------------
__global__ __launch_bounds__(256) void aggregate_kernel(
    const int* __restrict__ offsets, const uint2* __restrict__ sorted_sd,
    const __half* __restrict__ a_sorted, const unsigned short* __restrict__ g_src,
    float* __restrict__ out, int N)
{
    int d = blockIdx.x * 32 + (threadIdx.x >> 3);
    if (d >= N) return;
    int l = threadIdx.x & 7;
    int beg = offsets[d], end = offsets[d + 1];

    float acc[8] = {0.f, 0.f, 0.f, 0.f, 0.f, 0.f, 0.f, 0.f};
    int i = beg;
    for (; i + 2 <= end; i += 2) {
        unsigned s0 = sorted_sd[i].x;
        unsigned s1 = sorted_sd[i + 1].x;
        float av0 = __half2float(a_sorted[(size_t)i * NH + l]);
        float av1 = __half2float(a_sorted[(size_t)(i + 1) * NH + l]);
        uint4 q0 = *(const uint4*)(g_src + (size_t)s0 * NF + l * 8);
        uint4 q1 = *(const uint4*)(g_src + (size_t)s1 * NF + l * 8);
        float f0[8], f1[8];
        unpack8(q0, f0); unpack8(q1, f1);
        #pragma unroll
        for (int t = 0; t < 8; t++) acc[t] = fmaf(av0, f0[t], acc[t]);
        #pragma unroll
        for (int t = 0; t < 8; t++) acc[t] = fmaf(av1, f1[t], acc[t]);
    }
    if (i < end) {
        unsigned s0 = sorted_sd[i].x;
        float av0 = __half2float(a_sorted[(size_t)i * NH + l]);
        uint4 q0 = *(const uint4*)(g_src + (size_t)s0 * NF + l * 8);
        float f0[8]; unpack8(q0, f0);
        #pragma unroll
        for (int t = 0; t < 8; t++) acc[t] = fmaf(av0, f0[t], acc[t]);
    }

    float4* o4 = (float4*)(out + (size_t)d * NF + l * 8);
    float4 v0 = o4[0], v1 = o4[1];
    v0.x += acc[0]; v0.y += acc[1]; v0.z += acc[2]; v0.w += acc[3];
    v1.x += acc[4]; v1.y += acc[5]; v1.z += acc[6]; v1.w += acc[7];
    o4[0] = v0; o4[1] = v1;
}

// ---------------------------------------------------------------------------
// Fallbacks (small ws): R5 atomic edge kernel / fully fused.
// ---------------------------------------------------------------------------
__global__ __launch_bounds__(256) void edge_kernel(
    const int* __restrict__ edge, const int* __restrict__ flags,
    const unsigned short* __restrict__ g_src, const unsigned short* __restrict__ g_dst,
    const float* __restrict__ Wa1, const float* __restrict__ ba1,
    const float* __restrict__ Wa2, const float* __restrict__ ba2,
    float* __restrict__ out, int E, int N)
{
    __shared__ __align__(16) float sW1[NF * NHID];
    __shared__ __align__(16) float sW2[NHID * NH];
    __shared__ float sb1[NHID], sb2[NH];
    int tid = threadIdx.x;
    for (int i = tid; i < NF * NHID; i += 256) sW1[i] = Wa1[i];
    if (tid < NHID * NH) sW2[tid] = Wa2[tid];
    if (tid < NHID) sb1[tid] = ba1[tid];
    if (tid < NH) sb2[tid] = ba2[tid];
    __syncthreads();

    int e = blockIdx.x * 256 + tid;
    if (e >= E) return;
    int s, d;
    load_edge(edge, e, E, flags[0], s, d);
    if ((unsigned)s >= (unsigned)N || (unsigned)d >= (unsigned)N) return;

    float ms[NF];
    float hid[NHID];
    #pragma unroll
    for (int j = 0; j < NHID; j++) hid[j] = sb1[j];

    const uint4* gs = (const uint4*)(g_src + (size_t)s * NF);
    const uint4* gd = (const uint4*)(g_dst + (size_t)d * NF);
    #pragma unroll
    for (int k = 0; k < 8; k++) {
        float a8[8], b8[8];
        unpack8(gs[k], a8);
        unpack8(gd[k], b8);
        #pragma unroll
        for (int t = 0; t < 8; t++) {
            int i = k * 8 + t;
            ms[i] = a8[t];
            float x = leaky(a8[t] + b8[t]);
            #pragma unroll
            for (int j = 0; j < NHID; j++) hid[j] = fmaf(x, sW1[i * NHID + j], hid[j]);
        }
    }

    float a[NH];
    #pragma unroll
    for (int j = 0; j < NH; j++) a[j] = sb2[j];
    #pragma unroll
    for (int k = 0; k < NHID; k++) {
        float xk = leaky(hid[k]);
        #pragma unroll
        for (int j = 0; j < NH; j++) a[j] = fmaf(xk, sW2[k * NH + j], a[j]);
    }

    float* arow = out + (size_t)d * NF;
    #pragma unroll
    for (int hh = 0; hh < NH; hh++) {
        float ah = sigmoidf(a[hh]);
        #pragma unroll
        for (int dd = 0; dd < ND; dd++)
            unsafeAtomicAdd(arow + hh * ND + dd, ah * ms[hh * ND + dd]);
    }
}

__global__ __launch_bounds__(256) void edge_kernel_fused(
    const int* __restrict__ edge, const int* __restrict__ flags,
    const float* __restrict__ h,
    const float* __restrict__ W_src, const float* __restrict__ b_src,
    const float* __restrict__ W_dst, const float* __restrict__ b_dst,
    const float* __restrict__ Wa1, const float* __restrict__ ba1,
    const float* __restrict__ Wa2, const float* __restrict__ ba2,
    float* __restrict__ out, int E, int N)
{
    __shared__ __align__(16) float sWs[NF * NF];
    __shared__ __align__(16) float sWd[NF * NF];
    __shared__ __align__(16) float sW1[NF * NHID];
    __shared__ __align__(16) float sW2[NHID * NH];
    __shared__ float sbs[NF], sbd[NF], sb1[NHID], sb2[NH];
    int tid = threadIdx.x;
    for (int i = tid; i < NF * NF; i += 256) { sWs[i] = W_src[i]; sWd[i] = W_dst[i]; }
    for (int i = tid; i < NF * NHID; i += 256) sW1[i] = Wa1[i];
    if (tid < NHID * NH) sW2[tid] = Wa2[tid];
    if (tid < NF) { sbs[tid] = b_src[tid]; sbd[tid] = b_dst[tid]; }
    if (tid < NHID) sb1[tid] = ba1[tid];
    if (tid < NH) sb2[tid] = ba2[tid];
    __syncthreads();

    int e = blockIdx.x * 256 + tid;
    if (e >= E) return;
    int wide = flags ? flags[0] : 0;
    int s, d;
    load_edge(edge, e, E, wide, s, d);
    if ((unsigned)s >= (unsigned)N || (unsigned)d >= (unsigned)N) return;

    float gsr[NF], msg[NF];
    {
        float hrow[NF];
        #pragma unroll
        for (int i = 0; i < NF; i++) hrow[i] = h[(size_t)s * NF + i];
        #pragma unroll
        for (int j = 0; j < NF; j++) gsr[j] = sbs[j];
        for (int i = 0; i < NF; i++) {
            float hi = hrow[i];
            #pragma unroll
            for (int j = 0; j < NF; j++) gsr[j] = fmaf(hi, sWs[i * NF + j], gsr[j]);
        }
    }
    #pragma unroll
    for (int j = 0; j < NF; j++) msg[j] = gsr[j] + sbd[j];
    for (int i = 0; i < NF; i++) {
        float hi = h[(size_t)d * NF + i];
        #pragma unroll
        for (int j = 0; j < NF; j++) msg[j] = fmaf(hi, sWd[i * NF + j], msg[j]);
    }

    float hid[NHID];
    #pragma unroll
    for (int j = 0; j < NHID; j++) hid[j] = sb1[j];
    for (int i = 0; i < NF; i++) {
        float x = leaky(msg[i]);
        #pragma unroll
        for (int j = 0; j < NHID; j++) hid[j] = fmaf(x, sW1[i * NHID + j], hid[j]);
    }
    float a[NH];
    #pragma unroll
    for (int j = 0; j < NH; j++) a[j] = sb2[j];
    #pragma unroll
    for (int k = 0; k < NHID; k++) {
        float xk = leaky(hid[k]);
        #pragma unroll
        for (int j = 0; j < NH; j++) a[j] = fmaf(xk, sW2[k * NH + j], a[j]);
    }

    float* arow = out + (size_t)d * NF;
    #pragma unroll
    for (int hh = 0; hh < NH; hh++) {
        float ah = sigmoidf(a[hh]);
        #pragma unroll
        for (int dd = 0; dd < ND; dd++)
            unsafeAtomicAdd(arow + hh * ND + dd, ah * gsr[hh * ND + dd]);
    }
}

static inline size_t al256(size_t x) { return (x + 255) & ~(size_t)255; }

extern "C" void kernel_launch(void* const* d_in, const int* in_sizes, int n_in,
                              void* d_out, int out_size, void* d_ws, size_t ws_size,
                              hipStream_t stream) {
    const float* h       = (const float*)d_in[0];
    const float* W_src   = (const float*)d_in[1];
    const float* b_src   = (const float*)d_in[2];
    const float* W_dst   = (const float*)d_in[3];
    const float* b_dst   = (const float*)d_in[4];
    const float* Wa1_src = (const float*)d_in[5];
    const float* ba1_src = (const float*)d_in[6];
    const float* Wa2_src = (const float*)d_in[7];
    const float* ba2_src = (const float*)d_in[8];
    const float* Wa1_dst = (const float*)d_in[9];
    const float* ba1_dst = (const float*)d_in[10];
    const float* Wa2_dst = (const float*)d_in[11];
    const float* ba2_dst = (const float*)d_in[12];
    const int* edge = (const int*)d_in[13];

    int N = in_sizes[0] / NF;
    int E = in_sizes[13] / 2;
    float* out = (float*)d_out;

    int nodeBlocks = (N + 255) / 256;
    int nodeWaves  = (N + 63) / 64;
    int edgeBlocks = (E + 255) / 256;
    int NB1 = (N + 2047) / 2048;

    size_t o_flags  = 0;
    size_t o_wbf    = al256(o_flags + 256);
    size_t o_gsrc   = al256(o_wbf + (size_t)WBF_TOTAL * 2);
    size_t o_gdst   = al256(o_gsrc + (size_t)N * NF * 2);
    size_t o_asort  = al256(o_gdst + (size_t)N * NF * 2);   // E*NH*2 bytes; first E*4 aliased as rank[]
    size_t o_counts = al256(o_asort + (size_t)E * NH * 2);
    size_t o_offs   = al256(o_counts + (size_t)N * 4);
    size_t o_bsums  = al256(o_offs + ((size_t)N + 1) * 4);
    size_t o_sorted = al256(o_bsums + (size_t)NB1 * 4);
    size_t need     = o_sorted + (size_t)E * 8;

    size_t gB = (size_t)N * NF * 2;

    if (ws_size >= need) {
        char* w = (char*)d_ws;
        int*            flags   = (int*)(w + o_flags);
        unsigned short* wbf     = (unsigned short*)(w + o_wbf);
        unsigned short* WsT     = wbf;
        unsigned short* WdT     = wbf + 4096;
        unsigned short* W1dT    = wbf + 8192;
        unsigned short* W1sT    = wbf + 10240;
        unsigned short* W2sT    = wbf + 12288;
        unsigned short* g_src   = (unsigned short*)(w + o_gsrc);
        unsigned short* g_dst   = (unsigned short*)(w + o_gdst);
        __half*         a_sort  = (__half*)(w + o_asort);
        int*            rank    = (int*)(w + o_asort);      // alias: dead before a_sort is born
        int*            counts  = (int*)(w + o_counts);
        int*            offsets = (int*)(w + o_offs);
        int*            bsums   = (int*)(w + o_bsums);
        uint2*          sorted  = (uint2*)(w + o_sorted);

        detect_kernel<<<1, 1, 0, stream>>>(edge, flags);
        prep_weights_kernel<<<(WBF_TOTAL + 255) / 256, 256, 0, stream>>>(
            W_src, W_dst, Wa1_dst, Wa1_src, Wa2_src, wbf);

        node_mfma_kernel<<<nodeWaves, 64, 0, stream>>>(
            h, WsT, b_src, WdT, b_dst,
            W1dT, ba1_dst, Wa2_dst, ba2_dst,
            g_src, g_dst, out, counts, N);

        hist_kernel<<<edgeBlocks, 256, 0, stream>>>(edge, flags, counts, rank, E, N);

        scan1_kernel<<<NB1, 256, 0, stream>>>(counts, offsets, bsums, N);
        scan2_kernel<<<1, 1, 0, stream>>>(bsums, offsets, NB1, N);
        scan3_kernel<<<NB1, 256, 0, stream>>>(offsets, bsums, N);

        scatter_kernel<<<edgeBlocks, 256, 0, stream>>>(
            edge, flags, offsets, rank, sorted, E, N);

        edge_mlp_mfma_kernel<<<edgeBlocks, 256, 0, stream>>>(
            sorted, offsets + N, g_src, g_dst,
            W1sT, ba1_src, W2sT, ba2_src, a_sort);

        aggregate_kernel<<<(N + 31) / 32, 256, 0, stream>>>(
            offsets, sorted, a_sort, g_src, out, N);
    } else if (ws_size >= 256 + 2 * gB) {
        int* flags = (int*)d_ws;
        unsigned short* g_src = (unsigned short*)((char*)d_ws + 256);
        unsigned short* g_dst = g_src + (size_t)N * NF;

        detect_kernel<<<1, 1, 0, stream>>>(edge, flags);

        node_kernel_t<true><<<nodeBlocks, 256, 0, stream>>>(
            h, W_src, b_src, W_dst, b_dst,
            Wa1_dst, ba1_dst, Wa2_dst, ba2_dst,
            g_src, g_dst, out, N);

        edge_kernel<<<edgeBlocks, 256, 0, stream>>>(
            edge, flags, g_src, g_dst,
            Wa1_src, ba1_src, Wa2_src, ba2_src,
            out, E, N);
    } else {
        int* flags = (ws_size >= 256) ? (int*)d_ws : nullptr;
        if (flags) detect_kernel<<<1, 1, 0, stream>>>(edge, flags);

        node_kernel_t<false><<<nodeBlocks, 256, 0, stream>>>(
            h, W_src, b_src, W_dst, b_dst,
            Wa1_dst, ba1_dst, Wa2_dst, ba2_dst,
            nullptr, nullptr, out, N);

        edge_kernel_fused<<<edgeBlocks, 256, 0, stream>>>(
            edge, flags, h,
            W_src, b_src, W_dst, b_dst,
            Wa1_src, ba1_src, Wa2_src, ba2_src,
            out, E, N);
    }
}